// Round 2
// baseline (5074.500 us; speedup 1.0000x reference)
//
#include <hip/hip_runtime.h>
#include <cstddef>
#include <cstdint>

// Problem constants (match reference)
constexpr int Bc  = 4;
constexpr int Tc  = 2048;
constexpr int Dc  = 1024;
constexpr int Hc  = 16;
constexpr int DHc = 64;    // head dim
constexpr int Ec  = 8;     // experts
constexpr int DEc = 256;   // expert dim
constexpr int NTOK = Bc * Tc;          // 8192 tokens
constexpr int EDE = Ec * DEc;          // 2048

// ---------------------------------------------------------------------------
// LayerNorm: one block (256 threads) per row of D=1024
// ---------------------------------------------------------------------------
__global__ __launch_bounds__(256)
void ln_kernel(const float* __restrict__ in, const float* __restrict__ g,
               const float* __restrict__ bt, float* __restrict__ out) {
  const int row = blockIdx.x;
  const int tid = threadIdx.x;
  const float* xr = in + (size_t)row * Dc;
  float4 v = *(const float4*)(xr + tid * 4);
  float s  = v.x + v.y + v.z + v.w;
  float ss = v.x * v.x + v.y * v.y + v.z * v.z + v.w * v.w;
#pragma unroll
  for (int off = 32; off; off >>= 1) {
    s  += __shfl_xor(s, off);
    ss += __shfl_xor(ss, off);
  }
  __shared__ float red[8];
  const int w = tid >> 6;
  if ((tid & 63) == 0) { red[w] = s; red[4 + w] = ss; }
  __syncthreads();
  const float ts  = red[0] + red[1] + red[2] + red[3];
  const float tss = red[4] + red[5] + red[6] + red[7];
  const float mean = ts * (1.0f / Dc);
  const float var  = tss * (1.0f / Dc) - mean * mean;
  const float rstd = rsqrtf(var + 1e-5f);
  float4 gv = *(const float4*)(g + tid * 4);
  float4 bv = *(const float4*)(bt + tid * 4);
  float4 o;
  o.x = (v.x - mean) * rstd * gv.x + bv.x;
  o.y = (v.y - mean) * rstd * gv.y + bv.y;
  o.z = (v.z - mean) * rstd * gv.z + bv.z;
  o.w = (v.w - mean) * rstd * gv.w + bv.w;
  *(float4*)(out + (size_t)row * Dc + tid * 4) = o;
}

// ---------------------------------------------------------------------------
// fp32 GEMM: C[M,N] = A[M,K] @ W[N,K]^T (+bias)(+resid)(+=C if ACC)
// Tile 128x128, BK=16, 256 threads, 8x8 per thread. All dims multiples.
// ---------------------------------------------------------------------------
template <bool ACC>
__global__ __launch_bounds__(256)
void gemm_nt(const float* __restrict__ A, int lda,
             const float* __restrict__ W,     // [N,K] row-major
             const float* __restrict__ bias,  // [N] or null
             const float* __restrict__ resid, // [M,ldc] or null
             float* __restrict__ C, int ldc, int K) {
  __shared__ float As[16][132];
  __shared__ float Bs[16][132];
  const int tid = threadIdx.x;
  const int m0 = blockIdx.y * 128;
  const int n0 = blockIdx.x * 128;
  const int lrow = tid >> 1;
  const int lk = (tid & 1) * 8;
  const float* Ag = A + (size_t)(m0 + lrow) * lda + lk;
  const float* Wg = W + (size_t)(n0 + lrow) * K + lk;
  const int tx = tid & 15, ty = tid >> 4;
  float acc[8][8];
#pragma unroll
  for (int i = 0; i < 8; ++i) {
#pragma unroll
    for (int j = 0; j < 8; ++j) acc[i][j] = 0.f;
  }
  for (int k0 = 0; k0 < K; k0 += 16) {
    float4 a0 = *(const float4*)(Ag + k0);
    float4 a1 = *(const float4*)(Ag + k0 + 4);
    float4 w0 = *(const float4*)(Wg + k0);
    float4 w1 = *(const float4*)(Wg + k0 + 4);
    As[lk + 0][lrow] = a0.x; As[lk + 1][lrow] = a0.y;
    As[lk + 2][lrow] = a0.z; As[lk + 3][lrow] = a0.w;
    As[lk + 4][lrow] = a1.x; As[lk + 5][lrow] = a1.y;
    As[lk + 6][lrow] = a1.z; As[lk + 7][lrow] = a1.w;
    Bs[lk + 0][lrow] = w0.x; Bs[lk + 1][lrow] = w0.y;
    Bs[lk + 2][lrow] = w0.z; Bs[lk + 3][lrow] = w0.w;
    Bs[lk + 4][lrow] = w1.x; Bs[lk + 5][lrow] = w1.y;
    Bs[lk + 6][lrow] = w1.z; Bs[lk + 7][lrow] = w1.w;
    __syncthreads();
#pragma unroll
    for (int kk = 0; kk < 16; ++kk) {
      float4 av0 = *(const float4*)&As[kk][ty * 8];
      float4 av1 = *(const float4*)&As[kk][ty * 8 + 4];
      float4 bv0 = *(const float4*)&Bs[kk][tx * 8];
      float4 bv1 = *(const float4*)&Bs[kk][tx * 8 + 4];
      float a[8]  = {av0.x, av0.y, av0.z, av0.w, av1.x, av1.y, av1.z, av1.w};
      float bb[8] = {bv0.x, bv0.y, bv0.z, bv0.w, bv1.x, bv1.y, bv1.z, bv1.w};
#pragma unroll
      for (int i = 0; i < 8; ++i) {
#pragma unroll
        for (int j = 0; j < 8; ++j) acc[i][j] = fmaf(a[i], bb[j], acc[i][j]);
      }
    }
    __syncthreads();
  }
#pragma unroll
  for (int i = 0; i < 8; ++i) {
    const int r = m0 + ty * 8 + i;
    float* Crow = C + (size_t)r * ldc + n0 + tx * 8;
#pragma unroll
    for (int j = 0; j < 8; ++j) {
      float v = acc[i][j];
      if (bias)  v += bias[n0 + tx * 8 + j];
      if (resid) v += resid[(size_t)r * ldc + n0 + tx * 8 + j];
      if (ACC)   v += Crow[j];
      Crow[j] = v;
    }
  }
}

// ---------------------------------------------------------------------------
// Flash attention, fp32. Block = 256 threads (4 waves), 16 q-rows per block
// (4 per wave). K/V chunks of 64 staged in LDS. O written over the Q slot of
// qkv in place (each q row/col range is touched only by its own block).
// qkv layout: [B, T, 3*D]; head h occupies cols h*64..h*64+63 in each third.
// ---------------------------------------------------------------------------
__global__ __launch_bounds__(256)
void attn_kernel(float* __restrict__ qkv) {
  constexpr int QB = 16;
  constexpr int CH = 64;
  const int nqt = Tc / QB;  // 128
  const int bh = blockIdx.x / nqt;
  const int qt = blockIdx.x % nqt;
  const int b = bh / Hc, h = bh % Hc;
  __shared__ float Qs[QB][DHc];
  __shared__ float Ks[CH][DHc + 1];
  __shared__ float Vs[CH][DHc + 1];
  __shared__ float Ps[QB][CH + 1];
  const int tid = threadIdx.x;
  const int lane = tid & 63;
  const int w = tid >> 6;
  float* base = qkv + ((size_t)b * Tc) * (3 * Dc) + h * DHc;
  {  // load + scale Q
    const int r = tid >> 4;
    const int c = (tid & 15) * 4;
    const float* qp = base + (size_t)(qt * QB + r) * (3 * Dc) + c;
    float4 qv = *(const float4*)qp;
    Qs[r][c + 0] = qv.x * 0.125f;
    Qs[r][c + 1] = qv.y * 0.125f;
    Qs[r][c + 2] = qv.z * 0.125f;
    Qs[r][c + 3] = qv.w * 0.125f;
  }
  float mr[4] = {-1e30f, -1e30f, -1e30f, -1e30f};
  float lr[4] = {0.f, 0.f, 0.f, 0.f};
  float orr[4] = {0.f, 0.f, 0.f, 0.f};
  __syncthreads();
  for (int j0 = 0; j0 < Tc; j0 += CH) {
    {  // stage K,V chunk
      const int jr = tid >> 2;
      const int jc = (tid & 3) * 16;
      const float* kp = base + (size_t)(j0 + jr) * (3 * Dc) + Dc + jc;
      const float* vp = base + (size_t)(j0 + jr) * (3 * Dc) + 2 * Dc + jc;
#pragma unroll
      for (int u = 0; u < 4; ++u) {
        float4 kv = *(const float4*)(kp + u * 4);
        float4 vv = *(const float4*)(vp + u * 4);
        Ks[jr][jc + u * 4 + 0] = kv.x; Ks[jr][jc + u * 4 + 1] = kv.y;
        Ks[jr][jc + u * 4 + 2] = kv.z; Ks[jr][jc + u * 4 + 3] = kv.w;
        Vs[jr][jc + u * 4 + 0] = vv.x; Vs[jr][jc + u * 4 + 1] = vv.y;
        Vs[jr][jc + u * 4 + 2] = vv.z; Vs[jr][jc + u * 4 + 3] = vv.w;
      }
    }
    __syncthreads();
    // scores: lane = key index within chunk
    float s[4] = {0.f, 0.f, 0.f, 0.f};
#pragma unroll 16
    for (int d = 0; d < DHc; ++d) {
      const float kd = Ks[lane][d];
      s[0] = fmaf(Qs[w * 4 + 0][d], kd, s[0]);
      s[1] = fmaf(Qs[w * 4 + 1][d], kd, s[1]);
      s[2] = fmaf(Qs[w * 4 + 2][d], kd, s[2]);
      s[3] = fmaf(Qs[w * 4 + 3][d], kd, s[3]);
    }
#pragma unroll
    for (int qi = 0; qi < 4; ++qi) {
      float cm = s[qi];
#pragma unroll
      for (int off = 32; off; off >>= 1) cm = fmaxf(cm, __shfl_xor(cm, off));
      const float mn = fmaxf(mr[qi], cm);
      const float p = __expf(s[qi] - mn);
      float cs = p;
#pragma unroll
      for (int off = 32; off; off >>= 1) cs += __shfl_xor(cs, off);
      const float sc = __expf(mr[qi] - mn);
      lr[qi] = lr[qi] * sc + cs;
      orr[qi] *= sc;
      mr[qi] = mn;
      Ps[w * 4 + qi][lane] = p;
    }
    // o update: lane = dim index
#pragma unroll 8
    for (int j = 0; j < CH; ++j) {
      const float vj = Vs[j][lane];
      orr[0] = fmaf(Ps[w * 4 + 0][j], vj, orr[0]);
      orr[1] = fmaf(Ps[w * 4 + 1][j], vj, orr[1]);
      orr[2] = fmaf(Ps[w * 4 + 2][j], vj, orr[2]);
      orr[3] = fmaf(Ps[w * 4 + 3][j], vj, orr[3]);
    }
    __syncthreads();
  }
#pragma unroll
  for (int qi = 0; qi < 4; ++qi) {
    const int r = qt * QB + w * 4 + qi;
    base[(size_t)r * (3 * Dc) + lane] = orr[qi] / lr[qi];
  }
}

// ---------------------------------------------------------------------------
// Router: logits = (h2 @ rw^T)/temp; top-2 threshold; sigmoid suppression;
// softmax(logits * suppression). One block per token.
// ---------------------------------------------------------------------------
__global__ __launch_bounds__(256)
void router_kernel(const float* __restrict__ h2, const float* __restrict__ rw,
                   const float* __restrict__ log_temp, float* __restrict__ wts) {
  const int t = blockIdx.x;
  const int tid = threadIdx.x;
  const float* hr = h2 + (size_t)t * Dc;
  float4 hv = *(const float4*)(hr + tid * 4);
  float part[Ec];
#pragma unroll
  for (int e = 0; e < Ec; ++e) {
    float4 wv = *(const float4*)(rw + (size_t)e * Dc + tid * 4);
    part[e] = hv.x * wv.x + hv.y * wv.y + hv.z * wv.z + hv.w * wv.w;
  }
#pragma unroll
  for (int off = 32; off; off >>= 1) {
#pragma unroll
    for (int e = 0; e < Ec; ++e) part[e] += __shfl_xor(part[e], off);
  }
  __shared__ float red[4][Ec];
  const int w = tid >> 6;
  if ((tid & 63) == 0) {
#pragma unroll
    for (int e = 0; e < Ec; ++e) red[w][e] = part[e];
  }
  __syncthreads();
  if (tid == 0) {
    const float lt = *log_temp;
    const float temp = log1pf(__expf(lt)) + 0.1f;
    float lg[Ec];
#pragma unroll
    for (int e = 0; e < Ec; ++e)
      lg[e] = (red[0][e] + red[1][e] + red[2][e] + red[3][e]) / temp;
    float m1 = -1e30f, m2 = -1e30f;
#pragma unroll
    for (int e = 0; e < Ec; ++e) {
      const float v = lg[e];
      if (v > m1) { m2 = m1; m1 = v; }
      else if (v > m2) { m2 = v; }
    }
    float sl[Ec];
    float mx = -1e30f;
#pragma unroll
    for (int e = 0; e < Ec; ++e) {
      const float sup = 1.f / (1.f + __expf(-10.f * (lg[e] - m2)));
      sl[e] = lg[e] * sup;
      mx = fmaxf(mx, sl[e]);
    }
    float ssum = 0.f;
#pragma unroll
    for (int e = 0; e < Ec; ++e) {
      const float p = __expf(sl[e] - mx);
      sl[e] = p;
      ssum += p;
    }
    const float inv = 1.f / ssum;
#pragma unroll
    for (int e = 0; e < Ec; ++e) wts[(size_t)t * Ec + e] = sl[e] * inv;
  }
}

// ---------------------------------------------------------------------------
// act = silu(hg) * hu * weight[t,e], in place into hg. float4 per thread.
// ---------------------------------------------------------------------------
__global__ __launch_bounds__(256)
void moe_act_kernel(float* __restrict__ hg, const float* __restrict__ hu,
                    const float* __restrict__ wts) {
  const size_t idx = ((size_t)blockIdx.x * 256 + threadIdx.x) * 4;
  const int t = (int)(idx >> 11);        // / 2048
  const int e = (int)((idx >> 8) & 7);   // (idx % 2048) / 256
  const float wgt = wts[(size_t)t * Ec + e];
  float4 a = *(float4*)(hg + idx);
  const float4 u = *(const float4*)(hu + idx);
  float4 r;
  r.x = (a.x / (1.f + __expf(-a.x))) * u.x * wgt;
  r.y = (a.y / (1.f + __expf(-a.y))) * u.y * wgt;
  r.z = (a.z / (1.f + __expf(-a.z))) * u.z * wgt;
  r.w = (a.w / (1.f + __expf(-a.w))) * u.w * wgt;
  *(float4*)(hg + idx) = r;
}

// ---------------------------------------------------------------------------
extern "C" void kernel_launch(void* const* d_in, const int* in_sizes, int n_in,
                              void* d_out, int out_size, void* d_ws, size_t ws_size,
                              hipStream_t stream) {
  (void)in_sizes; (void)n_in; (void)out_size; (void)ws_size;
  const float* x        = (const float*)d_in[0];
  const float* ln1_g    = (const float*)d_in[1];
  const float* ln1_b    = (const float*)d_in[2];
  const float* in_w     = (const float*)d_in[3];
  const float* in_b     = (const float*)d_in[4];
  const float* out_w    = (const float*)d_in[5];
  const float* out_b    = (const float*)d_in[6];
  const float* ln2_g    = (const float*)d_in[7];
  const float* ln2_b    = (const float*)d_in[8];
  const float* rw       = (const float*)d_in[9];
  const float* log_temp = (const float*)d_in[10];
  const float* Wg       = (const float*)d_in[11];
  const float* Wu       = (const float*)d_in[12];
  const float* Wd       = (const float*)d_in[13];
  float* out = (float*)d_out;

  // Workspace layout (floats), total 192.25 MiB (fits 256 MiB ws):
  //   h   [8M]  : 32 MiB   (LN1 out, later reused as LN2 out h2)
  //   qkv [24M] : 96 MiB   (QKV; dead after out-proj -> reused as hg)
  //   hu  [16M] : 64 MiB
  //   wts [64K] : 0.25 MiB
  float* ws  = (float*)d_ws;
  float* h   = ws;
  float* qkv = h + (size_t)NTOK * Dc;
  float* hu  = qkv + (size_t)NTOK * 3 * Dc;
  float* wts = hu + (size_t)NTOK * EDE;
  float* hg  = qkv;  // reuse: qkv is dead after the out-proj GEMM

  const dim3 blk(256);

  // 1. LN1: x -> h
  ln_kernel<<<dim3(NTOK), blk, 0, stream>>>(x, ln1_g, ln1_b, h);
  // 2. QKV: h @ in_w^T + in_b -> qkv [8192, 3072]
  gemm_nt<false><<<dim3(3 * Dc / 128, NTOK / 128), blk, 0, stream>>>(
      h, Dc, in_w, in_b, nullptr, qkv, 3 * Dc, Dc);
  // 3. attention in place (O overwrites Q slot)
  attn_kernel<<<dim3(Bc * Hc * (Tc / 16)), blk, 0, stream>>>(qkv);
  // 4. out proj + bias + residual(x) -> out
  gemm_nt<false><<<dim3(Dc / 128, NTOK / 128), blk, 0, stream>>>(
      qkv, 3 * Dc, out_w, out_b, x, out, Dc, Dc);
  // 5. LN2: out -> h (h2)
  ln_kernel<<<dim3(NTOK), blk, 0, stream>>>(out, ln2_g, ln2_b, h);
  // 6. router weights
  router_kernel<<<dim3(NTOK), blk, 0, stream>>>(h, rw, log_temp, wts);
  // 7. up: h @ Wu^T -> hu [8192, 2048]  (do "up" first: hg aliases qkv,
  //    and qkv's last reader is the out-proj GEMM, already done)
  gemm_nt<false><<<dim3(EDE / 128, NTOK / 128), blk, 0, stream>>>(
      h, Dc, Wu, nullptr, nullptr, hu, EDE, Dc);
  // 8. gate: h @ Wg^T -> hg (over dead qkv)
  gemm_nt<false><<<dim3(EDE / 128, NTOK / 128), blk, 0, stream>>>(
      h, Dc, Wg, nullptr, nullptr, hg, EDE, Dc);
  // 9. act = silu(hg)*hu*w  (in place into hg)
  moe_act_kernel<<<dim3((int)((size_t)NTOK * EDE / 4 / 256)), blk, 0, stream>>>(
      hg, hu, wts);
  // 10. down proj per expert, accumulate into out
  for (int e = 0; e < Ec; ++e) {
    gemm_nt<true><<<dim3(Dc / 128, NTOK / 128), blk, 0, stream>>>(
        hg + e * DEc, EDE, Wd + (size_t)e * Dc * DEc, nullptr, nullptr,
        out, Dc, DEc);
  }
}

// Round 3
// 2673.757 us; speedup vs baseline: 1.8979x; 1.8979x over previous
//
#include <hip/hip_runtime.h>
#include <hip/hip_bf16.h>
#include <cstddef>
#include <cstdint>

// Problem constants (match reference)
constexpr int Bc  = 4;
constexpr int Tc  = 2048;
constexpr int Dc  = 1024;
constexpr int Hc  = 16;
constexpr int DHc = 64;    // head dim
constexpr int Ec  = 8;     // experts
constexpr int DEc = 256;   // expert dim
constexpr int NTOK = Bc * Tc;          // 8192 tokens
constexpr int EDE = Ec * DEc;          // 2048

typedef __attribute__((ext_vector_type(8))) short s8v;   // 8 bf16 (4 VGPRs)
typedef __attribute__((ext_vector_type(4))) float f4v;   // MFMA C/D

__device__ inline ushort f2bf(float f) {  // fp32 -> bf16 bits, RNE
  union { float f; uint32_t u; } v; v.f = f;
  uint32_t r = v.u + 0x7FFFu + ((v.u >> 16) & 1u);
  return (ushort)(r >> 16);
}

// ---------------------------------------------------------------------------
// LayerNorm: one block (256 threads) per row of D=1024
// ---------------------------------------------------------------------------
__global__ __launch_bounds__(256)
void ln_kernel(const float* __restrict__ in, const float* __restrict__ g,
               const float* __restrict__ bt, float* __restrict__ out) {
  const int row = blockIdx.x;
  const int tid = threadIdx.x;
  const float* xr = in + (size_t)row * Dc;
  float4 v = *(const float4*)(xr + tid * 4);
  float s  = v.x + v.y + v.z + v.w;
  float ss = v.x * v.x + v.y * v.y + v.z * v.z + v.w * v.w;
#pragma unroll
  for (int off = 32; off; off >>= 1) {
    s  += __shfl_xor(s, off);
    ss += __shfl_xor(ss, off);
  }
  __shared__ float red[8];
  const int w = tid >> 6;
  if ((tid & 63) == 0) { red[w] = s; red[4 + w] = ss; }
  __syncthreads();
  const float ts  = red[0] + red[1] + red[2] + red[3];
  const float tss = red[4] + red[5] + red[6] + red[7];
  const float mean = ts * (1.0f / Dc);
  const float var  = tss * (1.0f / Dc) - mean * mean;
  const float rstd = rsqrtf(var + 1e-5f);
  float4 gv = *(const float4*)(g + tid * 4);
  float4 bv = *(const float4*)(bt + tid * 4);
  float4 o;
  o.x = (v.x - mean) * rstd * gv.x + bv.x;
  o.y = (v.y - mean) * rstd * gv.y + bv.y;
  o.z = (v.z - mean) * rstd * gv.z + bv.z;
  o.w = (v.w - mean) * rstd * gv.w + bv.w;
  *(float4*)(out + (size_t)row * Dc + tid * 4) = o;
}

// ---------------------------------------------------------------------------
// fp32 GEMM: C[M,N] = A[M,K] @ W[N,K]^T (+bias)(+resid)(+=C if ACC)
// Tile 128x128, BK=16, 256 threads, 8x8 per thread. All dims multiples.
// ---------------------------------------------------------------------------
template <bool ACC>
__global__ __launch_bounds__(256)
void gemm_nt(const float* __restrict__ A, int lda,
             const float* __restrict__ W,     // [N,K] row-major
             const float* __restrict__ bias,  // [N] or null
             const float* __restrict__ resid, // [M,ldc] or null
             float* __restrict__ C, int ldc, int K) {
  __shared__ float As[16][132];
  __shared__ float Bs[16][132];
  const int tid = threadIdx.x;
  const int m0 = blockIdx.y * 128;
  const int n0 = blockIdx.x * 128;
  const int lrow = tid >> 1;
  const int lk = (tid & 1) * 8;
  const float* Ag = A + (size_t)(m0 + lrow) * lda + lk;
  const float* Wg = W + (size_t)(n0 + lrow) * K + lk;
  const int tx = tid & 15, ty = tid >> 4;
  float acc[8][8];
#pragma unroll
  for (int i = 0; i < 8; ++i) {
#pragma unroll
    for (int j = 0; j < 8; ++j) acc[i][j] = 0.f;
  }
  for (int k0 = 0; k0 < K; k0 += 16) {
    float4 a0 = *(const float4*)(Ag + k0);
    float4 a1 = *(const float4*)(Ag + k0 + 4);
    float4 w0 = *(const float4*)(Wg + k0);
    float4 w1 = *(const float4*)(Wg + k0 + 4);
    As[lk + 0][lrow] = a0.x; As[lk + 1][lrow] = a0.y;
    As[lk + 2][lrow] = a0.z; As[lk + 3][lrow] = a0.w;
    As[lk + 4][lrow] = a1.x; As[lk + 5][lrow] = a1.y;
    As[lk + 6][lrow] = a1.z; As[lk + 7][lrow] = a1.w;
    Bs[lk + 0][lrow] = w0.x; Bs[lk + 1][lrow] = w0.y;
    Bs[lk + 2][lrow] = w0.z; Bs[lk + 3][lrow] = w0.w;
    Bs[lk + 4][lrow] = w1.x; Bs[lk + 5][lrow] = w1.y;
    Bs[lk + 6][lrow] = w1.z; Bs[lk + 7][lrow] = w1.w;
    __syncthreads();
#pragma unroll
    for (int kk = 0; kk < 16; ++kk) {
      float4 av0 = *(const float4*)&As[kk][ty * 8];
      float4 av1 = *(const float4*)&As[kk][ty * 8 + 4];
      float4 bv0 = *(const float4*)&Bs[kk][tx * 8];
      float4 bv1 = *(const float4*)&Bs[kk][tx * 8 + 4];
      float a[8]  = {av0.x, av0.y, av0.z, av0.w, av1.x, av1.y, av1.z, av1.w};
      float bb[8] = {bv0.x, bv0.y, bv0.z, bv0.w, bv1.x, bv1.y, bv1.z, bv1.w};
#pragma unroll
      for (int i = 0; i < 8; ++i) {
#pragma unroll
        for (int j = 0; j < 8; ++j) acc[i][j] = fmaf(a[i], bb[j], acc[i][j]);
      }
    }
    __syncthreads();
  }
#pragma unroll
  for (int i = 0; i < 8; ++i) {
    const int r = m0 + ty * 8 + i;
    float* Crow = C + (size_t)r * ldc + n0 + tx * 8;
#pragma unroll
    for (int j = 0; j < 8; ++j) {
      float v = acc[i][j];
      if (bias)  v += bias[n0 + tx * 8 + j];
      if (resid) v += resid[(size_t)r * ldc + n0 + tx * 8 + j];
      if (ACC)   v += Crow[j];
      Crow[j] = v;
    }
  }
}

// ---------------------------------------------------------------------------
// qkv fp32 [NTOK,3072] -> head-major bf16 Q(x0.125),K,V [B*H, T, 64]
// one thread per 8 consecutive elements.
// ---------------------------------------------------------------------------
__global__ __launch_bounds__(256)
void qkv_convert(const float* __restrict__ qkv, ushort* __restrict__ Qb,
                 ushort* __restrict__ Kb, ushort* __restrict__ Vb) {
  const size_t eidx = ((size_t)blockIdx.x * 256 + threadIdx.x) * 8;
  const int tok = (int)(eidx / 3072);
  const int c = (int)(eidx % 3072);
  const int which = c >> 10;          // 0=q 1=k 2=v
  const int r = c & 1023;
  const int h = r >> 6, d = r & 63;
  const float scale = (which == 0) ? 0.125f : 1.0f;
  const float4 a = *(const float4*)(qkv + eidx);
  const float4 b2 = *(const float4*)(qkv + eidx + 4);
  ushort o[8];
  o[0] = f2bf(a.x * scale);  o[1] = f2bf(a.y * scale);
  o[2] = f2bf(a.z * scale);  o[3] = f2bf(a.w * scale);
  o[4] = f2bf(b2.x * scale); o[5] = f2bf(b2.y * scale);
  o[6] = f2bf(b2.z * scale); o[7] = f2bf(b2.w * scale);
  ushort* dst = (which == 0) ? Qb : (which == 1) ? Kb : Vb;
  const int bb = tok >> 11, t = tok & 2047;
  *(s8v*)(dst + ((((size_t)bb * Hc + h) * Tc + t) << 6) + d) = *(const s8v*)o;
}

// ---------------------------------------------------------------------------
// MFMA flash attention. Block = 256 thr (4 waves), 64 q-rows/block (16/wave).
// K/V chunks of 64 in LDS (V transposed at stage time); XOR-swizzled layouts.
// O (fp32) written into the Q slot of qkv (dead after convert).
// ---------------------------------------------------------------------------
__global__ __launch_bounds__(256)
void attn_mfma(const ushort* __restrict__ Qb, const ushort* __restrict__ Kb,
               const ushort* __restrict__ Vb, float* __restrict__ qkv) {
  __shared__ ushort Ksm[64 * 64];   // [key][d]   swizzled
  __shared__ ushort Vtsm[64 * 64];  // [d][key]   swizzled
  __shared__ ushort Psm[4 * 16 * 64];  // per-wave [q][key] swizzled
  const int tid = threadIdx.x;
  const int lane = tid & 63, w = tid >> 6;
  const int g = lane >> 4, c = lane & 15;
  const int bid = blockIdx.x;
  const int qt = bid & 31, bh = bid >> 5;   // consecutive blocks share head
  const ushort* Qh = Qb + (size_t)bh * Tc * 64;
  const ushort* Kh = Kb + (size_t)bh * Tc * 64;
  const ushort* Vh = Vb + (size_t)bh * Tc * 64;
  // Q fragments (A: row=lane&15, k=d=(lane>>4)*8+j, per 32-d half)
  const int qrow = qt * 64 + w * 16 + c;
  s8v qf0 = *(const s8v*)(Qh + (size_t)qrow * 64 + g * 8);
  s8v qf1 = *(const s8v*)(Qh + (size_t)qrow * 64 + 32 + g * 8);
  const f4v fz = {0.f, 0.f, 0.f, 0.f};
  f4v accO[4] = {fz, fz, fz, fz};
  float mold[4] = {-1e30f, -1e30f, -1e30f, -1e30f};
  float lsum[4] = {0.f, 0.f, 0.f, 0.f};
  ushort* Pw = Psm + w * 16 * 64;

  for (int j0 = 0; j0 < Tc; j0 += 64) {
    // stage K [64 keys][64 d], 16B per thread-segment
#pragma unroll
    for (int seg = 0; seg < 2; ++seg) {
      const int idx = seg * 256 + tid;
      const int key = idx >> 3, d0 = (idx & 7) * 8;
      *(s8v*)&Ksm[key * 64 + (d0 ^ ((key & 7) << 3))] =
          *(const s8v*)(Kh + (size_t)(j0 + key) * 64 + d0);
    }
    // stage V transposed -> Vtsm[d][key]
#pragma unroll
    for (int seg = 0; seg < 2; ++seg) {
      const int idx = seg * 256 + tid;
      const int key = idx & 63, d0 = (idx >> 6) * 8;
      s8v v = *(const s8v*)(Vh + (size_t)(j0 + key) * 64 + d0);
#pragma unroll
      for (int j = 0; j < 8; ++j) {
        const int dr = d0 + j;
        Vtsm[dr * 64 + (key ^ ((dr & 7) << 3))] = (ushort)v[j];
      }
    }
    __syncthreads();
    // QK^T: S[16q][64k] as 4 MFMA tiles (D: row=g*4+r, col=c)
    f4v s[4];
#pragma unroll
    for (int kt = 0; kt < 4; ++kt) {
      s[kt] = fz;
#pragma unroll
      for (int hf = 0; hf < 2; ++hf) {
        const int krow = kt * 16 + c;
        const int col0 = hf * 32 + g * 8;
        s8v kf = *(const s8v*)&Ksm[krow * 64 + (col0 ^ ((krow & 7) << 3))];
        s[kt] = __builtin_amdgcn_mfma_f32_16x16x32_bf16(
            hf ? qf1 : qf0, kf, s[kt], 0, 0, 0);
      }
    }
    // online softmax over rows q = g*4+r (16-lane group shares rows)
#pragma unroll
    for (int r = 0; r < 4; ++r) {
      float mx = fmaxf(fmaxf(s[0][r], s[1][r]), fmaxf(s[2][r], s[3][r]));
#pragma unroll
      for (int mk = 1; mk < 16; mk <<= 1) mx = fmaxf(mx, __shfl_xor(mx, mk));
      const float mnew = fmaxf(mold[r], mx);
      const float sc = __expf(mold[r] - mnew);
      mold[r] = mnew;
      float rs = 0.f;
#pragma unroll
      for (int kt = 0; kt < 4; ++kt) {
        const float p = __expf(s[kt][r] - mnew);
        s[kt][r] = p;
        rs += p;
      }
#pragma unroll
      for (int mk = 1; mk < 16; mk <<= 1) rs += __shfl_xor(rs, mk);
      lsum[r] = lsum[r] * sc + rs;
#pragma unroll
      for (int dt = 0; dt < 4; ++dt) accO[dt][r] *= sc;
      const int prow = g * 4 + r;
#pragma unroll
      for (int kt = 0; kt < 4; ++kt) {
        const int pcol = kt * 16 + c;
        Pw[prow * 64 + (pcol ^ ((prow & 7) << 3))] = f2bf(s[kt][r]);
      }
    }
    // PV: O[16q][64d] += P[16,64] @ V[64,64]
#pragma unroll
    for (int kh = 0; kh < 2; ++kh) {
      const int pcol0 = kh * 32 + g * 8;
      s8v pf = *(const s8v*)&Pw[c * 64 + (pcol0 ^ ((c & 7) << 3))];
#pragma unroll
      for (int dt = 0; dt < 4; ++dt) {
        const int vrow = dt * 16 + c;
        s8v vf = *(const s8v*)&Vtsm[vrow * 64 + (pcol0 ^ ((vrow & 7) << 3))];
        accO[dt] = __builtin_amdgcn_mfma_f32_16x16x32_bf16(pf, vf, accO[dt], 0, 0, 0);
      }
    }
    __syncthreads();
  }
  // write O/l (fp32) into Q slot of qkv
  const int h = bh & 15, b = bh >> 4;
#pragma unroll
  for (int r = 0; r < 4; ++r) {
    const int tokr = b * Tc + qt * 64 + w * 16 + g * 4 + r;
    const float inv = 1.f / lsum[r];
    float* orow = qkv + (size_t)tokr * 3072 + h * 64;
#pragma unroll
    for (int dt = 0; dt < 4; ++dt) orow[dt * 16 + c] = accO[dt][r] * inv;
  }
}

// ---------------------------------------------------------------------------
// Router: logits = (h2 @ rw^T)/temp; top-2 threshold; sigmoid suppression;
// softmax(logits * suppression). One block per token.
// ---------------------------------------------------------------------------
__global__ __launch_bounds__(256)
void router_kernel(const float* __restrict__ h2, const float* __restrict__ rw,
                   const float* __restrict__ log_temp, float* __restrict__ wts) {
  const int t = blockIdx.x;
  const int tid = threadIdx.x;
  const float* hr = h2 + (size_t)t * Dc;
  float4 hv = *(const float4*)(hr + tid * 4);
  float part[Ec];
#pragma unroll
  for (int e = 0; e < Ec; ++e) {
    float4 wv = *(const float4*)(rw + (size_t)e * Dc + tid * 4);
    part[e] = hv.x * wv.x + hv.y * wv.y + hv.z * wv.z + hv.w * wv.w;
  }
#pragma unroll
  for (int off = 32; off; off >>= 1) {
#pragma unroll
    for (int e = 0; e < Ec; ++e) part[e] += __shfl_xor(part[e], off);
  }
  __shared__ float red[4][Ec];
  const int w = tid >> 6;
  if ((tid & 63) == 0) {
#pragma unroll
    for (int e = 0; e < Ec; ++e) red[w][e] = part[e];
  }
  __syncthreads();
  if (tid == 0) {
    const float lt = *log_temp;
    const float temp = log1pf(__expf(lt)) + 0.1f;
    float lg[Ec];
#pragma unroll
    for (int e = 0; e < Ec; ++e)
      lg[e] = (red[0][e] + red[1][e] + red[2][e] + red[3][e]) / temp;
    float m1 = -1e30f, m2 = -1e30f;
#pragma unroll
    for (int e = 0; e < Ec; ++e) {
      const float v = lg[e];
      if (v > m1) { m2 = m1; m1 = v; }
      else if (v > m2) { m2 = v; }
    }
    float sl[Ec];
    float mx = -1e30f;
#pragma unroll
    for (int e = 0; e < Ec; ++e) {
      const float sup = 1.f / (1.f + __expf(-10.f * (lg[e] - m2)));
      sl[e] = lg[e] * sup;
      mx = fmaxf(mx, sl[e]);
    }
    float ssum = 0.f;
#pragma unroll
    for (int e = 0; e < Ec; ++e) {
      const float p = __expf(sl[e] - mx);
      sl[e] = p;
      ssum += p;
    }
    const float inv = 1.f / ssum;
#pragma unroll
    for (int e = 0; e < Ec; ++e) wts[(size_t)t * Ec + e] = sl[e] * inv;
  }
}

// ---------------------------------------------------------------------------
// act = silu(hg) * hu * weight[t,e], in place into hg. float4 per thread.
// ---------------------------------------------------------------------------
__global__ __launch_bounds__(256)
void moe_act_kernel(float* __restrict__ hg, const float* __restrict__ hu,
                    const float* __restrict__ wts) {
  const size_t idx = ((size_t)blockIdx.x * 256 + threadIdx.x) * 4;
  const int t = (int)(idx >> 11);        // / 2048
  const int e = (int)((idx >> 8) & 7);   // (idx % 2048) / 256
  const float wgt = wts[(size_t)t * Ec + e];
  float4 a = *(float4*)(hg + idx);
  const float4 u = *(const float4*)(hu + idx);
  float4 r;
  r.x = (a.x / (1.f + __expf(-a.x))) * u.x * wgt;
  r.y = (a.y / (1.f + __expf(-a.y))) * u.y * wgt;
  r.z = (a.z / (1.f + __expf(-a.z))) * u.z * wgt;
  r.w = (a.w / (1.f + __expf(-a.w))) * u.w * wgt;
  *(float4*)(hg + idx) = r;
}

// ---------------------------------------------------------------------------
extern "C" void kernel_launch(void* const* d_in, const int* in_sizes, int n_in,
                              void* d_out, int out_size, void* d_ws, size_t ws_size,
                              hipStream_t stream) {
  (void)in_sizes; (void)n_in; (void)out_size; (void)ws_size;
  const float* x        = (const float*)d_in[0];
  const float* ln1_g    = (const float*)d_in[1];
  const float* ln1_b    = (const float*)d_in[2];
  const float* in_w     = (const float*)d_in[3];
  const float* in_b     = (const float*)d_in[4];
  const float* out_w    = (const float*)d_in[5];
  const float* out_b    = (const float*)d_in[6];
  const float* ln2_g    = (const float*)d_in[7];
  const float* ln2_b    = (const float*)d_in[8];
  const float* rw       = (const float*)d_in[9];
  const float* log_temp = (const float*)d_in[10];
  const float* Wg       = (const float*)d_in[11];
  const float* Wu       = (const float*)d_in[12];
  const float* Wd       = (const float*)d_in[13];
  float* out = (float*)d_out;

  // Workspace layout (floats), total 192.25 MiB (same as passing round 2):
  //   h   [8M]  : 32 MiB
  //   qkv [24M] : 96 MiB   (dead after out-proj -> reused as hg)
  //   hu  [16M] : 64 MiB   (dead until MoE -> holds bf16 Q/K/V, 50.3 MiB)
  //   wts [64K] : 0.25 MiB
  float* ws  = (float*)d_ws;
  float* h   = ws;
  float* qkv = h + (size_t)NTOK * Dc;
  float* hu  = qkv + (size_t)NTOK * 3 * Dc;
  float* wts = hu + (size_t)NTOK * EDE;
  float* hg  = qkv;                       // reuse
  ushort* Qb = (ushort*)hu;               // bf16 region overlaps hu
  ushort* Kb = Qb + (size_t)NTOK * Dc;    // each buffer: B*H*T*64 = NTOK*1024
  ushort* Vb = Kb + (size_t)NTOK * Dc;

  const dim3 blk(256);

  // 1. LN1: x -> h
  ln_kernel<<<dim3(NTOK), blk, 0, stream>>>(x, ln1_g, ln1_b, h);
  // 2. QKV: h @ in_w^T + in_b -> qkv [8192, 3072]
  gemm_nt<false><<<dim3(3 * Dc / 128, NTOK / 128), blk, 0, stream>>>(
      h, Dc, in_w, in_b, nullptr, qkv, 3 * Dc, Dc);
  // 2.5 convert to head-major bf16 (Q pre-scaled by 1/8)
  qkv_convert<<<dim3(NTOK * 3072 / 8 / 256), blk, 0, stream>>>(qkv, Qb, Kb, Vb);
  // 3. MFMA attention; O (fp32) overwrites Q slot of qkv
  attn_mfma<<<dim3(Bc * Hc * (Tc / 64)), blk, 0, stream>>>(Qb, Kb, Vb, qkv);
  // 4. out proj + bias + residual(x) -> out
  gemm_nt<false><<<dim3(Dc / 128, NTOK / 128), blk, 0, stream>>>(
      qkv, 3 * Dc, out_w, out_b, x, out, Dc, Dc);
  // 5. LN2: out -> h (h2)
  ln_kernel<<<dim3(NTOK), blk, 0, stream>>>(out, ln2_g, ln2_b, h);
  // 6. router weights
  router_kernel<<<dim3(NTOK), blk, 0, stream>>>(h, rw, log_temp, wts);
  // 7. up: h @ Wu^T -> hu [8192, 2048]  (bf16 q/k/v dead now)
  gemm_nt<false><<<dim3(EDE / 128, NTOK / 128), blk, 0, stream>>>(
      h, Dc, Wu, nullptr, nullptr, hu, EDE, Dc);
  // 8. gate: h @ Wg^T -> hg (over dead qkv)
  gemm_nt<false><<<dim3(EDE / 128, NTOK / 128), blk, 0, stream>>>(
      h, Dc, Wg, nullptr, nullptr, hg, EDE, Dc);
  // 9. act = silu(hg)*hu*w  (in place into hg)
  moe_act_kernel<<<dim3((int)((size_t)NTOK * EDE / 4 / 256)), blk, 0, stream>>>(
      hg, hu, wts);
  // 10. down proj per expert, accumulate into out
  for (int e = 0; e < Ec; ++e) {
    gemm_nt<true><<<dim3(Dc / 128, NTOK / 128), blk, 0, stream>>>(
        hg + e * DEc, EDE, Wd + (size_t)e * Dc * DEc, nullptr, nullptr,
        out, Dc, DEc);
  }
}

// Round 4
// 617.877 us; speedup vs baseline: 8.2128x; 4.3273x over previous
//
#include <hip/hip_runtime.h>
#include <hip/hip_bf16.h>
#include <cstddef>
#include <cstdint>

// Problem constants (match reference)
constexpr int Bc  = 4;
constexpr int Tc  = 2048;
constexpr int Dc  = 1024;
constexpr int Hc  = 16;
constexpr int DHc = 64;    // head dim
constexpr int Ec  = 8;     // experts
constexpr int DEc = 256;   // expert dim
constexpr int NTOK = Bc * Tc;          // 8192 tokens
constexpr int EDE = Ec * DEc;          // 2048

typedef __attribute__((ext_vector_type(8))) short  s8v;   // 8 bf16 (4 VGPRs)
typedef __attribute__((ext_vector_type(4))) float  f4v;   // MFMA C/D
typedef __attribute__((ext_vector_type(8))) ushort u8v;
typedef __attribute__((ext_vector_type(4))) ushort u4v;

__device__ inline ushort f2bf(float f) {  // fp32 -> bf16 bits, RNE
  union { float f; uint32_t u; } v; v.f = f;
  uint32_t r = v.u + 0x7FFFu + ((v.u >> 16) & 1u);
  return (ushort)(r >> 16);
}
__device__ inline float bf2f(ushort u) {
  union { uint32_t u; float f; } v; v.u = ((uint32_t)u) << 16;
  return v.f;
}

// async global->LDS, 16B per lane; LDS dest must be wave-uniform + lane*16
#define GLOAD_LDS(gsrc, ldst)                                        \
  __builtin_amdgcn_global_load_lds(                                  \
      (const __attribute__((address_space(1))) void*)(gsrc),         \
      (__attribute__((address_space(3))) void*)(ldst), 16, 0, 0)

// ---------------------------------------------------------------------------
// fp32 -> bf16 flat convert (weights); n multiple of 2048
// ---------------------------------------------------------------------------
__global__ __launch_bounds__(256)
void f32_to_bf16(const float* __restrict__ src, ushort* __restrict__ dst) {
  const size_t i = ((size_t)blockIdx.x * 256 + threadIdx.x) * 8;
  const float4 a = *(const float4*)(src + i);
  const float4 b = *(const float4*)(src + i + 4);
  u8v o;
  o[0] = f2bf(a.x); o[1] = f2bf(a.y); o[2] = f2bf(a.z); o[3] = f2bf(a.w);
  o[4] = f2bf(b.x); o[5] = f2bf(b.y); o[6] = f2bf(b.z); o[7] = f2bf(b.w);
  *(u8v*)(dst + i) = o;
}

// Wd [E,D,DE] fp32 -> Wdb [D, E*DE] bf16  (Wdb[d][e*256+f] = Wd[e][d][f])
__global__ __launch_bounds__(256)
void wd_reorder(const float* __restrict__ Wd, ushort* __restrict__ Wdb) {
  const size_t i = ((size_t)blockIdx.x * 256 + threadIdx.x) * 8;
  const int e = (int)(i >> 18);            // /(1024*256)
  const int d = (int)((i >> 8) & 1023);
  const int f = (int)(i & 255);
  const float4 a = *(const float4*)(Wd + i);
  const float4 b = *(const float4*)(Wd + i + 4);
  u8v o;
  o[0] = f2bf(a.x); o[1] = f2bf(a.y); o[2] = f2bf(a.z); o[3] = f2bf(a.w);
  o[4] = f2bf(b.x); o[5] = f2bf(b.y); o[6] = f2bf(b.z); o[7] = f2bf(b.w);
  *(u8v*)(Wdb + (size_t)d * EDE + e * DEc + f) = o;
}

// ---------------------------------------------------------------------------
// LayerNorm: one block (256 threads) per row of D=1024; bf16 output
// ---------------------------------------------------------------------------
__global__ __launch_bounds__(256)
void ln_kernel(const float* __restrict__ in, const float* __restrict__ g,
               const float* __restrict__ bt, ushort* __restrict__ out) {
  const int row = blockIdx.x;
  const int tid = threadIdx.x;
  const float* xr = in + (size_t)row * Dc;
  float4 v = *(const float4*)(xr + tid * 4);
  float s  = v.x + v.y + v.z + v.w;
  float ss = v.x * v.x + v.y * v.y + v.z * v.z + v.w * v.w;
#pragma unroll
  for (int off = 32; off; off >>= 1) {
    s  += __shfl_xor(s, off);
    ss += __shfl_xor(ss, off);
  }
  __shared__ float red[8];
  const int w = tid >> 6;
  if ((tid & 63) == 0) { red[w] = s; red[4 + w] = ss; }
  __syncthreads();
  const float ts  = red[0] + red[1] + red[2] + red[3];
  const float tss = red[4] + red[5] + red[6] + red[7];
  const float mean = ts * (1.0f / Dc);
  const float var  = tss * (1.0f / Dc) - mean * mean;
  const float rstd = rsqrtf(var + 1e-5f);
  float4 gv = *(const float4*)(g + tid * 4);
  float4 bv = *(const float4*)(bt + tid * 4);
  u4v o;
  o[0] = f2bf((v.x - mean) * rstd * gv.x + bv.x);
  o[1] = f2bf((v.y - mean) * rstd * gv.y + bv.y);
  o[2] = f2bf((v.z - mean) * rstd * gv.z + bv.z);
  o[3] = f2bf((v.w - mean) * rstd * gv.w + bv.w);
  *(u4v*)(out + (size_t)row * Dc + tid * 4) = o;
}

// ---------------------------------------------------------------------------
// bf16 MFMA GEMM: C[M,N] = A[M,K] @ B[N,K]^T, m97 structure.
// 128x128 tile, BK=32, 256 thr = 4 waves (2x2), 4x4 frags of 16x16x32/wave.
// LDS linear for global_load_lds; source pre-swizzled; reads XOR-swizzled.
// EPI: 0 = QKV scatter bf16 (bias, q*0.125)   1 = fp32 +bias+resid
//      2 = bf16 plain                          3 = fp32 accumulate
// ---------------------------------------------------------------------------
template <int EPI>
__global__ __launch_bounds__(256)
void gemm_bf16(const ushort* __restrict__ A, const ushort* __restrict__ B,
               const float* __restrict__ bias, const float* __restrict__ resid,
               void* __restrict__ Cout, int ldc, int K) {
  __shared__ __align__(16) ushort As[128 * 32];
  __shared__ __align__(16) ushort Bs[128 * 32];
  const int tid = threadIdx.x;
  const int lane = tid & 63, w = tid >> 6;
  const int g = lane >> 4, c = lane & 15;
  const int m0 = blockIdx.y * 128, n0 = blockIdx.x * 128;
  const int wm = (w >> 1) * 64, wn = (w & 1) * 64;
  const f4v fz = {0.f, 0.f, 0.f, 0.f};
  f4v acc[4][4];
#pragma unroll
  for (int i = 0; i < 4; ++i)
#pragma unroll
    for (int j = 0; j < 4; ++j) acc[i][j] = fz;

  // staging chunk constants (ci = seg*256 + tid)
  int srow[2], skoff[2];
#pragma unroll
  for (int seg = 0; seg < 2; ++seg) {
    const int ci = seg * 256 + tid;
    srow[seg] = ci >> 2;
    skoff[seg] = 8 * ((ci & 3) ^ ((srow[seg] >> 1) & 3));
  }

  for (int k0 = 0; k0 < K; k0 += 32) {
#pragma unroll
    for (int seg = 0; seg < 2; ++seg) {
      const int ci = seg * 256 + tid;
      GLOAD_LDS(A + (size_t)(m0 + srow[seg]) * K + k0 + skoff[seg], &As[ci * 8]);
      GLOAD_LDS(B + (size_t)(n0 + srow[seg]) * K + k0 + skoff[seg], &Bs[ci * 8]);
    }
    __syncthreads();
    s8v af[4], bf[4];
#pragma unroll
    for (int mi = 0; mi < 4; ++mi) {
      const int R = wm + mi * 16 + c;
      af[mi] = *(const s8v*)&As[R * 32 + 8 * (g ^ ((R >> 1) & 3))];
    }
#pragma unroll
    for (int ni = 0; ni < 4; ++ni) {
      const int R = wn + ni * 16 + c;
      bf[ni] = *(const s8v*)&Bs[R * 32 + 8 * (g ^ ((R >> 1) & 3))];
    }
#pragma unroll
    for (int mi = 0; mi < 4; ++mi)
#pragma unroll
      for (int ni = 0; ni < 4; ++ni)
        acc[mi][ni] = __builtin_amdgcn_mfma_f32_16x16x32_bf16(
            af[mi], bf[ni], acc[mi][ni], 0, 0, 0);
    __syncthreads();
  }

  // epilogue: C/D layout col=lane&15, row=(lane>>4)*4+reg  [m89-verified]
#pragma unroll
  for (int mi = 0; mi < 4; ++mi) {
#pragma unroll
    for (int ni = 0; ni < 4; ++ni) {
#pragma unroll
      for (int j = 0; j < 4; ++j) {
        const int row = m0 + wm + mi * 16 + g * 4 + j;
        const int col = n0 + wn + ni * 16 + c;
        float v = acc[mi][ni][j];
        if constexpr (EPI == 0) {  // QKV scatter
          v += bias[col];
          const int which = col >> 10, hh = (col >> 6) & 15, d = col & 63;
          if (which == 0) v *= 0.125f;
          const int b = row >> 11, t = row & 2047;
          ((ushort*)Cout)[(size_t)which * ((size_t)NTOK * Dc) +
                          ((((size_t)b * Hc + hh) * Tc + t) << 6) + d] = f2bf(v);
        } else if constexpr (EPI == 1) {  // fp32 + bias + resid
          v += bias[col] + resid[(size_t)row * ldc + col];
          ((float*)Cout)[(size_t)row * ldc + col] = v;
        } else if constexpr (EPI == 2) {  // bf16 plain
          ((ushort*)Cout)[(size_t)row * ldc + col] = f2bf(v);
        } else {  // fp32 accumulate
          ((float*)Cout)[(size_t)row * ldc + col] += v;
        }
      }
    }
  }
}

// ---------------------------------------------------------------------------
// MFMA flash attention. Block = 256 thr (4 waves), 64 q-rows/block (16/wave).
// K/V chunks of 64 in LDS (V transposed at stage time); XOR-swizzled layouts.
// O written bf16 to Ob [NTOK, 1024] (col = h*64 + d).
// ---------------------------------------------------------------------------
__global__ __launch_bounds__(256)
void attn_mfma(const ushort* __restrict__ Qb, const ushort* __restrict__ Kb,
               const ushort* __restrict__ Vb, ushort* __restrict__ Ob) {
  __shared__ ushort Ksm[64 * 64];   // [key][d]   swizzled
  __shared__ ushort Vtsm[64 * 64];  // [d][key]   swizzled
  __shared__ ushort Psm[4 * 16 * 64];  // per-wave [q][key] swizzled
  const int tid = threadIdx.x;
  const int lane = tid & 63, w = tid >> 6;
  const int g = lane >> 4, c = lane & 15;
  const int bid = blockIdx.x;
  const int qt = bid & 31, bh = bid >> 5;   // consecutive blocks share head
  const ushort* Qh = Qb + (size_t)bh * Tc * 64;
  const ushort* Kh = Kb + (size_t)bh * Tc * 64;
  const ushort* Vh = Vb + (size_t)bh * Tc * 64;
  const int qrow = qt * 64 + w * 16 + c;
  s8v qf0 = *(const s8v*)(Qh + (size_t)qrow * 64 + g * 8);
  s8v qf1 = *(const s8v*)(Qh + (size_t)qrow * 64 + 32 + g * 8);
  const f4v fz = {0.f, 0.f, 0.f, 0.f};
  f4v accO[4] = {fz, fz, fz, fz};
  float mold[4] = {-1e30f, -1e30f, -1e30f, -1e30f};
  float lsum[4] = {0.f, 0.f, 0.f, 0.f};
  ushort* Pw = Psm + w * 16 * 64;

  for (int j0 = 0; j0 < Tc; j0 += 64) {
#pragma unroll
    for (int seg = 0; seg < 2; ++seg) {
      const int idx = seg * 256 + tid;
      const int key = idx >> 3, d0 = (idx & 7) * 8;
      *(s8v*)&Ksm[key * 64 + (d0 ^ ((key & 7) << 3))] =
          *(const s8v*)(Kh + (size_t)(j0 + key) * 64 + d0);
    }
#pragma unroll
    for (int seg = 0; seg < 2; ++seg) {
      const int idx = seg * 256 + tid;
      const int key = idx & 63, d0 = (idx >> 6) * 8;
      s8v v = *(const s8v*)(Vh + (size_t)(j0 + key) * 64 + d0);
#pragma unroll
      for (int j = 0; j < 8; ++j) {
        const int dr = d0 + j;
        Vtsm[dr * 64 + (key ^ ((dr & 7) << 3))] = (ushort)v[j];
      }
    }
    __syncthreads();
    f4v s[4];
#pragma unroll
    for (int kt = 0; kt < 4; ++kt) {
      s[kt] = fz;
#pragma unroll
      for (int hf = 0; hf < 2; ++hf) {
        const int krow = kt * 16 + c;
        const int col0 = hf * 32 + g * 8;
        s8v kf = *(const s8v*)&Ksm[krow * 64 + (col0 ^ ((krow & 7) << 3))];
        s[kt] = __builtin_amdgcn_mfma_f32_16x16x32_bf16(
            hf ? qf1 : qf0, kf, s[kt], 0, 0, 0);
      }
    }
#pragma unroll
    for (int r = 0; r < 4; ++r) {
      float mx = fmaxf(fmaxf(s[0][r], s[1][r]), fmaxf(s[2][r], s[3][r]));
#pragma unroll
      for (int mk = 1; mk < 16; mk <<= 1) mx = fmaxf(mx, __shfl_xor(mx, mk));
      const float mnew = fmaxf(mold[r], mx);
      const float sc = __expf(mold[r] - mnew);
      mold[r] = mnew;
      float rs = 0.f;
#pragma unroll
      for (int kt = 0; kt < 4; ++kt) {
        const float p = __expf(s[kt][r] - mnew);
        s[kt][r] = p;
        rs += p;
      }
#pragma unroll
      for (int mk = 1; mk < 16; mk <<= 1) rs += __shfl_xor(rs, mk);
      lsum[r] = lsum[r] * sc + rs;
#pragma unroll
      for (int dt = 0; dt < 4; ++dt) accO[dt][r] *= sc;
      const int prow = g * 4 + r;
#pragma unroll
      for (int kt = 0; kt < 4; ++kt) {
        const int pcol = kt * 16 + c;
        Pw[prow * 64 + (pcol ^ ((prow & 7) << 3))] = f2bf(s[kt][r]);
      }
    }
#pragma unroll
    for (int kh = 0; kh < 2; ++kh) {
      const int pcol0 = kh * 32 + g * 8;
      s8v pf = *(const s8v*)&Pw[c * 64 + (pcol0 ^ ((c & 7) << 3))];
#pragma unroll
      for (int dt = 0; dt < 4; ++dt) {
        const int vrow = dt * 16 + c;
        s8v vf = *(const s8v*)&Vtsm[vrow * 64 + (pcol0 ^ ((vrow & 7) << 3))];
        accO[dt] = __builtin_amdgcn_mfma_f32_16x16x32_bf16(pf, vf, accO[dt], 0, 0, 0);
      }
    }
    __syncthreads();
  }
  const int h = bh & 15, b = bh >> 4;
#pragma unroll
  for (int r = 0; r < 4; ++r) {
    const int tokr = b * Tc + qt * 64 + w * 16 + g * 4 + r;
    const float inv = 1.f / lsum[r];
    ushort* orow = Ob + (size_t)tokr * Dc + h * 64;
#pragma unroll
    for (int dt = 0; dt < 4; ++dt) orow[dt * 16 + c] = f2bf(accO[dt][r] * inv);
  }
}

// ---------------------------------------------------------------------------
// Router: logits = (h2 @ rw^T)/temp; top-2 threshold; sigmoid suppression;
// softmax(logits * suppression). One block per token. h2 is bf16.
// ---------------------------------------------------------------------------
__global__ __launch_bounds__(256)
void router_kernel(const ushort* __restrict__ h2, const float* __restrict__ rw,
                   const float* __restrict__ log_temp, float* __restrict__ wts) {
  const int t = blockIdx.x;
  const int tid = threadIdx.x;
  const ushort* hr = h2 + (size_t)t * Dc;
  u4v hb = *(const u4v*)(hr + tid * 4);
  const float h0 = bf2f(hb[0]), h1 = bf2f(hb[1]), h2v = bf2f(hb[2]), h3 = bf2f(hb[3]);
  float part[Ec];
#pragma unroll
  for (int e = 0; e < Ec; ++e) {
    float4 wv = *(const float4*)(rw + (size_t)e * Dc + tid * 4);
    part[e] = h0 * wv.x + h1 * wv.y + h2v * wv.z + h3 * wv.w;
  }
#pragma unroll
  for (int off = 32; off; off >>= 1) {
#pragma unroll
    for (int e = 0; e < Ec; ++e) part[e] += __shfl_xor(part[e], off);
  }
  __shared__ float red[4][Ec];
  const int w = tid >> 6;
  if ((tid & 63) == 0) {
#pragma unroll
    for (int e = 0; e < Ec; ++e) red[w][e] = part[e];
  }
  __syncthreads();
  if (tid == 0) {
    const float lt = *log_temp;
    const float temp = log1pf(__expf(lt)) + 0.1f;
    float lg[Ec];
#pragma unroll
    for (int e = 0; e < Ec; ++e)
      lg[e] = (red[0][e] + red[1][e] + red[2][e] + red[3][e]) / temp;
    float m1 = -1e30f, m2 = -1e30f;
#pragma unroll
    for (int e = 0; e < Ec; ++e) {
      const float v = lg[e];
      if (v > m1) { m2 = m1; m1 = v; }
      else if (v > m2) { m2 = v; }
    }
    float sl[Ec];
    float mx = -1e30f;
#pragma unroll
    for (int e = 0; e < Ec; ++e) {
      const float sup = 1.f / (1.f + __expf(-10.f * (lg[e] - m2)));
      sl[e] = lg[e] * sup;
      mx = fmaxf(mx, sl[e]);
    }
    float ssum = 0.f;
#pragma unroll
    for (int e = 0; e < Ec; ++e) {
      const float p = __expf(sl[e] - mx);
      sl[e] = p;
      ssum += p;
    }
    const float inv = 1.f / ssum;
#pragma unroll
    for (int e = 0; e < Ec; ++e) wts[(size_t)t * Ec + e] = sl[e] * inv;
  }
}

// ---------------------------------------------------------------------------
// act = silu(hg) * hu * weight[t,e], bf16 in/out, in place into hg.
// ---------------------------------------------------------------------------
__global__ __launch_bounds__(256)
void moe_act_kernel(ushort* __restrict__ hg, const ushort* __restrict__ hu,
                    const float* __restrict__ wts) {
  const size_t idx = ((size_t)blockIdx.x * 256 + threadIdx.x) * 8;
  const int t = (int)(idx >> 11);        // / 2048
  const int e = (int)((idx >> 8) & 7);   // (idx % 2048) / 256
  const float wgt = wts[(size_t)t * Ec + e];
  u8v a = *(const u8v*)(hg + idx);
  u8v u = *(const u8v*)(hu + idx);
  u8v r;
#pragma unroll
  for (int j = 0; j < 8; ++j) {
    const float av = bf2f(a[j]), uv = bf2f(u[j]);
    r[j] = f2bf((av / (1.f + __expf(-av))) * uv * wgt);
  }
  *(u8v*)(hg + idx) = r;
}

// ---------------------------------------------------------------------------
extern "C" void kernel_launch(void* const* d_in, const int* in_sizes, int n_in,
                              void* d_out, int out_size, void* d_ws, size_t ws_size,
                              hipStream_t stream) {
  (void)in_sizes; (void)n_in; (void)out_size; (void)ws_size;
  const float* x        = (const float*)d_in[0];
  const float* ln1_g    = (const float*)d_in[1];
  const float* ln1_b    = (const float*)d_in[2];
  const float* in_w     = (const float*)d_in[3];
  const float* in_b     = (const float*)d_in[4];
  const float* out_w    = (const float*)d_in[5];
  const float* out_b    = (const float*)d_in[6];
  const float* ln2_g    = (const float*)d_in[7];
  const float* ln2_b    = (const float*)d_in[8];
  const float* rw       = (const float*)d_in[9];
  const float* log_temp = (const float*)d_in[10];
  const float* Wg       = (const float*)d_in[11];
  const float* Wu       = (const float*)d_in[12];
  const float* Wd       = (const float*)d_in[13];
  float* out = (float*)d_out;

  // Workspace (ushorts, all 2MB-multiple offsets), total ~164.3 MiB:
  ushort* h_bf   = (ushort*)d_ws;                       // NTOK*1024   16 MiB
  ushort* Qb     = h_bf   + (size_t)NTOK * Dc;          // 16 MiB
  ushort* Kb     = Qb     + (size_t)NTOK * Dc;          // 16 MiB
  ushort* Vb     = Kb     + (size_t)NTOK * Dc;          // 16 MiB
  ushort* Ob     = Vb     + (size_t)NTOK * Dc;          // 16 MiB
  ushort* hg     = Ob     + (size_t)NTOK * Dc;          // NTOK*2048   32 MiB
  ushort* hu     = hg     + (size_t)NTOK * EDE;         // 32 MiB
  ushort* wb_in  = hu     + (size_t)NTOK * EDE;         // 3072*1024    6 MiB
  ushort* wb_out = wb_in  + (size_t)3 * Dc * Dc;        // 1024*1024    2 MiB
  ushort* wb_g   = wb_out + (size_t)Dc * Dc;            // 2048*1024    4 MiB
  ushort* wb_u   = wb_g   + (size_t)EDE * Dc;           // 4 MiB
  ushort* wb_d   = wb_u   + (size_t)EDE * Dc;           // 1024*2048    4 MiB
  float*  wts    = (float*)(wb_d + (size_t)Dc * EDE);   // NTOK*8     0.25 MiB

  const dim3 blk(256);

  // 0. weight conversions (every call; deterministic)
  f32_to_bf16<<<dim3(3 * Dc * Dc / 2048), blk, 0, stream>>>(in_w, wb_in);
  f32_to_bf16<<<dim3(Dc * Dc / 2048), blk, 0, stream>>>(out_w, wb_out);
  f32_to_bf16<<<dim3(EDE * Dc / 2048), blk, 0, stream>>>(Wg, wb_g);
  f32_to_bf16<<<dim3(EDE * Dc / 2048), blk, 0, stream>>>(Wu, wb_u);
  wd_reorder<<<dim3(Ec * Dc * DEc / 2048), blk, 0, stream>>>(Wd, wb_d);

  // 1. LN1: x -> h_bf (bf16)
  ln_kernel<<<dim3(NTOK), blk, 0, stream>>>(x, ln1_g, ln1_b, h_bf);
  // 2. QKV GEMM -> head-major bf16 Q(x0.125)/K/V directly
  gemm_bf16<0><<<dim3(3 * Dc / 128, NTOK / 128), blk, 0, stream>>>(
      h_bf, wb_in, in_b, nullptr, Qb, 0, Dc);
  // 3. MFMA attention -> Ob bf16
  attn_mfma<<<dim3(Bc * Hc * (Tc / 64)), blk, 0, stream>>>(Qb, Kb, Vb, Ob);
  // 4. out proj + bias + residual(x) -> out fp32
  gemm_bf16<1><<<dim3(Dc / 128, NTOK / 128), blk, 0, stream>>>(
      Ob, wb_out, out_b, x, out, Dc, Dc);
  // 5. LN2: out -> h_bf (h2)
  ln_kernel<<<dim3(NTOK), blk, 0, stream>>>(out, ln2_g, ln2_b, h_bf);
  // 6. router weights
  router_kernel<<<dim3(NTOK), blk, 0, stream>>>(h_bf, rw, log_temp, wts);
  // 7. gate / up GEMMs -> bf16
  gemm_bf16<2><<<dim3(EDE / 128, NTOK / 128), blk, 0, stream>>>(
      h_bf, wb_g, nullptr, nullptr, hg, EDE, Dc);
  gemm_bf16<2><<<dim3(EDE / 128, NTOK / 128), blk, 0, stream>>>(
      h_bf, wb_u, nullptr, nullptr, hu, EDE, Dc);
  // 8. act = silu(hg)*hu*w (bf16, in place)
  moe_act_kernel<<<dim3((int)((size_t)NTOK * EDE / 8 / 256)), blk, 0, stream>>>(
      hg, hu, wts);
  // 9. single down GEMM over concatenated experts, K=2048, += into out
  gemm_bf16<3><<<dim3(Dc / 128, NTOK / 128), blk, 0, stream>>>(
      hg, wb_d, nullptr, nullptr, out, Dc, EDE);
}

// Round 5
// 583.048 us; speedup vs baseline: 8.7034x; 1.0597x over previous
//
#include <hip/hip_runtime.h>
#include <hip/hip_bf16.h>
#include <cstddef>
#include <cstdint>

// Problem constants (match reference)
constexpr int Bc  = 4;
constexpr int Tc  = 2048;
constexpr int Dc  = 1024;
constexpr int Hc  = 16;
constexpr int DHc = 64;    // head dim
constexpr int Ec  = 8;     // experts
constexpr int DEc = 256;   // expert dim
constexpr int NTOK = Bc * Tc;          // 8192 tokens
constexpr int EDE = Ec * DEc;          // 2048

typedef __attribute__((ext_vector_type(8))) short  s8v;   // 8 bf16 (4 VGPRs)
typedef __attribute__((ext_vector_type(4))) float  f4v;   // MFMA C/D
typedef __attribute__((ext_vector_type(8))) ushort u8v;
typedef __attribute__((ext_vector_type(4))) ushort u4v;

__device__ inline ushort f2bf(float f) {  // fp32 -> bf16 bits, RNE
  union { float f; uint32_t u; } v; v.f = f;
  uint32_t r = v.u + 0x7FFFu + ((v.u >> 16) & 1u);
  return (ushort)(r >> 16);
}
__device__ inline float bf2f(ushort u) {
  union { uint32_t u; float f; } v; v.u = ((uint32_t)u) << 16;
  return v.f;
}

// async global->LDS, 16B per lane; LDS dest must be wave-uniform + lane*16
#define GLOAD_LDS(gsrc, ldst)                                        \
  __builtin_amdgcn_global_load_lds(                                  \
      (const __attribute__((address_space(1))) void*)(gsrc),         \
      (__attribute__((address_space(3))) void*)(ldst), 16, 0, 0)

// ds_read_b64_tr_b16: per-lane gather of 4 bf16 at element-stride 16
// (byte-stride 32) starting at the lane's own LDS address. [m156/m162 model]
__device__ inline u4v ds_tr16(const ushort* p) {
  u4v r;
  asm volatile("ds_read_b64_tr_b16 %0, %1"
               : "=v"(r)
               : "v"((const __attribute__((address_space(3))) ushort*)p));
  return r;
}

// ---------------------------------------------------------------------------
// fp32 -> bf16 flat convert (weights); n multiple of 2048
// ---------------------------------------------------------------------------
__global__ __launch_bounds__(256)
void f32_to_bf16(const float* __restrict__ src, ushort* __restrict__ dst) {
  const size_t i = ((size_t)blockIdx.x * 256 + threadIdx.x) * 8;
  const float4 a = *(const float4*)(src + i);
  const float4 b = *(const float4*)(src + i + 4);
  u8v o;
  o[0] = f2bf(a.x); o[1] = f2bf(a.y); o[2] = f2bf(a.z); o[3] = f2bf(a.w);
  o[4] = f2bf(b.x); o[5] = f2bf(b.y); o[6] = f2bf(b.z); o[7] = f2bf(b.w);
  *(u8v*)(dst + i) = o;
}

// Wd [E,D,DE] fp32 -> Wdb [D, E*DE] bf16  (Wdb[d][e*256+f] = Wd[e][d][f])
__global__ __launch_bounds__(256)
void wd_reorder(const float* __restrict__ Wd, ushort* __restrict__ Wdb) {
  const size_t i = ((size_t)blockIdx.x * 256 + threadIdx.x) * 8;
  const int e = (int)(i >> 18);            // /(1024*256)
  const int d = (int)((i >> 8) & 1023);
  const int f = (int)(i & 255);
  const float4 a = *(const float4*)(Wd + i);
  const float4 b = *(const float4*)(Wd + i + 4);
  u8v o;
  o[0] = f2bf(a.x); o[1] = f2bf(a.y); o[2] = f2bf(a.z); o[3] = f2bf(a.w);
  o[4] = f2bf(b.x); o[5] = f2bf(b.y); o[6] = f2bf(b.z); o[7] = f2bf(b.w);
  *(u8v*)(Wdb + (size_t)d * EDE + e * DEc + f) = o;
}

// ---------------------------------------------------------------------------
// LayerNorm: one block (256 threads) per row of D=1024; bf16 output
// ---------------------------------------------------------------------------
__global__ __launch_bounds__(256)
void ln_kernel(const float* __restrict__ in, const float* __restrict__ g,
               const float* __restrict__ bt, ushort* __restrict__ out) {
  const int row = blockIdx.x;
  const int tid = threadIdx.x;
  const float* xr = in + (size_t)row * Dc;
  float4 v = *(const float4*)(xr + tid * 4);
  float s  = v.x + v.y + v.z + v.w;
  float ss = v.x * v.x + v.y * v.y + v.z * v.z + v.w * v.w;
#pragma unroll
  for (int off = 32; off; off >>= 1) {
    s  += __shfl_xor(s, off);
    ss += __shfl_xor(ss, off);
  }
  __shared__ float red[8];
  const int w = tid >> 6;
  if ((tid & 63) == 0) { red[w] = s; red[4 + w] = ss; }
  __syncthreads();
  const float ts  = red[0] + red[1] + red[2] + red[3];
  const float tss = red[4] + red[5] + red[6] + red[7];
  const float mean = ts * (1.0f / Dc);
  const float var  = tss * (1.0f / Dc) - mean * mean;
  const float rstd = rsqrtf(var + 1e-5f);
  float4 gv = *(const float4*)(g + tid * 4);
  float4 bv = *(const float4*)(bt + tid * 4);
  u4v o;
  o[0] = f2bf((v.x - mean) * rstd * gv.x + bv.x);
  o[1] = f2bf((v.y - mean) * rstd * gv.y + bv.y);
  o[2] = f2bf((v.z - mean) * rstd * gv.z + bv.z);
  o[3] = f2bf((v.w - mean) * rstd * gv.w + bv.w);
  *(u4v*)(out + (size_t)row * Dc + tid * 4) = o;
}

// ---------------------------------------------------------------------------
// bf16 MFMA GEMM: C[M,N] = A[M,K] @ B[N,K]^T, m97 structure.
// 128x128 tile, BK=32, 256 thr = 4 waves (2x2), 4x4 frags of 16x16x32/wave.
// LDS linear for global_load_lds; source pre-swizzled; reads XOR-swizzled.
// EPI: 0 = QKV scatter bf16 (bias, q*0.125, V transposed [bh][d][t])
//      1 = fp32 +bias+resid   2 = bf16 plain   3 = fp32 accumulate
// ---------------------------------------------------------------------------
template <int EPI>
__global__ __launch_bounds__(256)
void gemm_bf16(const ushort* __restrict__ A, const ushort* __restrict__ B,
               const float* __restrict__ bias, const float* __restrict__ resid,
               void* __restrict__ Cout, int ldc, int K) {
  __shared__ __align__(16) ushort As[128 * 32];
  __shared__ __align__(16) ushort Bs[128 * 32];
  const int tid = threadIdx.x;
  const int lane = tid & 63, w = tid >> 6;
  const int g = lane >> 4, c = lane & 15;
  const int m0 = blockIdx.y * 128, n0 = blockIdx.x * 128;
  const int wm = (w >> 1) * 64, wn = (w & 1) * 64;
  const f4v fz = {0.f, 0.f, 0.f, 0.f};
  f4v acc[4][4];
#pragma unroll
  for (int i = 0; i < 4; ++i)
#pragma unroll
    for (int j = 0; j < 4; ++j) acc[i][j] = fz;

  int srow[2], skoff[2];
#pragma unroll
  for (int seg = 0; seg < 2; ++seg) {
    const int ci = seg * 256 + tid;
    srow[seg] = ci >> 2;
    skoff[seg] = 8 * ((ci & 3) ^ ((srow[seg] >> 1) & 3));
  }

  for (int k0 = 0; k0 < K; k0 += 32) {
#pragma unroll
    for (int seg = 0; seg < 2; ++seg) {
      const int ci = seg * 256 + tid;
      GLOAD_LDS(A + (size_t)(m0 + srow[seg]) * K + k0 + skoff[seg], &As[ci * 8]);
      GLOAD_LDS(B + (size_t)(n0 + srow[seg]) * K + k0 + skoff[seg], &Bs[ci * 8]);
    }
    __syncthreads();
    s8v af[4], bf[4];
#pragma unroll
    for (int mi = 0; mi < 4; ++mi) {
      const int R = wm + mi * 16 + c;
      af[mi] = *(const s8v*)&As[R * 32 + 8 * (g ^ ((R >> 1) & 3))];
    }
#pragma unroll
    for (int ni = 0; ni < 4; ++ni) {
      const int R = wn + ni * 16 + c;
      bf[ni] = *(const s8v*)&Bs[R * 32 + 8 * (g ^ ((R >> 1) & 3))];
    }
#pragma unroll
    for (int mi = 0; mi < 4; ++mi)
#pragma unroll
      for (int ni = 0; ni < 4; ++ni)
        acc[mi][ni] = __builtin_amdgcn_mfma_f32_16x16x32_bf16(
            af[mi], bf[ni], acc[mi][ni], 0, 0, 0);
    __syncthreads();
  }

  // epilogue: C/D layout col=lane&15, row=(lane>>4)*4+reg  [m89-verified]
#pragma unroll
  for (int mi = 0; mi < 4; ++mi) {
#pragma unroll
    for (int ni = 0; ni < 4; ++ni) {
      if constexpr (EPI == 0) {  // QKV scatter, head-major
        const int col = n0 + wn + ni * 16 + c;
        const int which = col >> 10, hh = (col >> 6) & 15, d = col & 63;
        const int row0 = m0 + wm + mi * 16 + g * 4;
        const int b = row0 >> 11, t0 = row0 & 2047;
        const float bs = bias[col];
        const float qs = (which == 0) ? 0.125f : 1.f;
        ushort* base = (ushort*)Cout;
        if (which == 2) {  // V transposed: Vt[bh][d][t], 4 consecutive t
          u4v pk;
#pragma unroll
          for (int j = 0; j < 4; ++j) pk[j] = f2bf(acc[mi][ni][j] + bs);
          *(u4v*)&base[2 * (size_t)NTOK * Dc +
                       (((size_t)(b * Hc + hh)) * 64 + d) * Tc + t0] = pk;
        } else {
          const size_t off = (size_t)which * ((size_t)NTOK * Dc);
#pragma unroll
          for (int j = 0; j < 4; ++j)
            base[off + (((size_t)(b * Hc + hh)) * Tc + t0 + j) * 64 + d] =
                f2bf((acc[mi][ni][j] + bs) * qs);
        }
      } else {
#pragma unroll
        for (int j = 0; j < 4; ++j) {
          const int row = m0 + wm + mi * 16 + g * 4 + j;
          const int col = n0 + wn + ni * 16 + c;
          float v = acc[mi][ni][j];
          if constexpr (EPI == 1) {
            v += bias[col] + resid[(size_t)row * ldc + col];
            ((float*)Cout)[(size_t)row * ldc + col] = v;
          } else if constexpr (EPI == 2) {
            ((ushort*)Cout)[(size_t)row * ldc + col] = f2bf(v);
          } else {
            ((float*)Cout)[(size_t)row * ldc + col] += v;
          }
        }
      }
    }
  }
}

// ---------------------------------------------------------------------------
// MFMA flash attention. Block = 256 thr (4 waves), 64 q-rows/block (16/wave).
// K [key][d] and pre-transposed V [d][key] staged in LDS (XOR-swizzled,
// b128 only). P stored transposed (P^T[64k][16q], packed b64 writes) and
// read back as the PV A-fragment via ds_read_b64_tr_b16. Defer-max (THR=8)
// skips the O-rescale when the running max doesn't grow. O written bf16.
// ---------------------------------------------------------------------------
__global__ __launch_bounds__(256)
void attn_mfma(const ushort* __restrict__ Qb, const ushort* __restrict__ Kb,
               const ushort* __restrict__ Vt, ushort* __restrict__ Ob) {
  __shared__ ushort Ksm[64 * 64];      // [key][d]  swizzled
  __shared__ ushort Vtsm[64 * 64];     // [d][key]  swizzled
  __shared__ ushort Ptsm[4 * 64 * 16]; // per-wave P^T [key][q]
  const int tid = threadIdx.x;
  const int lane = tid & 63, w = tid >> 6;
  const int g = lane >> 4, c = lane & 15;
  const int bid = blockIdx.x;
  const int qt = bid & 31, bh = bid >> 5;   // consecutive blocks share head
  const ushort* Qh = Qb + (size_t)bh * Tc * 64;
  const ushort* Kh = Kb + (size_t)bh * Tc * 64;
  const ushort* Vth = Vt + (size_t)bh * 64 * Tc;   // [d][t]
  const int qrow = qt * 64 + w * 16 + c;
  s8v qf0 = *(const s8v*)(Qh + (size_t)qrow * 64 + g * 8);
  s8v qf1 = *(const s8v*)(Qh + (size_t)qrow * 64 + 32 + g * 8);
  const f4v fz = {0.f, 0.f, 0.f, 0.f};
  f4v accO[4] = {fz, fz, fz, fz};
  float mold[4] = {-1e30f, -1e30f, -1e30f, -1e30f};
  float lsum[4] = {0.f, 0.f, 0.f, 0.f};
  ushort* Ptw = Ptsm + w * 64 * 16;

  for (int j0 = 0; j0 < Tc; j0 += 64) {
    // stage K [64 keys][64 d]
#pragma unroll
    for (int seg = 0; seg < 2; ++seg) {
      const int idx = seg * 256 + tid;
      const int key = idx >> 3, d0 = (idx & 7) * 8;
      *(s8v*)&Ksm[key * 64 + (d0 ^ ((key & 7) << 3))] =
          *(const s8v*)(Kh + (size_t)(j0 + key) * 64 + d0);
    }
    // stage V^T [64 d][64 keys] straight from transposed global
#pragma unroll
    for (int seg = 0; seg < 2; ++seg) {
      const int idx = seg * 256 + tid;
      const int d = idx >> 3, key0 = (idx & 7) * 8;
      *(s8v*)&Vtsm[d * 64 + (key0 ^ ((d & 7) << 3))] =
          *(const s8v*)(Vth + (size_t)d * Tc + j0 + key0);
    }
    __syncthreads();
    // QK^T: S[16q][64k] as 4 MFMA tiles (D: row=g*4+r, col=c)
    f4v s[4];
    __builtin_amdgcn_s_setprio(1);
#pragma unroll
    for (int kt = 0; kt < 4; ++kt) {
      s[kt] = fz;
#pragma unroll
      for (int hf = 0; hf < 2; ++hf) {
        const int krow = kt * 16 + c;
        const int col0 = hf * 32 + g * 8;
        s8v kf = *(const s8v*)&Ksm[krow * 64 + (col0 ^ ((krow & 7) << 3))];
        s[kt] = __builtin_amdgcn_mfma_f32_16x16x32_bf16(
            hf ? qf1 : qf0, kf, s[kt], 0, 0, 0);
      }
    }
    __builtin_amdgcn_s_setprio(0);
    // online softmax rows q=g*4+r; defer-max with THR=8
    float mxr[4];
    bool need = false;
#pragma unroll
    for (int r = 0; r < 4; ++r) {
      float mx = fmaxf(fmaxf(s[0][r], s[1][r]), fmaxf(s[2][r], s[3][r]));
#pragma unroll
      for (int mk = 1; mk < 16; mk <<= 1) mx = fmaxf(mx, __shfl_xor(mx, mk));
      mxr[r] = mx;
      need = need || (mx > mold[r] + 8.f);
    }
    if (__any((int)need)) {
#pragma unroll
      for (int r = 0; r < 4; ++r) {
        const float mnew = fmaxf(mold[r], mxr[r]);
        const float sc = __expf(mold[r] - mnew);
        lsum[r] *= sc;
#pragma unroll
        for (int dt = 0; dt < 4; ++dt) accO[dt][r] *= sc;
        mold[r] = mnew;
      }
    }
#pragma unroll
    for (int r = 0; r < 4; ++r) {
      float rs = 0.f;
#pragma unroll
      for (int kt = 0; kt < 4; ++kt) {
        const float p = __expf(s[kt][r] - mold[r]);
        s[kt][r] = p;
        rs += p;
      }
#pragma unroll
      for (int mk = 1; mk < 16; mk <<= 1) rs += __shfl_xor(rs, mk);
      lsum[r] += rs;
    }
    // P^T write: row kt*16+c, cols g*4..g*4+3 (packed b64)
#pragma unroll
    for (int kt = 0; kt < 4; ++kt) {
      u4v pk;
#pragma unroll
      for (int r = 0; r < 4; ++r) pk[r] = f2bf(s[kt][r]);
      *(u4v*)&Ptw[(kt * 16 + c) * 16 + g * 4] = pk;
    }
    // drain P^T writes, then tr-gather the PV A-fragments
    asm volatile("s_waitcnt lgkmcnt(0)" ::: "memory");
    __builtin_amdgcn_sched_barrier(0);
    u4v plo0 = ds_tr16(&Ptw[(g * 8) * 16 + c]);
    u4v phi0 = ds_tr16(&Ptw[(g * 8) * 16 + c + 64]);
    u4v plo1 = ds_tr16(&Ptw[(32 + g * 8) * 16 + c]);
    u4v phi1 = ds_tr16(&Ptw[(32 + g * 8) * 16 + c + 64]);
    asm volatile("s_waitcnt lgkmcnt(0)" ::: "memory");
    __builtin_amdgcn_sched_barrier(0);
    union { u4v h[2]; s8v v; } u0, u1;
    u0.h[0] = plo0; u0.h[1] = phi0;
    u1.h[0] = plo1; u1.h[1] = phi1;
    s8v pf[2] = {u0.v, u1.v};
    // PV: O[16q][64d] += P[16,64] @ V[64,64]
    __builtin_amdgcn_s_setprio(1);
#pragma unroll
    for (int kh = 0; kh < 2; ++kh) {
      const int pcol0 = kh * 32 + g * 8;
#pragma unroll
      for (int dt = 0; dt < 4; ++dt) {
        const int vrow = dt * 16 + c;
        s8v vf = *(const s8v*)&Vtsm[vrow * 64 + (pcol0 ^ ((vrow & 7) << 3))];
        accO[dt] = __builtin_amdgcn_mfma_f32_16x16x32_bf16(pf[kh], vf, accO[dt], 0, 0, 0);
      }
    }
    __builtin_amdgcn_s_setprio(0);
    __syncthreads();
  }
  const int h = bh & 15, b = bh >> 4;
#pragma unroll
  for (int r = 0; r < 4; ++r) {
    const int tokr = b * Tc + qt * 64 + w * 16 + g * 4 + r;
    const float inv = 1.f / lsum[r];
    ushort* orow = Ob + (size_t)tokr * Dc + h * 64;
#pragma unroll
    for (int dt = 0; dt < 4; ++dt) orow[dt * 16 + c] = f2bf(accO[dt][r] * inv);
  }
}

// ---------------------------------------------------------------------------
// Router: logits = (h2 @ rw^T)/temp; top-2 threshold; sigmoid suppression;
// softmax(logits * suppression). One block per token. h2 is bf16.
// ---------------------------------------------------------------------------
__global__ __launch_bounds__(256)
void router_kernel(const ushort* __restrict__ h2, const float* __restrict__ rw,
                   const float* __restrict__ log_temp, float* __restrict__ wts) {
  const int t = blockIdx.x;
  const int tid = threadIdx.x;
  const ushort* hr = h2 + (size_t)t * Dc;
  u4v hb = *(const u4v*)(hr + tid * 4);
  const float h0 = bf2f(hb[0]), h1 = bf2f(hb[1]), h2v = bf2f(hb[2]), h3 = bf2f(hb[3]);
  float part[Ec];
#pragma unroll
  for (int e = 0; e < Ec; ++e) {
    float4 wv = *(const float4*)(rw + (size_t)e * Dc + tid * 4);
    part[e] = h0 * wv.x + h1 * wv.y + h2v * wv.z + h3 * wv.w;
  }
#pragma unroll
  for (int off = 32; off; off >>= 1) {
#pragma unroll
    for (int e = 0; e < Ec; ++e) part[e] += __shfl_xor(part[e], off);
  }
  __shared__ float red[4][Ec];
  const int w = tid >> 6;
  if ((tid & 63) == 0) {
#pragma unroll
    for (int e = 0; e < Ec; ++e) red[w][e] = part[e];
  }
  __syncthreads();
  if (tid == 0) {
    const float lt = *log_temp;
    const float temp = log1pf(__expf(lt)) + 0.1f;
    float lg[Ec];
#pragma unroll
    for (int e = 0; e < Ec; ++e)
      lg[e] = (red[0][e] + red[1][e] + red[2][e] + red[3][e]) / temp;
    float m1 = -1e30f, m2 = -1e30f;
#pragma unroll
    for (int e = 0; e < Ec; ++e) {
      const float v = lg[e];
      if (v > m1) { m2 = m1; m1 = v; }
      else if (v > m2) { m2 = v; }
    }
    float sl[Ec];
    float mx = -1e30f;
#pragma unroll
    for (int e = 0; e < Ec; ++e) {
      const float sup = 1.f / (1.f + __expf(-10.f * (lg[e] - m2)));
      sl[e] = lg[e] * sup;
      mx = fmaxf(mx, sl[e]);
    }
    float ssum = 0.f;
#pragma unroll
    for (int e = 0; e < Ec; ++e) {
      const float p = __expf(sl[e] - mx);
      sl[e] = p;
      ssum += p;
    }
    const float inv = 1.f / ssum;
#pragma unroll
    for (int e = 0; e < Ec; ++e) wts[(size_t)t * Ec + e] = sl[e] * inv;
  }
}

// ---------------------------------------------------------------------------
// act = silu(hg) * hu * weight[t,e], bf16 in/out, in place into hg.
// ---------------------------------------------------------------------------
__global__ __launch_bounds__(256)
void moe_act_kernel(ushort* __restrict__ hg, const ushort* __restrict__ hu,
                    const float* __restrict__ wts) {
  const size_t idx = ((size_t)blockIdx.x * 256 + threadIdx.x) * 8;
  const int t = (int)(idx >> 11);        // / 2048
  const int e = (int)((idx >> 8) & 7);   // (idx % 2048) / 256
  const float wgt = wts[(size_t)t * Ec + e];
  u8v a = *(const u8v*)(hg + idx);
  u8v u = *(const u8v*)(hu + idx);
  u8v r;
#pragma unroll
  for (int j = 0; j < 8; ++j) {
    const float av = bf2f(a[j]), uv = bf2f(u[j]);
    r[j] = f2bf((av / (1.f + __expf(-av))) * uv * wgt);
  }
  *(u8v*)(hg + idx) = r;
}

// ---------------------------------------------------------------------------
extern "C" void kernel_launch(void* const* d_in, const int* in_sizes, int n_in,
                              void* d_out, int out_size, void* d_ws, size_t ws_size,
                              hipStream_t stream) {
  (void)in_sizes; (void)n_in; (void)out_size; (void)ws_size;
  const float* x        = (const float*)d_in[0];
  const float* ln1_g    = (const float*)d_in[1];
  const float* ln1_b    = (const float*)d_in[2];
  const float* in_w     = (const float*)d_in[3];
  const float* in_b     = (const float*)d_in[4];
  const float* out_w    = (const float*)d_in[5];
  const float* out_b    = (const float*)d_in[6];
  const float* ln2_g    = (const float*)d_in[7];
  const float* ln2_b    = (const float*)d_in[8];
  const float* rw       = (const float*)d_in[9];
  const float* log_temp = (const float*)d_in[10];
  const float* Wg       = (const float*)d_in[11];
  const float* Wu       = (const float*)d_in[12];
  const float* Wd       = (const float*)d_in[13];
  float* out = (float*)d_out;

  // Workspace (ushorts), total ~164.3 MiB:
  ushort* h_bf   = (ushort*)d_ws;                       // NTOK*1024   16 MiB
  ushort* Qb     = h_bf   + (size_t)NTOK * Dc;          // 16 MiB
  ushort* Kb     = Qb     + (size_t)NTOK * Dc;          // 16 MiB
  ushort* Vt     = Kb     + (size_t)NTOK * Dc;          // 16 MiB ([bh][d][t])
  ushort* Ob     = Vt     + (size_t)NTOK * Dc;          // 16 MiB
  ushort* hg     = Ob     + (size_t)NTOK * Dc;          // NTOK*2048   32 MiB
  ushort* hu     = hg     + (size_t)NTOK * EDE;         // 32 MiB
  ushort* wb_in  = hu     + (size_t)NTOK * EDE;         // 3072*1024    6 MiB
  ushort* wb_out = wb_in  + (size_t)3 * Dc * Dc;        // 1024*1024    2 MiB
  ushort* wb_g   = wb_out + (size_t)Dc * Dc;            // 2048*1024    4 MiB
  ushort* wb_u   = wb_g   + (size_t)EDE * Dc;           // 4 MiB
  ushort* wb_d   = wb_u   + (size_t)EDE * Dc;           // 1024*2048    4 MiB
  float*  wts    = (float*)(wb_d + (size_t)Dc * EDE);   // NTOK*8     0.25 MiB

  const dim3 blk(256);

  // 0. weight conversions (every call; deterministic)
  f32_to_bf16<<<dim3(3 * Dc * Dc / 2048), blk, 0, stream>>>(in_w, wb_in);
  f32_to_bf16<<<dim3(Dc * Dc / 2048), blk, 0, stream>>>(out_w, wb_out);
  f32_to_bf16<<<dim3(EDE * Dc / 2048), blk, 0, stream>>>(Wg, wb_g);
  f32_to_bf16<<<dim3(EDE * Dc / 2048), blk, 0, stream>>>(Wu, wb_u);
  wd_reorder<<<dim3(Ec * Dc * DEc / 2048), blk, 0, stream>>>(Wd, wb_d);

  // 1. LN1: x -> h_bf (bf16)
  ln_kernel<<<dim3(NTOK), blk, 0, stream>>>(x, ln1_g, ln1_b, h_bf);
  // 2. QKV GEMM -> head-major bf16 Q(x0.125)/K + transposed V directly
  gemm_bf16<0><<<dim3(3 * Dc / 128, NTOK / 128), blk, 0, stream>>>(
      h_bf, wb_in, in_b, nullptr, Qb, 0, Dc);
  // 3. MFMA attention -> Ob bf16
  attn_mfma<<<dim3(Bc * Hc * (Tc / 64)), blk, 0, stream>>>(Qb, Kb, Vt, Ob);
  // 4. out proj + bias + residual(x) -> out fp32
  gemm_bf16<1><<<dim3(Dc / 128, NTOK / 128), blk, 0, stream>>>(
      Ob, wb_out, out_b, x, out, Dc, Dc);
  // 5. LN2: out -> h_bf (h2)
  ln_kernel<<<dim3(NTOK), blk, 0, stream>>>(out, ln2_g, ln2_b, h_bf);
  // 6. router weights
  router_kernel<<<dim3(NTOK), blk, 0, stream>>>(h_bf, rw, log_temp, wts);
  // 7. gate / up GEMMs -> bf16
  gemm_bf16<2><<<dim3(EDE / 128, NTOK / 128), blk, 0, stream>>>(
      h_bf, wb_g, nullptr, nullptr, hg, EDE, Dc);
  gemm_bf16<2><<<dim3(EDE / 128, NTOK / 128), blk, 0, stream>>>(
      h_bf, wb_u, nullptr, nullptr, hu, EDE, Dc);
  // 8. act = silu(hg)*hu*w (bf16, in place)
  moe_act_kernel<<<dim3((int)((size_t)NTOK * EDE / 8 / 256)), blk, 0, stream>>>(
      hg, hu, wts);
  // 9. single down GEMM over concatenated experts, K=2048, += into out
  gemm_bf16<3><<<dim3(Dc / 128, NTOK / 128), blk, 0, stream>>>(
      hg, wb_d, nullptr, nullptr, out, Dc, EDE);
}

// Round 6
// 468.653 us; speedup vs baseline: 10.8278x; 1.2441x over previous
//
#include <hip/hip_runtime.h>
#include <hip/hip_bf16.h>
#include <cstddef>
#include <cstdint>

// Problem constants (match reference)
constexpr int Bc  = 4;
constexpr int Tc  = 2048;
constexpr int Dc  = 1024;
constexpr int Hc  = 16;
constexpr int DHc = 64;    // head dim
constexpr int Ec  = 8;     // experts
constexpr int DEc = 256;   // expert dim
constexpr int NTOK = Bc * Tc;          // 8192 tokens
constexpr int EDE = Ec * DEc;          // 2048

typedef __attribute__((ext_vector_type(8)))  short  s8v;   // 8 bf16 (4 VGPRs)
typedef __attribute__((ext_vector_type(4)))  float  f4v;   // 16x16 MFMA C/D
typedef __attribute__((ext_vector_type(16))) float  f16v;  // 32x32 MFMA C/D
typedef __attribute__((ext_vector_type(8)))  ushort u8v;
typedef __attribute__((ext_vector_type(4)))  ushort u4v;

__device__ inline ushort f2bf(float f) {  // fp32 -> bf16 bits, RNE
  union { float f; uint32_t u; } v; v.f = f;
  uint32_t r = v.u + 0x7FFFu + ((v.u >> 16) & 1u);
  return (ushort)(r >> 16);
}
__device__ inline float bf2f(ushort u) {
  union { uint32_t u; float f; } v; v.u = ((uint32_t)u) << 16;
  return v.f;
}

// async global->LDS, 16B per lane; LDS dest = wave-uniform base + lane*16
#define GLOAD_LDS(gsrc, ldst)                                        \
  __builtin_amdgcn_global_load_lds(                                  \
      (const __attribute__((address_space(1))) void*)(gsrc),         \
      (__attribute__((address_space(3))) void*)(ldst), 16, 0, 0)

// pack 2 f32 -> 1 u32 of 2 bf16 (lo = a, hi = b), RNE
__device__ inline uint32_t cvtpk(float a, float b) {
  uint32_t r;
  asm("v_cvt_pk_bf16_f32 %0, %1, %2" : "=v"(r) : "v"(a), "v"(b));
  return r;
}

// ---------------------------------------------------------------------------
// fp32 -> bf16 flat convert (weights); n multiple of 2048
// ---------------------------------------------------------------------------
__global__ __launch_bounds__(256)
void f32_to_bf16(const float* __restrict__ src, ushort* __restrict__ dst) {
  const size_t i = ((size_t)blockIdx.x * 256 + threadIdx.x) * 8;
  const float4 a = *(const float4*)(src + i);
  const float4 b = *(const float4*)(src + i + 4);
  u8v o;
  o[0] = f2bf(a.x); o[1] = f2bf(a.y); o[2] = f2bf(a.z); o[3] = f2bf(a.w);
  o[4] = f2bf(b.x); o[5] = f2bf(b.y); o[6] = f2bf(b.z); o[7] = f2bf(b.w);
  *(u8v*)(dst + i) = o;
}

// Wd [E,D,DE] fp32 -> Wdb [D, E*DE] bf16  (Wdb[d][e*256+f] = Wd[e][d][f])
__global__ __launch_bounds__(256)
void wd_reorder(const float* __restrict__ Wd, ushort* __restrict__ Wdb) {
  const size_t i = ((size_t)blockIdx.x * 256 + threadIdx.x) * 8;
  const int e = (int)(i >> 18);            // /(1024*256)
  const int d = (int)((i >> 8) & 1023);
  const int f = (int)(i & 255);
  const float4 a = *(const float4*)(Wd + i);
  const float4 b = *(const float4*)(Wd + i + 4);
  u8v o;
  o[0] = f2bf(a.x); o[1] = f2bf(a.y); o[2] = f2bf(a.z); o[3] = f2bf(a.w);
  o[4] = f2bf(b.x); o[5] = f2bf(b.y); o[6] = f2bf(b.z); o[7] = f2bf(b.w);
  *(u8v*)(Wdb + (size_t)d * EDE + e * DEc + f) = o;
}

// ---------------------------------------------------------------------------
// LayerNorm: one block (256 threads) per row of D=1024; bf16 output
// ---------------------------------------------------------------------------
__global__ __launch_bounds__(256)
void ln_kernel(const float* __restrict__ in, const float* __restrict__ g,
               const float* __restrict__ bt, ushort* __restrict__ out) {
  const int row = blockIdx.x;
  const int tid = threadIdx.x;
  const float* xr = in + (size_t)row * Dc;
  float4 v = *(const float4*)(xr + tid * 4);
  float s  = v.x + v.y + v.z + v.w;
  float ss = v.x * v.x + v.y * v.y + v.z * v.z + v.w * v.w;
#pragma unroll
  for (int off = 32; off; off >>= 1) {
    s  += __shfl_xor(s, off);
    ss += __shfl_xor(ss, off);
  }
  __shared__ float red[8];
  const int w = tid >> 6;
  if ((tid & 63) == 0) { red[w] = s; red[4 + w] = ss; }
  __syncthreads();
  const float ts  = red[0] + red[1] + red[2] + red[3];
  const float tss = red[4] + red[5] + red[6] + red[7];
  const float mean = ts * (1.0f / Dc);
  const float var  = tss * (1.0f / Dc) - mean * mean;
  const float rstd = rsqrtf(var + 1e-5f);
  float4 gv = *(const float4*)(g + tid * 4);
  float4 bv = *(const float4*)(bt + tid * 4);
  u4v o;
  o[0] = f2bf((v.x - mean) * rstd * gv.x + bv.x);
  o[1] = f2bf((v.y - mean) * rstd * gv.y + bv.y);
  o[2] = f2bf((v.z - mean) * rstd * gv.z + bv.z);
  o[3] = f2bf((v.w - mean) * rstd * gv.w + bv.w);
  *(u4v*)(out + (size_t)row * Dc + tid * 4) = o;
}

// ---------------------------------------------------------------------------
// bf16 MFMA GEMM: C[M,N] = A[M,K] @ B[N,K]^T, m97 structure.
// 128x128 tile, BK=32, 256 thr = 4 waves (2x2), 4x4 frags of 16x16x32/wave.
// LDS linear for global_load_lds; source pre-swizzled; reads XOR-swizzled.
// EPI: 0 = QKV scatter bf16 (bias, q*0.125, V transposed [bh][d][t])
//      1 = fp32 +bias+resid   2 = bf16 plain   3 = fp32 accumulate
// ---------------------------------------------------------------------------
template <int EPI>
__global__ __launch_bounds__(256)
void gemm_bf16(const ushort* __restrict__ A, int lda,
               const ushort* __restrict__ B,
               const float* __restrict__ bias, const float* __restrict__ resid,
               void* __restrict__ Cout, int ldc, int K) {
  __shared__ __align__(16) ushort As[128 * 32];
  __shared__ __align__(16) ushort Bs[128 * 32];
  const int tid = threadIdx.x;
  const int lane = tid & 63, w = tid >> 6;
  const int g = lane >> 4, c = lane & 15;
  const int m0 = blockIdx.y * 128, n0 = blockIdx.x * 128;
  const int wm = (w >> 1) * 64, wn = (w & 1) * 64;
  const f4v fz = {0.f, 0.f, 0.f, 0.f};
  f4v acc[4][4];
#pragma unroll
  for (int i = 0; i < 4; ++i)
#pragma unroll
    for (int j = 0; j < 4; ++j) acc[i][j] = fz;

  int srow[2], skoff[2];
#pragma unroll
  for (int seg = 0; seg < 2; ++seg) {
    const int ci = seg * 256 + tid;
    srow[seg] = ci >> 2;
    skoff[seg] = 8 * ((ci & 3) ^ ((srow[seg] >> 1) & 3));
  }

  for (int k0 = 0; k0 < K; k0 += 32) {
#pragma unroll
    for (int seg = 0; seg < 2; ++seg) {
      const int ci = seg * 256 + tid;
      GLOAD_LDS(A + (size_t)(m0 + srow[seg]) * lda + k0 + skoff[seg], &As[ci * 8]);
      GLOAD_LDS(B + (size_t)(n0 + srow[seg]) * K + k0 + skoff[seg], &Bs[ci * 8]);
    }
    __syncthreads();
    s8v af[4], bf[4];
#pragma unroll
    for (int mi = 0; mi < 4; ++mi) {
      const int R = wm + mi * 16 + c;
      af[mi] = *(const s8v*)&As[R * 32 + 8 * (g ^ ((R >> 1) & 3))];
    }
#pragma unroll
    for (int ni = 0; ni < 4; ++ni) {
      const int R = wn + ni * 16 + c;
      bf[ni] = *(const s8v*)&Bs[R * 32 + 8 * (g ^ ((R >> 1) & 3))];
    }
#pragma unroll
    for (int mi = 0; mi < 4; ++mi)
#pragma unroll
      for (int ni = 0; ni < 4; ++ni)
        acc[mi][ni] = __builtin_amdgcn_mfma_f32_16x16x32_bf16(
            af[mi], bf[ni], acc[mi][ni], 0, 0, 0);
    __syncthreads();
  }

  // epilogue: C/D layout col=lane&15, row=(lane>>4)*4+reg  [m89-verified]
#pragma unroll
  for (int mi = 0; mi < 4; ++mi) {
#pragma unroll
    for (int ni = 0; ni < 4; ++ni) {
      if constexpr (EPI == 0) {  // QKV scatter, head-major
        const int col = n0 + wn + ni * 16 + c;
        const int which = col >> 10, hh = (col >> 6) & 15, d = col & 63;
        const int row0 = m0 + wm + mi * 16 + g * 4;
        const int b = row0 >> 11, t0 = row0 & 2047;
        const float bs = bias[col];
        const float qs = (which == 0) ? 0.125f : 1.f;
        ushort* base = (ushort*)Cout;
        if (which == 2) {  // V transposed: Vt[bh][d][t], 4 consecutive t
          u4v pk;
#pragma unroll
          for (int j = 0; j < 4; ++j) pk[j] = f2bf(acc[mi][ni][j] + bs);
          *(u4v*)&base[2 * (size_t)NTOK * Dc +
                       (((size_t)(b * Hc + hh)) * 64 + d) * Tc + t0] = pk;
        } else {
          const size_t off = (size_t)which * ((size_t)NTOK * Dc);
#pragma unroll
          for (int j = 0; j < 4; ++j)
            base[off + (((size_t)(b * Hc + hh)) * Tc + t0 + j) * 64 + d] =
                f2bf((acc[mi][ni][j] + bs) * qs);
        }
      } else {
#pragma unroll
        for (int j = 0; j < 4; ++j) {
          const int row = m0 + wm + mi * 16 + g * 4 + j;
          const int col = n0 + wn + ni * 16 + c;
          float v = acc[mi][ni][j];
          if constexpr (EPI == 1) {
            v += bias[col] + resid[(size_t)row * ldc + col];
            ((float*)Cout)[(size_t)row * ldc + col] = v;
          } else if constexpr (EPI == 2) {
            ((ushort*)Cout)[(size_t)row * ldc + col] = f2bf(v);
          } else {
            ((float*)Cout)[(size_t)row * ldc + col] += v;
          }
        }
      }
    }
  }
}

// ---------------------------------------------------------------------------
// MFMA flash attention, swapped-operand 32x32 form (no P LDS round-trip).
// Block = 256 thr (4 waves), 32 q-rows/wave -> 128 q/block.
// Per 64-key chunk: S^T = mfma32(K,Q) so lane holds 32 scores of ONE q-row
// (q = lane&31; lanes l, l+32 split the 64 keys). In-register softmax with
// one shfl_xor(32) pair-reduce + defer-max (THR=8). P fragments built
// in-register via v_cvt_pk_bf16_f32 + v_permlane32_swap_b32, feed
// O^T = mfma32(V^T, P) so accO's column index is q (lane-local rescale).
// K [key][d] and V^T [d][key] staged via global_load_lds w/ pre-swizzled src.
// ---------------------------------------------------------------------------
__global__ __launch_bounds__(256)
void attn_mfma(const ushort* __restrict__ Qb, const ushort* __restrict__ Kb,
               const ushort* __restrict__ Vt, ushort* __restrict__ Ob) {
  __shared__ __align__(16) ushort Ksm[64 * 64];   // [key][d]  swizzled content
  __shared__ __align__(16) ushort Vtsm[64 * 64];  // [d][key]  swizzled content
  const int tid = threadIdx.x;
  const int lane = tid & 63, w = tid >> 6;
  const int ql = lane & 31, hi = lane >> 5;
  const int bid = blockIdx.x;
  const int qt = bid & 15, bh = bid >> 4;   // 16 q-tiles of 128 per bh
  const ushort* Qh = Qb + (size_t)bh * Tc * 64;
  const ushort* Kh = Kb + (size_t)bh * Tc * 64;
  const ushort* Vth = Vt + (size_t)bh * 64 * Tc;   // [d][t]
  // Q B-fragments: n = q = ql, k = d = ds*16 + hi*8 + j
  const int qrow = qt * 128 + w * 32 + ql;
  s8v qf[4];
#pragma unroll
  for (int ds = 0; ds < 4; ++ds)
    qf[ds] = *(const s8v*)(Qh + (size_t)qrow * 64 + ds * 16 + hi * 8);
  f16v accO0, accO1;
#pragma unroll
  for (int i = 0; i < 16; ++i) { accO0[i] = 0.f; accO1[i] = 0.f; }
  float mold = -1e30f, lsum = 0.f;
  // staging: K seg: key=ci>>3, d0=(ci&7)*8 ; V seg: d=ci>>3, k0=(ci&7)*8
  int srow[2], soff[2];
#pragma unroll
  for (int seg = 0; seg < 2; ++seg) {
    const int ci = seg * 256 + tid;
    srow[seg] = ci >> 3;
    soff[seg] = ((ci & 7) * 8) ^ ((srow[seg] & 7) << 3);
  }

  for (int j0 = 0; j0 < Tc; j0 += 64) {
#pragma unroll
    for (int seg = 0; seg < 2; ++seg) {
      const int ci = seg * 256 + tid;
      GLOAD_LDS(Kh + (size_t)(j0 + srow[seg]) * 64 + soff[seg], &Ksm[ci * 8]);
      GLOAD_LDS(Vth + (size_t)srow[seg] * Tc + j0 + soff[seg], &Vtsm[ci * 8]);
    }
    __syncthreads();
    // S^T[key][q]: 2 key-half tiles; A = K-frag (m=key), B = Q-frag (n=q)
    f16v s0, s1;
#pragma unroll
    for (int i = 0; i < 16; ++i) { s0[i] = 0.f; s1[i] = 0.f; }
    __builtin_amdgcn_s_setprio(1);
#pragma unroll
    for (int ds = 0; ds < 4; ++ds) {
      const int col = (ds * 16 + hi * 8);
      const int r0 = ql;
      s8v kf0 = *(const s8v*)&Ksm[r0 * 64 + (col ^ ((r0 & 7) << 3))];
      s0 = __builtin_amdgcn_mfma_f32_32x32x16_bf16(kf0, qf[ds], s0, 0, 0, 0);
      const int r1 = 32 + ql;
      s8v kf1 = *(const s8v*)&Ksm[r1 * 64 + (col ^ ((r1 & 7) << 3))];
      s1 = __builtin_amdgcn_mfma_f32_32x32x16_bf16(kf1, qf[ds], s1, 0, 0, 0);
    }
    __builtin_amdgcn_s_setprio(0);
    // softmax: lane holds 32 scores of q=ql; pair (l, l+32) spans 64 keys
    float mx = -1e30f;
#pragma unroll
    for (int i = 0; i < 16; ++i) mx = fmaxf(mx, fmaxf(s0[i], s1[i]));
    mx = fmaxf(mx, __shfl_xor(mx, 32));
    const bool need = mx > mold + 8.f;
    if (__any((int)need)) {
      const float mnew = fmaxf(mold, mx);
      const float sc = __expf(mold - mnew);
      lsum *= sc;
#pragma unroll
      for (int i = 0; i < 16; ++i) { accO0[i] *= sc; accO1[i] *= sc; }
      mold = mnew;
    }
    float rs = 0.f;
#pragma unroll
    for (int i = 0; i < 16; ++i) {
      s0[i] = __expf(s0[i] - mold); rs += s0[i];
      s1[i] = __expf(s1[i] - mold); rs += s1[i];
    }
    rs += __shfl_xor(rs, 32);
    lsum += rs;
    // build P B-fragments in-register: pa[s] covers keys s*16 + hi*8 + j.
    // source reg for (j, s, hi): quad m = 2(s&1)+hi of tile s>>1, hi'=(j>>2).
    // swap(x=b, y=a): y -> {own a | partner b}, x -> {partner a | own b}
    // => frag words = {y0, y1, x0, x1} uniformly for both lane halves.
    s8v pa[4];
#pragma unroll
    for (int s = 0; s < 4; ++s) {
      const f16v st = (s < 2) ? s0 : s1;
      const int mA = 2 * (s & 1);          // quad regs 4mA..4mA+3
      uint32_t a0 = cvtpk(st[4 * mA + 0], st[4 * mA + 1]);
      uint32_t a1 = cvtpk(st[4 * mA + 2], st[4 * mA + 3]);
      uint32_t b0 = cvtpk(st[4 * mA + 4], st[4 * mA + 5]);
      uint32_t b1 = cvtpk(st[4 * mA + 6], st[4 * mA + 7]);
      asm("v_permlane32_swap_b32 %0, %1" : "+v"(b0), "+v"(a0));
      asm("v_permlane32_swap_b32 %0, %1" : "+v"(b1), "+v"(a1));
      union { uint32_t u[4]; s8v v; } pk;
      pk.u[0] = a0; pk.u[1] = a1; pk.u[2] = b0; pk.u[3] = b1;
      pa[s] = pk.v;
    }
    // PV: O^T[d][q] += V^T[d,k] P[q,k]^T ; A = V^T-frag (m=d), B = P-frag
    __builtin_amdgcn_s_setprio(1);
#pragma unroll
    for (int s = 0; s < 4; ++s) {
      const int col = (s * 16 + hi * 8);
      const int r0 = ql;
      s8v vf0 = *(const s8v*)&Vtsm[r0 * 64 + (col ^ ((r0 & 7) << 3))];
      accO0 = __builtin_amdgcn_mfma_f32_32x32x16_bf16(vf0, pa[s], accO0, 0, 0, 0);
      const int r1 = 32 + ql;
      s8v vf1 = *(const s8v*)&Vtsm[r1 * 64 + (col ^ ((r1 & 7) << 3))];
      accO1 = __builtin_amdgcn_mfma_f32_32x32x16_bf16(vf1, pa[s], accO1, 0, 0, 0);
    }
    __builtin_amdgcn_s_setprio(0);
    __syncthreads();
  }
  // epilogue: accO col = q = ql; row = d_local = (reg&3)+8*(reg>>2)+4*hi
  const int h = bh & 15, b = bh >> 4;
  const int tok = b * Tc + qt * 128 + w * 32 + ql;
  const float inv = 1.f / lsum;
  ushort* orow = Ob + (size_t)tok * Dc + h * 64;
#pragma unroll
  for (int dt = 0; dt < 2; ++dt) {
    const f16v ac = dt ? accO1 : accO0;
#pragma unroll
    for (int rq = 0; rq < 4; ++rq) {
      u4v pk;
#pragma unroll
      for (int j = 0; j < 4; ++j) pk[j] = f2bf(ac[4 * rq + j] * inv);
      *(u4v*)&orow[dt * 32 + 8 * rq + 4 * hi] = pk;
    }
  }
}

// ---------------------------------------------------------------------------
// Router: logits = (h2 @ rw^T)/temp; top-2 threshold; sigmoid suppression;
// softmax(logits * suppression). One block per token. h2 is bf16.
// ---------------------------------------------------------------------------
__global__ __launch_bounds__(256)
void router_kernel(const ushort* __restrict__ h2, const float* __restrict__ rw,
                   const float* __restrict__ log_temp, float* __restrict__ wts) {
  const int t = blockIdx.x;
  const int tid = threadIdx.x;
  const ushort* hr = h2 + (size_t)t * Dc;
  u4v hb = *(const u4v*)(hr + tid * 4);
  const float h0 = bf2f(hb[0]), h1 = bf2f(hb[1]), h2v = bf2f(hb[2]), h3 = bf2f(hb[3]);
  float part[Ec];
#pragma unroll
  for (int e = 0; e < Ec; ++e) {
    float4 wv = *(const float4*)(rw + (size_t)e * Dc + tid * 4);
    part[e] = h0 * wv.x + h1 * wv.y + h2v * wv.z + h3 * wv.w;
  }
#pragma unroll
  for (int off = 32; off; off >>= 1) {
#pragma unroll
    for (int e = 0; e < Ec; ++e) part[e] += __shfl_xor(part[e], off);
  }
  __shared__ float red[4][Ec];
  const int w = tid >> 6;
  if ((tid & 63) == 0) {
#pragma unroll
    for (int e = 0; e < Ec; ++e) red[w][e] = part[e];
  }
  __syncthreads();
  if (tid == 0) {
    const float lt = *log_temp;
    const float temp = log1pf(__expf(lt)) + 0.1f;
    float lg[Ec];
#pragma unroll
    for (int e = 0; e < Ec; ++e)
      lg[e] = (red[0][e] + red[1][e] + red[2][e] + red[3][e]) / temp;
    float m1 = -1e30f, m2 = -1e30f;
#pragma unroll
    for (int e = 0; e < Ec; ++e) {
      const float v = lg[e];
      if (v > m1) { m2 = m1; m1 = v; }
      else if (v > m2) { m2 = v; }
    }
    float sl[Ec];
    float mx = -1e30f;
#pragma unroll
    for (int e = 0; e < Ec; ++e) {
      const float sup = 1.f / (1.f + __expf(-10.f * (lg[e] - m2)));
      sl[e] = lg[e] * sup;
      mx = fmaxf(mx, sl[e]);
    }
    float ssum = 0.f;
#pragma unroll
    for (int e = 0; e < Ec; ++e) {
      const float p = __expf(sl[e] - mx);
      sl[e] = p;
      ssum += p;
    }
    const float inv = 1.f / ssum;
#pragma unroll
    for (int e = 0; e < Ec; ++e) wts[(size_t)t * Ec + e] = sl[e] * inv;
  }
}

// ---------------------------------------------------------------------------
// act = silu(gate) * up * weight[t,e]; gate = hgu[t][n], up = hgu[t][2048+n];
// writes act in place into the gate half. 8 bf16 per thread.
// ---------------------------------------------------------------------------
__global__ __launch_bounds__(256)
void moe_act_kernel(ushort* __restrict__ hgu, const float* __restrict__ wts) {
  const size_t idx = ((size_t)blockIdx.x * 256 + threadIdx.x) * 8;
  const int t = (int)(idx >> 11);        // / 2048
  const int n = (int)(idx & 2047);
  const int e = n >> 8;
  const float wgt = wts[(size_t)t * Ec + e];
  ushort* gp = hgu + (size_t)t * (2 * EDE) + n;
  u8v a = *(const u8v*)gp;
  u8v u = *(const u8v*)(gp + EDE);
  u8v r;
#pragma unroll
  for (int j = 0; j < 8; ++j) {
    const float av = bf2f(a[j]), uv = bf2f(u[j]);
    r[j] = f2bf((av / (1.f + __expf(-av))) * uv * wgt);
  }
  *(u8v*)gp = r;
}

// ---------------------------------------------------------------------------
extern "C" void kernel_launch(void* const* d_in, const int* in_sizes, int n_in,
                              void* d_out, int out_size, void* d_ws, size_t ws_size,
                              hipStream_t stream) {
  (void)in_sizes; (void)n_in; (void)out_size; (void)ws_size;
  const float* x        = (const float*)d_in[0];
  const float* ln1_g    = (const float*)d_in[1];
  const float* ln1_b    = (const float*)d_in[2];
  const float* in_w     = (const float*)d_in[3];
  const float* in_b     = (const float*)d_in[4];
  const float* out_w    = (const float*)d_in[5];
  const float* out_b    = (const float*)d_in[6];
  const float* ln2_g    = (const float*)d_in[7];
  const float* ln2_b    = (const float*)d_in[8];
  const float* rw       = (const float*)d_in[9];
  const float* log_temp = (const float*)d_in[10];
  const float* Wg       = (const float*)d_in[11];
  const float* Wu       = (const float*)d_in[12];
  const float* Wd       = (const float*)d_in[13];
  float* out = (float*)d_out;

  // Workspace (ushorts), total ~164.3 MiB:
  ushort* h_bf   = (ushort*)d_ws;                       // NTOK*1024   16 MiB
  ushort* Qb     = h_bf   + (size_t)NTOK * Dc;          // 16 MiB
  ushort* Kb     = Qb     + (size_t)NTOK * Dc;          // 16 MiB
  ushort* Vt     = Kb     + (size_t)NTOK * Dc;          // 16 MiB ([bh][d][t])
  ushort* Ob     = Vt     + (size_t)NTOK * Dc;          // 16 MiB
  ushort* hgu    = Ob     + (size_t)NTOK * Dc;          // NTOK*4096   64 MiB
  ushort* wb_in  = hgu    + (size_t)NTOK * 2 * EDE;     // 3072*1024    6 MiB
  ushort* wb_out = wb_in  + (size_t)3 * Dc * Dc;        // 1024*1024    2 MiB
  ushort* wb_g   = wb_out + (size_t)Dc * Dc;            // 2048*1024    4 MiB
  ushort* wb_u   = wb_g   + (size_t)EDE * Dc;           // 4 MiB (contig w/ wb_g)
  ushort* wb_d   = wb_u   + (size_t)EDE * Dc;           // 1024*2048    4 MiB
  float*  wts    = (float*)(wb_d + (size_t)Dc * EDE);   // NTOK*8     0.25 MiB

  const dim3 blk(256);

  // 0. weight conversions (every call; deterministic)
  f32_to_bf16<<<dim3(3 * Dc * Dc / 2048), blk, 0, stream>>>(in_w, wb_in);
  f32_to_bf16<<<dim3(Dc * Dc / 2048), blk, 0, stream>>>(out_w, wb_out);
  f32_to_bf16<<<dim3(EDE * Dc / 2048), blk, 0, stream>>>(Wg, wb_g);
  f32_to_bf16<<<dim3(EDE * Dc / 2048), blk, 0, stream>>>(Wu, wb_u);
  wd_reorder<<<dim3(Ec * Dc * DEc / 2048), blk, 0, stream>>>(Wd, wb_d);

  // 1. LN1: x -> h_bf (bf16)
  ln_kernel<<<dim3(NTOK), blk, 0, stream>>>(x, ln1_g, ln1_b, h_bf);
  // 2. QKV GEMM -> head-major bf16 Q(x0.125)/K + transposed V directly
  gemm_bf16<0><<<dim3(3 * Dc / 128, NTOK / 128), blk, 0, stream>>>(
      h_bf, Dc, wb_in, in_b, nullptr, Qb, 0, Dc);
  // 3. MFMA attention (swapped 32x32, in-register softmax) -> Ob bf16
  attn_mfma<<<dim3(Bc * Hc * (Tc / 128)), blk, 0, stream>>>(Qb, Kb, Vt, Ob);
  // 4. out proj + bias + residual(x) -> out fp32
  gemm_bf16<1><<<dim3(Dc / 128, NTOK / 128), blk, 0, stream>>>(
      Ob, Dc, wb_out, out_b, x, out, Dc, Dc);
  // 5. LN2: out -> h_bf (h2)
  ln_kernel<<<dim3(NTOK), blk, 0, stream>>>(out, ln2_g, ln2_b, h_bf);
  // 6. router weights
  router_kernel<<<dim3(NTOK), blk, 0, stream>>>(h_bf, rw, log_temp, wts);
  // 7. fused gate+up GEMM: B = [wb_g; wb_u] as [4096,1024] -> hgu [8192,4096]
  gemm_bf16<2><<<dim3(2 * EDE / 128, NTOK / 128), blk, 0, stream>>>(
      h_bf, Dc, wb_g, nullptr, nullptr, hgu, 2 * EDE, Dc);
  // 8. act = silu(gate)*up*w, in place into gate half of hgu
  moe_act_kernel<<<dim3((int)((size_t)NTOK * EDE / 8 / 256)), blk, 0, stream>>>(
      hgu, wts);
  // 9. single down GEMM over concatenated experts (lda=4096, K=2048), += out
  gemm_bf16<3><<<dim3(Dc / 128, NTOK / 128), blk, 0, stream>>>(
      hgu, 2 * EDE, wb_d, nullptr, nullptr, out, Dc, EDE);
}

// Round 7
// 443.157 us; speedup vs baseline: 11.4508x; 1.0575x over previous
//
#include <hip/hip_runtime.h>
#include <hip/hip_bf16.h>
#include <cstddef>
#include <cstdint>

// Problem constants (match reference)
constexpr int Bc  = 4;
constexpr int Tc  = 2048;
constexpr int Dc  = 1024;
constexpr int Hc  = 16;
constexpr int Ec  = 8;     // experts
constexpr int DEc = 256;   // expert dim
constexpr int NTOK = Bc * Tc;          // 8192 tokens
constexpr int EDE = Ec * DEc;          // 2048

typedef __attribute__((ext_vector_type(8)))  short  s8v;   // 8 bf16 (4 VGPRs)
typedef __attribute__((ext_vector_type(4)))  float  f4v;   // 16x16 MFMA C/D
typedef __attribute__((ext_vector_type(16))) float  f16v;  // 32x32 MFMA C/D
typedef __attribute__((ext_vector_type(8)))  ushort u8v;
typedef __attribute__((ext_vector_type(4)))  ushort u4v;

constexpr float LOG2E = 1.44269504088896340736f;

__device__ inline ushort f2bf(float f) {  // fp32 -> bf16 bits, RNE
  union { float f; uint32_t u; } v; v.f = f;
  uint32_t r = v.u + 0x7FFFu + ((v.u >> 16) & 1u);
  return (ushort)(r >> 16);
}
__device__ inline float bf2f(ushort u) {
  union { uint32_t u; float f; } v; v.u = ((uint32_t)u) << 16;
  return v.f;
}
__device__ inline float exp2v(float x) {   // 2^x on the TRANS pipe
  float r; asm("v_exp_f32 %0, %1" : "=v"(r) : "v"(x)); return r;
}
__device__ inline float max3f(float a, float b, float c) {
  return fmaxf(fmaxf(a, b), c);             // clang fuses to v_max3_f32
}
// pair-reduce lane l <-> l^32 without DS ops (pure VALU)
__device__ inline float pmax32(float x) {
  float a = x, b = x;
  asm("v_permlane32_swap_b32 %0, %1" : "+v"(b), "+v"(a));
  return fmaxf(a, b);
}
__device__ inline float psum32(float x) {
  float a = x, b = x;
  asm("v_permlane32_swap_b32 %0, %1" : "+v"(b), "+v"(a));
  return a + b;
}

// async global->LDS, 16B per lane; LDS dest = wave-uniform base + lane*16
#define GLOAD_LDS(gsrc, ldst)                                        \
  __builtin_amdgcn_global_load_lds(                                  \
      (const __attribute__((address_space(1))) void*)(gsrc),         \
      (__attribute__((address_space(3))) void*)(ldst), 16, 0, 0)

// pack 2 f32 -> 1 u32 of 2 bf16 (lo = a, hi = b), RNE
__device__ inline uint32_t cvtpk(float a, float b) {
  uint32_t r;
  asm("v_cvt_pk_bf16_f32 %0, %1, %2" : "=v"(r) : "v"(a), "v"(b));
  return r;
}

// ---------------------------------------------------------------------------
// fp32 -> bf16 flat convert (weights); n multiple of 2048
// ---------------------------------------------------------------------------
__global__ __launch_bounds__(256)
void f32_to_bf16(const float* __restrict__ src, ushort* __restrict__ dst) {
  const size_t i = ((size_t)blockIdx.x * 256 + threadIdx.x) * 8;
  const float4 a = *(const float4*)(src + i);
  const float4 b = *(const float4*)(src + i + 4);
  u8v o;
  o[0] = f2bf(a.x); o[1] = f2bf(a.y); o[2] = f2bf(a.z); o[3] = f2bf(a.w);
  o[4] = f2bf(b.x); o[5] = f2bf(b.y); o[6] = f2bf(b.z); o[7] = f2bf(b.w);
  *(u8v*)(dst + i) = o;
}

// Wd [E,D,DE] fp32 -> Wdb [D, E*DE] bf16  (Wdb[d][e*256+f] = Wd[e][d][f])
__global__ __launch_bounds__(256)
void wd_reorder(const float* __restrict__ Wd, ushort* __restrict__ Wdb) {
  const size_t i = ((size_t)blockIdx.x * 256 + threadIdx.x) * 8;
  const int e = (int)(i >> 18);            // /(1024*256)
  const int d = (int)((i >> 8) & 1023);
  const int f = (int)(i & 255);
  const float4 a = *(const float4*)(Wd + i);
  const float4 b = *(const float4*)(Wd + i + 4);
  u8v o;
  o[0] = f2bf(a.x); o[1] = f2bf(a.y); o[2] = f2bf(a.z); o[3] = f2bf(a.w);
  o[4] = f2bf(b.x); o[5] = f2bf(b.y); o[6] = f2bf(b.z); o[7] = f2bf(b.w);
  *(u8v*)(Wdb + (size_t)d * EDE + e * DEc + f) = o;
}

// Wg/Wu [2048,1024] fp32 -> interleaved wb_gu [4096,1024] bf16:
// row r: j = (r>>5)*16 + (r&15); (r&16)==0 -> Wg[j], else Wu[j].
__global__ __launch_bounds__(256)
void wgu_reorder(const float* __restrict__ Wg, const float* __restrict__ Wu,
                 ushort* __restrict__ dst) {
  const size_t i = ((size_t)blockIdx.x * 256 + threadIdx.x) * 8;
  const int r = (int)(i >> 10), k = (int)(i & 1023);
  const int j = ((r >> 5) << 4) + (r & 15);
  const float* src = (r & 16) ? Wu : Wg;
  const float4 a = *(const float4*)(src + (size_t)j * Dc + k);
  const float4 b = *(const float4*)(src + (size_t)j * Dc + k + 4);
  u8v o;
  o[0] = f2bf(a.x); o[1] = f2bf(a.y); o[2] = f2bf(a.z); o[3] = f2bf(a.w);
  o[4] = f2bf(b.x); o[5] = f2bf(b.y); o[6] = f2bf(b.z); o[7] = f2bf(b.w);
  *(u8v*)(dst + i) = o;
}

// ---------------------------------------------------------------------------
// LayerNorm (+ optional fused router). One block per token row (D=1024).
// ROUTER=1: also computes logits=(h2@rw^T)/temp, top-2 sigmoid suppression,
// softmax -> wts[t][8]. Uses fp32 normalized values (pre-bf16-round).
// ---------------------------------------------------------------------------
template <int ROUTER>
__global__ __launch_bounds__(256)
void ln_kernel(const float* __restrict__ in, const float* __restrict__ g,
               const float* __restrict__ bt, ushort* __restrict__ out,
               const float* __restrict__ rw, const float* __restrict__ log_temp,
               float* __restrict__ wts) {
  const int row = blockIdx.x;
  const int tid = threadIdx.x;
  const float* xr = in + (size_t)row * Dc;
  float4 v = *(const float4*)(xr + tid * 4);
  float s  = v.x + v.y + v.z + v.w;
  float ss = v.x * v.x + v.y * v.y + v.z * v.z + v.w * v.w;
#pragma unroll
  for (int off = 32; off; off >>= 1) {
    s  += __shfl_xor(s, off);
    ss += __shfl_xor(ss, off);
  }
  __shared__ float red[8];
  const int w = tid >> 6;
  if ((tid & 63) == 0) { red[w] = s; red[4 + w] = ss; }
  __syncthreads();
  const float ts  = red[0] + red[1] + red[2] + red[3];
  const float tss = red[4] + red[5] + red[6] + red[7];
  const float mean = ts * (1.0f / Dc);
  const float var  = tss * (1.0f / Dc) - mean * mean;
  const float rstd = rsqrtf(var + 1e-5f);
  float4 gv = *(const float4*)(g + tid * 4);
  float4 bv = *(const float4*)(bt + tid * 4);
  const float n0 = (v.x - mean) * rstd * gv.x + bv.x;
  const float n1 = (v.y - mean) * rstd * gv.y + bv.y;
  const float n2 = (v.z - mean) * rstd * gv.z + bv.z;
  const float n3 = (v.w - mean) * rstd * gv.w + bv.w;
  u4v o;
  o[0] = f2bf(n0); o[1] = f2bf(n1); o[2] = f2bf(n2); o[3] = f2bf(n3);
  *(u4v*)(out + (size_t)row * Dc + tid * 4) = o;
  if constexpr (ROUTER) {
    float part[Ec];
#pragma unroll
    for (int e = 0; e < Ec; ++e) {
      float4 wv = *(const float4*)(rw + (size_t)e * Dc + tid * 4);
      part[e] = n0 * wv.x + n1 * wv.y + n2 * wv.z + n3 * wv.w;
    }
#pragma unroll
    for (int off = 32; off; off >>= 1) {
#pragma unroll
      for (int e = 0; e < Ec; ++e) part[e] += __shfl_xor(part[e], off);
    }
    __shared__ float red2[4][Ec];
    if ((tid & 63) == 0) {
#pragma unroll
      for (int e = 0; e < Ec; ++e) red2[w][e] = part[e];
    }
    __syncthreads();
    if (tid == 0) {
      const float lt = *log_temp;
      const float temp = log1pf(__expf(lt)) + 0.1f;
      float lg[Ec];
#pragma unroll
      for (int e = 0; e < Ec; ++e)
        lg[e] = (red2[0][e] + red2[1][e] + red2[2][e] + red2[3][e]) / temp;
      float m1 = -1e30f, m2 = -1e30f;
#pragma unroll
      for (int e = 0; e < Ec; ++e) {
        const float vv = lg[e];
        if (vv > m1) { m2 = m1; m1 = vv; }
        else if (vv > m2) { m2 = vv; }
      }
      float sl[Ec];
      float mx = -1e30f;
#pragma unroll
      for (int e = 0; e < Ec; ++e) {
        const float sup = 1.f / (1.f + __expf(-10.f * (lg[e] - m2)));
        sl[e] = lg[e] * sup;
        mx = fmaxf(mx, sl[e]);
      }
      float ssum = 0.f;
#pragma unroll
      for (int e = 0; e < Ec; ++e) {
        const float p = __expf(sl[e] - mx);
        sl[e] = p;
        ssum += p;
      }
      const float inv = 1.f / ssum;
#pragma unroll
      for (int e = 0; e < Ec; ++e) wts[(size_t)row * Ec + e] = sl[e] * inv;
    }
  }
}

// ---------------------------------------------------------------------------
// bf16 MFMA GEMM: C[M,N] = A[M,K] @ B[N,K]^T, m97 structure + XCD swizzle.
// 128x128 tile, BK=32, 256 thr = 4 waves (2x2), 4x4 frags of 16x16x32/wave.
// EPI: 0 = QKV scatter bf16 (bias, q*0.125*log2e, V transposed [bh][d][t])
//      1 = fp32 +bias+resid   3 = fp32 accumulate
//      4 = fused silu(gate)*up*wts -> act bf16 [NTOK,2048] (B interleaved)
// ---------------------------------------------------------------------------
template <int EPI>
__global__ __launch_bounds__(256)
void gemm_bf16(const ushort* __restrict__ A, int lda,
               const ushort* __restrict__ B,
               const float* __restrict__ bias, const float* __restrict__ resid,
               void* __restrict__ Cout, int ldc, int K) {
  __shared__ __align__(16) ushort As[128 * 32];
  __shared__ __align__(16) ushort Bs[128 * 32];
  const int tid = threadIdx.x;
  const int lane = tid & 63, w = tid >> 6;
  const int g = lane >> 4, c = lane & 15;
  // bijective XCD swizzle (all grids have nwg % 8 == 0)
  int bid = blockIdx.y * gridDim.x + blockIdx.x;
  const int qq = (gridDim.x * gridDim.y) >> 3;
  bid = (bid & 7) * qq + (bid >> 3);
  const int m0 = (bid / gridDim.x) * 128, n0 = (bid % gridDim.x) * 128;
  const int wm = (w >> 1) * 64, wn = (w & 1) * 64;
  const f4v fz = {0.f, 0.f, 0.f, 0.f};
  f4v acc[4][4];
#pragma unroll
  for (int i = 0; i < 4; ++i)
#pragma unroll
    for (int j = 0; j < 4; ++j) acc[i][j] = fz;

  int srow[2], skoff[2];
#pragma unroll
  for (int seg = 0; seg < 2; ++seg) {
    const int ci = seg * 256 + tid;
    srow[seg] = ci >> 2;
    skoff[seg] = 8 * ((ci & 3) ^ ((srow[seg] >> 1) & 3));
  }

  for (int k0 = 0; k0 < K; k0 += 32) {
#pragma unroll
    for (int seg = 0; seg < 2; ++seg) {
      const int ci = seg * 256 + tid;
      GLOAD_LDS(A + (size_t)(m0 + srow[seg]) * lda + k0 + skoff[seg], &As[ci * 8]);
      GLOAD_LDS(B + (size_t)(n0 + srow[seg]) * K + k0 + skoff[seg], &Bs[ci * 8]);
    }
    __syncthreads();
    s8v af[4], bf[4];
#pragma unroll
    for (int mi = 0; mi < 4; ++mi) {
      const int R = wm + mi * 16 + c;
      af[mi] = *(const s8v*)&As[R * 32 + 8 * (g ^ ((R >> 1) & 3))];
    }
#pragma unroll
    for (int ni = 0; ni < 4; ++ni) {
      const int R = wn + ni * 16 + c;
      bf[ni] = *(const s8v*)&Bs[R * 32 + 8 * (g ^ ((R >> 1) & 3))];
    }
#pragma unroll
    for (int mi = 0; mi < 4; ++mi)
#pragma unroll
      for (int ni = 0; ni < 4; ++ni)
        acc[mi][ni] = __builtin_amdgcn_mfma_f32_16x16x32_bf16(
            af[mi], bf[ni], acc[mi][ni], 0, 0, 0);
    __syncthreads();
  }

  // epilogue: C/D layout col=lane&15, row=(lane>>4)*4+reg  [m89-verified]
#pragma unroll
  for (int mi = 0; mi < 4; ++mi) {
    if constexpr (EPI == 4) {  // fused act: ni pairs (gate, up)
#pragma unroll
      for (int nip = 0; nip < 2; ++nip) {
        const int jbase = ((n0 + wn) >> 1) + nip * 16;  // 32-aligned
        const int e = jbase >> 8;
#pragma unroll
        for (int j = 0; j < 4; ++j) {
          const int row = m0 + wm + mi * 16 + g * 4 + j;
          const float wgt = bias[(size_t)row * Ec + e];  // bias = wts
          const float gv = acc[mi][2 * nip][j];
          const float uv = acc[mi][2 * nip + 1][j];
          const float av = (gv / (1.f + __expf(-gv))) * uv * wgt;
          ((ushort*)Cout)[(size_t)row * EDE + jbase + c] = f2bf(av);
        }
      }
    } else {
#pragma unroll
      for (int ni = 0; ni < 4; ++ni) {
        if constexpr (EPI == 0) {  // QKV scatter, head-major
          const int col = n0 + wn + ni * 16 + c;
          const int which = col >> 10, hh = (col >> 6) & 15, d = col & 63;
          const int row0 = m0 + wm + mi * 16 + g * 4;
          const int b = row0 >> 11, t0 = row0 & 2047;
          const float bs = bias[col];
          ushort* base = (ushort*)Cout;
          if (which == 2) {  // V transposed: Vt[bh][d][t], 4 consecutive t
            u4v pk;
#pragma unroll
            for (int j = 0; j < 4; ++j) pk[j] = f2bf(acc[mi][ni][j] + bs);
            *(u4v*)&base[2 * (size_t)NTOK * Dc +
                         (((size_t)(b * Hc + hh)) * 64 + d) * Tc + t0] = pk;
          } else {
            const float qs = (which == 0) ? 0.125f * LOG2E : 1.f;
            const size_t off = (size_t)which * ((size_t)NTOK * Dc);
#pragma unroll
            for (int j = 0; j < 4; ++j)
              base[off + (((size_t)(b * Hc + hh)) * Tc + t0 + j) * 64 + d] =
                  f2bf((acc[mi][ni][j] + bs) * qs);
          }
        } else {
#pragma unroll
          for (int j = 0; j < 4; ++j) {
            const int row = m0 + wm + mi * 16 + g * 4 + j;
            const int col = n0 + wn + ni * 16 + c;
            float v = acc[mi][ni][j];
            if constexpr (EPI == 1) {
              v += bias[col] + resid[(size_t)row * ldc + col];
              ((float*)Cout)[(size_t)row * ldc + col] = v;
            } else {
              ((float*)Cout)[(size_t)row * ldc + col] += v;
            }
          }
        }
      }
    }
  }
}

// ---------------------------------------------------------------------------
// MFMA flash attention, swapped-operand 32x32, exp2-domain softmax,
// double-buffered 2-phase K/V staging (prefetch next chunk before compute).
// Q is pre-scaled by 0.125*log2e so p = v_exp_f32(s - m) directly.
// ---------------------------------------------------------------------------
__global__ __launch_bounds__(256)
void attn_mfma(const ushort* __restrict__ Qb, const ushort* __restrict__ Kb,
               const ushort* __restrict__ Vt, ushort* __restrict__ Ob) {
  __shared__ __align__(16) ushort Ksm[2][64 * 64];   // [key][d]  swizzled
  __shared__ __align__(16) ushort Vtsm[2][64 * 64];  // [d][key]  swizzled
  const int tid = threadIdx.x;
  const int lane = tid & 63, w = tid >> 6;
  const int ql = lane & 31, hi = lane >> 5;
  int bid = blockIdx.x;
  bid = (bid & 7) * 128 + (bid >> 3);       // XCD swizzle (grid = 1024)
  const int qt = bid & 15, bh = bid >> 4;
  const ushort* Qh = Qb + (size_t)bh * Tc * 64;
  const ushort* Kh = Kb + (size_t)bh * Tc * 64;
  const ushort* Vth = Vt + (size_t)bh * 64 * Tc;   // [d][t]
  const int qrow = qt * 128 + w * 32 + ql;
  s8v qf[4];
#pragma unroll
  for (int ds = 0; ds < 4; ++ds)
    qf[ds] = *(const s8v*)(Qh + (size_t)qrow * 64 + ds * 16 + hi * 8);
  f16v accO0, accO1;
#pragma unroll
  for (int i = 0; i < 16; ++i) { accO0[i] = 0.f; accO1[i] = 0.f; }
  float mold = -1e30f, lsum = 0.f;
  int srow[2], soff[2];
#pragma unroll
  for (int seg = 0; seg < 2; ++seg) {
    const int ci = seg * 256 + tid;
    srow[seg] = ci >> 3;
    soff[seg] = ((ci & 7) * 8) ^ ((srow[seg] & 7) << 3);
  }
  auto stage = [&](int buf, int j0) {
#pragma unroll
    for (int seg = 0; seg < 2; ++seg) {
      const int ci = seg * 256 + tid;
      GLOAD_LDS(Kh + (size_t)(j0 + srow[seg]) * 64 + soff[seg], &Ksm[buf][ci * 8]);
      GLOAD_LDS(Vth + (size_t)srow[seg] * Tc + j0 + soff[seg], &Vtsm[buf][ci * 8]);
    }
  };

  stage(0, 0);
  __syncthreads();            // compiler drains vmcnt before s_barrier
  int cur = 0;
  for (int j0 = 0; j0 < Tc; j0 += 64) {
    if (j0 + 64 < Tc) stage(cur ^ 1, j0 + 64);   // prefetch next chunk
    // S^T[key][q]: A = K-frag (m=key), B = Q-frag (n=q)
    f16v s0, s1;
#pragma unroll
    for (int i = 0; i < 16; ++i) { s0[i] = 0.f; s1[i] = 0.f; }
    __builtin_amdgcn_s_setprio(1);
#pragma unroll
    for (int ds = 0; ds < 4; ++ds) {
      const int col = (ds * 16 + hi * 8);
      const int r0 = ql;
      s8v kf0 = *(const s8v*)&Ksm[cur][r0 * 64 + (col ^ ((r0 & 7) << 3))];
      s0 = __builtin_amdgcn_mfma_f32_32x32x16_bf16(kf0, qf[ds], s0, 0, 0, 0);
      const int r1 = 32 + ql;
      s8v kf1 = *(const s8v*)&Ksm[cur][r1 * 64 + (col ^ ((r1 & 7) << 3))];
      s1 = __builtin_amdgcn_mfma_f32_32x32x16_bf16(kf1, qf[ds], s1, 0, 0, 0);
    }
    __builtin_amdgcn_s_setprio(0);
    // softmax in exp2 domain; 4 independent max3 chains then pair-swap
    float cc0 = fmaxf(s0[0], s1[0]), cc1 = fmaxf(s0[1], s1[1]);
    float cc2 = fmaxf(s0[2], s1[2]), cc3 = fmaxf(s0[3], s1[3]);
#pragma unroll
    for (int i = 4; i < 16; i += 4) {
      cc0 = max3f(cc0, s0[i + 0], s1[i + 0]);
      cc1 = max3f(cc1, s0[i + 1], s1[i + 1]);
      cc2 = max3f(cc2, s0[i + 2], s1[i + 2]);
      cc3 = max3f(cc3, s0[i + 3], s1[i + 3]);
    }
    float mx = pmax32(fmaxf(max3f(cc0, cc1, cc2), cc3));
    const bool need = mx > mold + 11.5416f;    // 8 * log2(e)
    if (__any((int)need)) {
      const float mnew = fmaxf(mold, mx);
      const float sc = exp2v(mold - mnew);
      lsum *= sc;
#pragma unroll
      for (int i = 0; i < 16; ++i) { accO0[i] *= sc; accO1[i] *= sc; }
      mold = mnew;
    }
    float r0s = 0.f, r1s = 0.f, r2s = 0.f, r3s = 0.f;
#pragma unroll
    for (int i = 0; i < 16; i += 4) {
      s0[i+0] = exp2v(s0[i+0] - mold); r0s += s0[i+0];
      s0[i+1] = exp2v(s0[i+1] - mold); r1s += s0[i+1];
      s0[i+2] = exp2v(s0[i+2] - mold); r2s += s0[i+2];
      s0[i+3] = exp2v(s0[i+3] - mold); r3s += s0[i+3];
      s1[i+0] = exp2v(s1[i+0] - mold); r0s += s1[i+0];
      s1[i+1] = exp2v(s1[i+1] - mold); r1s += s1[i+1];
      s1[i+2] = exp2v(s1[i+2] - mold); r2s += s1[i+2];
      s1[i+3] = exp2v(s1[i+3] - mold); r3s += s1[i+3];
    }
    lsum += psum32((r0s + r1s) + (r2s + r3s));
    // build P B-fragments in-register (cvt_pk + permlane32_swap)
    s8v pa[4];
#pragma unroll
    for (int s = 0; s < 4; ++s) {
      const f16v st = (s < 2) ? s0 : s1;
      const int mA = 2 * (s & 1);
      uint32_t a0 = cvtpk(st[4 * mA + 0], st[4 * mA + 1]);
      uint32_t a1 = cvtpk(st[4 * mA + 2], st[4 * mA + 3]);
      uint32_t b0 = cvtpk(st[4 * mA + 4], st[4 * mA + 5]);
      uint32_t b1 = cvtpk(st[4 * mA + 6], st[4 * mA + 7]);
      asm("v_permlane32_swap_b32 %0, %1" : "+v"(b0), "+v"(a0));
      asm("v_permlane32_swap_b32 %0, %1" : "+v"(b1), "+v"(a1));
      union { uint32_t u[4]; s8v v; } pk;
      pk.u[0] = a0; pk.u[1] = a1; pk.u[2] = b0; pk.u[3] = b1;
      pa[s] = pk.v;
    }
    // PV: O^T[d][q] += V^T P^T
    __builtin_amdgcn_s_setprio(1);
#pragma unroll
    for (int s = 0; s < 4; ++s) {
      const int col = (s * 16 + hi * 8);
      const int r0 = ql;
      s8v vf0 = *(const s8v*)&Vtsm[cur][r0 * 64 + (col ^ ((r0 & 7) << 3))];
      accO0 = __builtin_amdgcn_mfma_f32_32x32x16_bf16(vf0, pa[s], accO0, 0, 0, 0);
      const int r1 = 32 + ql;
      s8v vf1 = *(const s8v*)&Vtsm[cur][r1 * 64 + (col ^ ((r1 & 7) << 3))];
      accO1 = __builtin_amdgcn_mfma_f32_32x32x16_bf16(vf1, pa[s], accO1, 0, 0, 0);
    }
    __builtin_amdgcn_s_setprio(0);
    __syncthreads();          // drains prefetch vmcnt; buffers safe to swap
    cur ^= 1;
  }
  // epilogue: accO col = q = ql; row = d_local = (reg&3)+8*(reg>>2)+4*hi
  const int h = bh & 15, b = bh >> 4;
  const int tok = b * Tc + qt * 128 + w * 32 + ql;
  const float inv = 1.f / lsum;
  ushort* orow = Ob + (size_t)tok * Dc + h * 64;
#pragma unroll
  for (int dt = 0; dt < 2; ++dt) {
    const f16v ac = dt ? accO1 : accO0;
#pragma unroll
    for (int rq = 0; rq < 4; ++rq) {
      u4v pk;
#pragma unroll
      for (int j = 0; j < 4; ++j) pk[j] = f2bf(ac[4 * rq + j] * inv);
      *(u4v*)&orow[dt * 32 + 8 * rq + 4 * hi] = pk;
    }
  }
}

// ---------------------------------------------------------------------------
extern "C" void kernel_launch(void* const* d_in, const int* in_sizes, int n_in,
                              void* d_out, int out_size, void* d_ws, size_t ws_size,
                              hipStream_t stream) {
  (void)in_sizes; (void)n_in; (void)out_size; (void)ws_size;
  const float* x        = (const float*)d_in[0];
  const float* ln1_g    = (const float*)d_in[1];
  const float* ln1_b    = (const float*)d_in[2];
  const float* in_w     = (const float*)d_in[3];
  const float* in_b     = (const float*)d_in[4];
  const float* out_w    = (const float*)d_in[5];
  const float* out_b    = (const float*)d_in[6];
  const float* ln2_g    = (const float*)d_in[7];
  const float* ln2_b    = (const float*)d_in[8];
  const float* rw       = (const float*)d_in[9];
  const float* log_temp = (const float*)d_in[10];
  const float* Wg       = (const float*)d_in[11];
  const float* Wu       = (const float*)d_in[12];
  const float* Wd       = (const float*)d_in[13];
  float* out = (float*)d_out;

  // Workspace (ushorts), total ~138 MiB:
  ushort* h_bf   = (ushort*)d_ws;                       // NTOK*1024   16 MiB
  ushort* Qb     = h_bf   + (size_t)NTOK * Dc;          // 16 MiB
  ushort* Kb     = Qb     + (size_t)NTOK * Dc;          // 16 MiB
  ushort* Vt     = Kb     + (size_t)NTOK * Dc;          // 16 MiB ([bh][d][t])
  ushort* Ob     = Vt     + (size_t)NTOK * Dc;          // 16 MiB
  ushort* act    = Ob     + (size_t)NTOK * Dc;          // NTOK*2048   32 MiB
  ushort* wb_in  = act    + (size_t)NTOK * EDE;         // 3072*1024    6 MiB
  ushort* wb_out = wb_in  + (size_t)3 * Dc * Dc;        // 1024*1024    2 MiB
  ushort* wb_gu  = wb_out + (size_t)Dc * Dc;            // 4096*1024    8 MiB
  ushort* wb_d   = wb_gu  + (size_t)2 * EDE * Dc;       // 1024*2048    4 MiB
  float*  wts    = (float*)(wb_d + (size_t)Dc * EDE);   // NTOK*8     0.25 MiB

  const dim3 blk(256);

  // 0. weight conversions (every call; deterministic)
  f32_to_bf16<<<dim3(3 * Dc * Dc / 2048), blk, 0, stream>>>(in_w, wb_in);
  f32_to_bf16<<<dim3(Dc * Dc / 2048), blk, 0, stream>>>(out_w, wb_out);
  wgu_reorder<<<dim3(2 * EDE * Dc / 2048), blk, 0, stream>>>(Wg, Wu, wb_gu);
  wd_reorder<<<dim3(Ec * Dc * DEc / 2048), blk, 0, stream>>>(Wd, wb_d);

  // 1. LN1: x -> h_bf (bf16)
  ln_kernel<0><<<dim3(NTOK), blk, 0, stream>>>(x, ln1_g, ln1_b, h_bf,
                                               nullptr, nullptr, nullptr);
  // 2. QKV GEMM -> head-major bf16 Q(x0.125*log2e)/K + transposed V
  gemm_bf16<0><<<dim3(3 * Dc / 128, NTOK / 128), blk, 0, stream>>>(
      h_bf, Dc, wb_in, in_b, nullptr, Qb, 0, Dc);
  // 3. MFMA attention (swapped 32x32, exp2 softmax, 2-phase) -> Ob bf16
  attn_mfma<<<dim3(Bc * Hc * (Tc / 128)), blk, 0, stream>>>(Qb, Kb, Vt, Ob);
  // 4. out proj + bias + residual(x) -> out fp32
  gemm_bf16<1><<<dim3(Dc / 128, NTOK / 128), blk, 0, stream>>>(
      Ob, Dc, wb_out, out_b, x, out, Dc, Dc);
  // 5. LN2 + fused router: out -> h_bf (h2), wts
  ln_kernel<1><<<dim3(NTOK), blk, 0, stream>>>(out, ln2_g, ln2_b, h_bf,
                                               rw, log_temp, wts);
  // 6. fused gate+up GEMM + silu*up*wts epilogue -> act bf16 [NTOK,2048]
  gemm_bf16<4><<<dim3(2 * EDE / 128, NTOK / 128), blk, 0, stream>>>(
      h_bf, Dc, wb_gu, wts, nullptr, act, EDE, Dc);
  // 7. single down GEMM over concatenated experts (K=2048), += into out
  gemm_bf16<3><<<dim3(Dc / 128, NTOK / 128), blk, 0, stream>>>(
      act, EDE, wb_d, nullptr, nullptr, out, Dc, EDE);
}

// Round 8
// 413.054 us; speedup vs baseline: 12.2853x; 1.0729x over previous
//
#include <hip/hip_runtime.h>
#include <hip/hip_bf16.h>
#include <cstddef>
#include <cstdint>

// Problem constants (match reference)
constexpr int Bc  = 4;
constexpr int Tc  = 2048;
constexpr int Dc  = 1024;
constexpr int Hc  = 16;
constexpr int Ec  = 8;     // experts
constexpr int DEc = 256;   // expert dim
constexpr int NTOK = Bc * Tc;          // 8192 tokens
constexpr int EDE = Ec * DEc;          // 2048

typedef __attribute__((ext_vector_type(8)))  short  s8v;   // 8 bf16 (4 VGPRs)
typedef __attribute__((ext_vector_type(4)))  float  f4v;   // 16x16 MFMA C/D
typedef __attribute__((ext_vector_type(16))) float  f16v;  // 32x32 MFMA C/D
typedef __attribute__((ext_vector_type(8)))  ushort u8v;
typedef __attribute__((ext_vector_type(4)))  ushort u4v;

constexpr float LOG2E = 1.44269504088896340736f;

__device__ inline ushort f2bf(float f) {  // fp32 -> bf16 bits, RNE
  union { float f; uint32_t u; } v; v.f = f;
  uint32_t r = v.u + 0x7FFFu + ((v.u >> 16) & 1u);
  return (ushort)(r >> 16);
}
__device__ inline float bf2f(ushort u) {
  union { uint32_t u; float f; } v; v.u = ((uint32_t)u) << 16;
  return v.f;
}
__device__ inline float exp2v(float x) {   // 2^x on the TRANS pipe
  float r; asm("v_exp_f32 %0, %1" : "=v"(r) : "v"(x)); return r;
}
__device__ inline float max3f(float a, float b, float c) {
  return fmaxf(fmaxf(a, b), c);             // clang fuses to v_max3_f32
}
// pair-reduce lane l <-> l^32 without DS ops (pure VALU)
__device__ inline float pmax32(float x) {
  float a = x, b = x;
  asm("v_permlane32_swap_b32 %0, %1" : "+v"(b), "+v"(a));
  return fmaxf(a, b);
}
__device__ inline float psum32(float x) {
  float a = x, b = x;
  asm("v_permlane32_swap_b32 %0, %1" : "+v"(b), "+v"(a));
  return a + b;
}

// async global->LDS, 16B per lane; LDS dest = wave-uniform base + lane*16
#define GLOAD_LDS(gsrc, ldst)                                        \
  __builtin_amdgcn_global_load_lds(                                  \
      (const __attribute__((address_space(1))) void*)(gsrc),         \
      (__attribute__((address_space(3))) void*)(ldst), 16, 0, 0)

// pack 2 f32 -> 1 u32 of 2 bf16 (lo = a, hi = b), RNE
__device__ inline uint32_t cvtpk(float a, float b) {
  uint32_t r;
  asm("v_cvt_pk_bf16_f32 %0, %1, %2" : "=v"(r) : "v"(a), "v"(b));
  return r;
}

// ---------------------------------------------------------------------------
// fp32 -> bf16 flat convert (weights); n multiple of 2048
// ---------------------------------------------------------------------------
__global__ __launch_bounds__(256)
void f32_to_bf16(const float* __restrict__ src, ushort* __restrict__ dst) {
  const size_t i = ((size_t)blockIdx.x * 256 + threadIdx.x) * 8;
  const float4 a = *(const float4*)(src + i);
  const float4 b = *(const float4*)(src + i + 4);
  u8v o;
  o[0] = f2bf(a.x); o[1] = f2bf(a.y); o[2] = f2bf(a.z); o[3] = f2bf(a.w);
  o[4] = f2bf(b.x); o[5] = f2bf(b.y); o[6] = f2bf(b.z); o[7] = f2bf(b.w);
  *(u8v*)(dst + i) = o;
}

// Wd [E,D,DE] fp32 -> Wdb [D, E*DE] bf16  (Wdb[d][e*256+f] = Wd[e][d][f])
__global__ __launch_bounds__(256)
void wd_reorder(const float* __restrict__ Wd, ushort* __restrict__ Wdb) {
  const size_t i = ((size_t)blockIdx.x * 256 + threadIdx.x) * 8;
  const int e = (int)(i >> 18);            // /(1024*256)
  const int d = (int)((i >> 8) & 1023);
  const int f = (int)(i & 255);
  const float4 a = *(const float4*)(Wd + i);
  const float4 b = *(const float4*)(Wd + i + 4);
  u8v o;
  o[0] = f2bf(a.x); o[1] = f2bf(a.y); o[2] = f2bf(a.z); o[3] = f2bf(a.w);
  o[4] = f2bf(b.x); o[5] = f2bf(b.y); o[6] = f2bf(b.z); o[7] = f2bf(b.w);
  *(u8v*)(Wdb + (size_t)d * EDE + e * DEc + f) = o;
}

// Wg/Wu [2048,1024] fp32 -> interleaved wb_gu [4096,1024] bf16:
// row r: j = (r>>5)*16 + (r&15); (r&16)==0 -> Wg[j], else Wu[j].
__global__ __launch_bounds__(256)
void wgu_reorder(const float* __restrict__ Wg, const float* __restrict__ Wu,
                 ushort* __restrict__ dst) {
  const size_t i = ((size_t)blockIdx.x * 256 + threadIdx.x) * 8;
  const int r = (int)(i >> 10), k = (int)(i & 1023);
  const int j = ((r >> 5) << 4) + (r & 15);
  const float* src = (r & 16) ? Wu : Wg;
  const float4 a = *(const float4*)(src + (size_t)j * Dc + k);
  const float4 b = *(const float4*)(src + (size_t)j * Dc + k + 4);
  u8v o;
  o[0] = f2bf(a.x); o[1] = f2bf(a.y); o[2] = f2bf(a.z); o[3] = f2bf(a.w);
  o[4] = f2bf(b.x); o[5] = f2bf(b.y); o[6] = f2bf(b.z); o[7] = f2bf(b.w);
  *(u8v*)(dst + i) = o;
}

// ---------------------------------------------------------------------------
// LayerNorm (+ optional fused router). One block per token row (D=1024).
// ---------------------------------------------------------------------------
template <int ROUTER>
__global__ __launch_bounds__(256)
void ln_kernel(const float* __restrict__ in, const float* __restrict__ g,
               const float* __restrict__ bt, ushort* __restrict__ out,
               const float* __restrict__ rw, const float* __restrict__ log_temp,
               float* __restrict__ wts) {
  const int row = blockIdx.x;
  const int tid = threadIdx.x;
  const float* xr = in + (size_t)row * Dc;
  float4 v = *(const float4*)(xr + tid * 4);
  float s  = v.x + v.y + v.z + v.w;
  float ss = v.x * v.x + v.y * v.y + v.z * v.z + v.w * v.w;
#pragma unroll
  for (int off = 32; off; off >>= 1) {
    s  += __shfl_xor(s, off);
    ss += __shfl_xor(ss, off);
  }
  __shared__ float red[8];
  const int w = tid >> 6;
  if ((tid & 63) == 0) { red[w] = s; red[4 + w] = ss; }
  __syncthreads();
  const float ts  = red[0] + red[1] + red[2] + red[3];
  const float tss = red[4] + red[5] + red[6] + red[7];
  const float mean = ts * (1.0f / Dc);
  const float var  = tss * (1.0f / Dc) - mean * mean;
  const float rstd = rsqrtf(var + 1e-5f);
  float4 gv = *(const float4*)(g + tid * 4);
  float4 bv = *(const float4*)(bt + tid * 4);
  const float n0 = (v.x - mean) * rstd * gv.x + bv.x;
  const float n1 = (v.y - mean) * rstd * gv.y + bv.y;
  const float n2 = (v.z - mean) * rstd * gv.z + bv.z;
  const float n3 = (v.w - mean) * rstd * gv.w + bv.w;
  u4v o;
  o[0] = f2bf(n0); o[1] = f2bf(n1); o[2] = f2bf(n2); o[3] = f2bf(n3);
  *(u4v*)(out + (size_t)row * Dc + tid * 4) = o;
  if constexpr (ROUTER) {
    float part[Ec];
#pragma unroll
    for (int e = 0; e < Ec; ++e) {
      float4 wv = *(const float4*)(rw + (size_t)e * Dc + tid * 4);
      part[e] = n0 * wv.x + n1 * wv.y + n2 * wv.z + n3 * wv.w;
    }
#pragma unroll
    for (int off = 32; off; off >>= 1) {
#pragma unroll
      for (int e = 0; e < Ec; ++e) part[e] += __shfl_xor(part[e], off);
    }
    __shared__ float red2[4][Ec];
    if ((tid & 63) == 0) {
#pragma unroll
      for (int e = 0; e < Ec; ++e) red2[w][e] = part[e];
    }
    __syncthreads();
    if (tid == 0) {
      const float lt = *log_temp;
      const float temp = log1pf(__expf(lt)) + 0.1f;
      float lg[Ec];
#pragma unroll
      for (int e = 0; e < Ec; ++e)
        lg[e] = (red2[0][e] + red2[1][e] + red2[2][e] + red2[3][e]) / temp;
      float m1 = -1e30f, m2 = -1e30f;
#pragma unroll
      for (int e = 0; e < Ec; ++e) {
        const float vv = lg[e];
        if (vv > m1) { m2 = m1; m1 = vv; }
        else if (vv > m2) { m2 = vv; }
      }
      float sl[Ec];
      float mx = -1e30f;
#pragma unroll
      for (int e = 0; e < Ec; ++e) {
        const float sup = 1.f / (1.f + __expf(-10.f * (lg[e] - m2)));
        sl[e] = lg[e] * sup;
        mx = fmaxf(mx, sl[e]);
      }
      float ssum = 0.f;
#pragma unroll
      for (int e = 0; e < Ec; ++e) {
        const float p = __expf(sl[e] - mx);
        sl[e] = p;
        ssum += p;
      }
      const float inv = 1.f / ssum;
#pragma unroll
      for (int e = 0; e < Ec; ++e) wts[(size_t)row * Ec + e] = sl[e] * inv;
    }
  }
}

// ---------------------------------------------------------------------------
// 256x256 8-phase bf16 GEMM (T3+T4): BK=64, 512 thr = 8 waves (2Mx4N),
// double-buffered 128KiB LDS, raw s_barrier + counted vmcnt (never 0 in
// steady state), setprio around MFMA clusters. C = A[M,K] @ B[N,K]^T.
// Issue order per tile t (filling buf for t+1): p0:B0,B1 p1:B2,B3 p2:A0,A2
// p3:A1,A3. Next tile phase 0 reads all B + A-issues 0,2 -> vmcnt(2) at
// boundary; phase 2 reads A-issues 1,3 -> vmcnt(4) at phase-1 end.
// EPI: 0 = QKV scatter   4 = fused silu(gate)*up*wts (B row-interleaved)
// ---------------------------------------------------------------------------
template <int EPI>
__global__ __launch_bounds__(512, 2)
void gemm256(const ushort* __restrict__ A, int lda,
             const ushort* __restrict__ B,
             const float* __restrict__ bias,
             void* __restrict__ Cout, int K) {
  __shared__ __align__(16) ushort Asm[2][256 * 64];
  __shared__ __align__(16) ushort Bsm[2][256 * 64];
  const int tid = threadIdx.x;
  const int lane = tid & 63, w = tid >> 6;
  const int g = lane >> 4, c = lane & 15;
  const int wr = w >> 2, wc = w & 3;
  int bid = blockIdx.y * gridDim.x + blockIdx.x;
  const int qq = (gridDim.x * gridDim.y) >> 3;
  bid = (bid & 7) * qq + (bid >> 3);
  const int m0 = (bid / gridDim.x) * 256, n0 = (bid % gridDim.x) * 256;
  f4v acc[8][4];
#pragma unroll
  for (int i = 0; i < 8; ++i)
#pragma unroll
    for (int j = 0; j < 4; ++j) acc[i][j] = f4v{0.f, 0.f, 0.f, 0.f};

  // staging geometry: issue i covers rows i*64..i*64+63 of the tile
  const int srow = tid >> 3;                       // 0..63
  const int koff = 8 * ((tid & 7) ^ (srow & 7));   // pre-swizzled k slot

#define STAGE_A(buf, kt, i)                                                  \
  GLOAD_LDS(A + (size_t)(m0 + (i) * 64 + srow) * lda + (kt) * 64 + koff,     \
            &Asm[buf][((i) * 512 + tid) * 8])
#define STAGE_B(buf, kt, i)                                                  \
  GLOAD_LDS(B + (size_t)(n0 + (i) * 64 + srow) * K + (kt) * 64 + koff,       \
            &Bsm[buf][((i) * 512 + tid) * 8])

  // fragment readers (XOR-swizzled)
#define RD_A(buf, mi, ks)                                                    \
  (*(const s8v*)&Asm[buf][(wr * 128 + (mi) * 16 + c) * 64 +                  \
      8 * (((ks) * 4 + g) ^ ((wr * 128 + (mi) * 16 + c) & 7))])
#define RD_B(buf, ni, ks)                                                    \
  (*(const s8v*)&Bsm[buf][(wc * 64 + (ni) * 16 + c) * 64 +                   \
      8 * (((ks) * 4 + g) ^ ((wc * 64 + (ni) * 16 + c) & 7))])

  const int NT = K >> 6;
  // prologue: stage tile 0 fully, drain, barrier
  STAGE_B(0, 0, 0); STAGE_B(0, 0, 1); STAGE_B(0, 0, 2); STAGE_B(0, 0, 3);
  STAGE_A(0, 0, 0); STAGE_A(0, 0, 2); STAGE_A(0, 0, 1); STAGE_A(0, 0, 3);
  asm volatile("s_waitcnt vmcnt(0)" ::: "memory");
  __builtin_amdgcn_s_barrier();

  for (int t = 0; t < NT; ++t) {
    const int cur = t & 1, nxt = cur ^ 1;
    const bool st = (t + 1 < NT);
    s8v bf[2][4], af[2][2];
    // ---- phase 0: read all B-frags + A mi 0,1; stage B0,B1 ----
#pragma unroll
    for (int ks = 0; ks < 2; ++ks) {
#pragma unroll
      for (int ni = 0; ni < 4; ++ni) bf[ks][ni] = RD_B(cur, ni, ks);
      af[ks][0] = RD_A(cur, 0, ks); af[ks][1] = RD_A(cur, 1, ks);
    }
    if (st) { STAGE_B(nxt, t + 1, 0); STAGE_B(nxt, t + 1, 1); }
    __builtin_amdgcn_s_barrier();
    __builtin_amdgcn_s_setprio(1);
#pragma unroll
    for (int ks = 0; ks < 2; ++ks)
#pragma unroll
      for (int q = 0; q < 2; ++q)
#pragma unroll
        for (int ni = 0; ni < 4; ++ni)
          acc[q][ni] = __builtin_amdgcn_mfma_f32_16x16x32_bf16(
              af[ks][q], bf[ks][ni], acc[q][ni], 0, 0, 0);
    __builtin_amdgcn_s_setprio(0);
    __builtin_amdgcn_s_barrier();
    // ---- phase 1: A mi 2,3; stage B2,B3; vmcnt(4) validates A-issues 1,3 ----
#pragma unroll
    for (int ks = 0; ks < 2; ++ks) {
      af[ks][0] = RD_A(cur, 2, ks); af[ks][1] = RD_A(cur, 3, ks);
    }
    if (st) { STAGE_B(nxt, t + 1, 2); STAGE_B(nxt, t + 1, 3); }
    __builtin_amdgcn_s_barrier();
    __builtin_amdgcn_s_setprio(1);
#pragma unroll
    for (int ks = 0; ks < 2; ++ks)
#pragma unroll
      for (int q = 0; q < 2; ++q)
#pragma unroll
        for (int ni = 0; ni < 4; ++ni)
          acc[2 + q][ni] = __builtin_amdgcn_mfma_f32_16x16x32_bf16(
              af[ks][q], bf[ks][ni], acc[2 + q][ni], 0, 0, 0);
    __builtin_amdgcn_s_setprio(0);
    if (st) asm volatile("s_waitcnt vmcnt(4)" ::: "memory");
    else    asm volatile("s_waitcnt vmcnt(0)" ::: "memory");
    __builtin_amdgcn_s_barrier();
    // ---- phase 2: A mi 4,5; stage A0,A2 ----
#pragma unroll
    for (int ks = 0; ks < 2; ++ks) {
      af[ks][0] = RD_A(cur, 4, ks); af[ks][1] = RD_A(cur, 5, ks);
    }
    if (st) { STAGE_A(nxt, t + 1, 0); STAGE_A(nxt, t + 1, 2); }
    __builtin_amdgcn_s_barrier();
    __builtin_amdgcn_s_setprio(1);
#pragma unroll
    for (int ks = 0; ks < 2; ++ks)
#pragma unroll
      for (int q = 0; q < 2; ++q)
#pragma unroll
        for (int ni = 0; ni < 4; ++ni)
          acc[4 + q][ni] = __builtin_amdgcn_mfma_f32_16x16x32_bf16(
              af[ks][q], bf[ks][ni], acc[4 + q][ni], 0, 0, 0);
    __builtin_amdgcn_s_setprio(0);
    __builtin_amdgcn_s_barrier();
    // ---- phase 3: A mi 6,7; stage A1,A3; boundary vmcnt(2) ----
#pragma unroll
    for (int ks = 0; ks < 2; ++ks) {
      af[ks][0] = RD_A(cur, 6, ks); af[ks][1] = RD_A(cur, 7, ks);
    }
    if (st) { STAGE_A(nxt, t + 1, 1); STAGE_A(nxt, t + 1, 3); }
    __builtin_amdgcn_s_barrier();
    __builtin_amdgcn_s_setprio(1);
#pragma unroll
    for (int ks = 0; ks < 2; ++ks)
#pragma unroll
      for (int q = 0; q < 2; ++q)
#pragma unroll
        for (int ni = 0; ni < 4; ++ni)
          acc[6 + q][ni] = __builtin_amdgcn_mfma_f32_16x16x32_bf16(
              af[ks][q], bf[ks][ni], acc[6 + q][ni], 0, 0, 0);
    __builtin_amdgcn_s_setprio(0);
    if (st) asm volatile("s_waitcnt vmcnt(2)" ::: "memory");
    __builtin_amdgcn_s_barrier();
  }
#undef STAGE_A
#undef STAGE_B
#undef RD_A
#undef RD_B

  // epilogue: C/D layout col=lane&15, row=(lane>>4)*4+reg  [m89-verified]
#pragma unroll
  for (int mi = 0; mi < 8; ++mi) {
    if constexpr (EPI == 4) {  // fused act: ni pairs (gate, up)
#pragma unroll
      for (int nip = 0; nip < 2; ++nip) {
        const int jbase = ((n0 + wc * 64) >> 1) + nip * 16;
        const int e = jbase >> 8;
#pragma unroll
        for (int j = 0; j < 4; ++j) {
          const int row = m0 + wr * 128 + mi * 16 + g * 4 + j;
          const float wgt = bias[(size_t)row * Ec + e];  // bias = wts
          const float gv = acc[mi][2 * nip][j];
          const float uv = acc[mi][2 * nip + 1][j];
          const float av = (gv / (1.f + __expf(-gv))) * uv * wgt;
          ((ushort*)Cout)[(size_t)row * EDE + jbase + c] = f2bf(av);
        }
      }
    } else {  // EPI == 0: QKV scatter, head-major
#pragma unroll
      for (int ni = 0; ni < 4; ++ni) {
        const int col = n0 + wc * 64 + ni * 16 + c;
        const int which = col >> 10, hh = (col >> 6) & 15, d = col & 63;
        const int row0 = m0 + wr * 128 + mi * 16 + g * 4;
        const int b = row0 >> 11, t0 = row0 & 2047;
        const float bs = bias[col];
        ushort* base = (ushort*)Cout;
        if (which == 2) {  // V transposed: Vt[bh][d][t]
          u4v pk;
#pragma unroll
          for (int j = 0; j < 4; ++j) pk[j] = f2bf(acc[mi][ni][j] + bs);
          *(u4v*)&base[2 * (size_t)NTOK * Dc +
                       (((size_t)(b * Hc + hh)) * 64 + d) * Tc + t0] = pk;
        } else {
          const float qs = (which == 0) ? 0.125f * LOG2E : 1.f;
          const size_t off = (size_t)which * ((size_t)NTOK * Dc);
#pragma unroll
          for (int j = 0; j < 4; ++j)
            base[off + (((size_t)(b * Hc + hh)) * Tc + t0 + j) * 64 + d] =
                f2bf((acc[mi][ni][j] + bs) * qs);
        }
      }
    }
  }
}

// ---------------------------------------------------------------------------
// 128x128 m97-structure bf16 GEMM (kept for N=1024 shapes).
// EPI: 1 = fp32 +bias+resid   3 = fp32 accumulate
// ---------------------------------------------------------------------------
template <int EPI>
__global__ __launch_bounds__(256)
void gemm_bf16(const ushort* __restrict__ A, int lda,
               const ushort* __restrict__ B,
               const float* __restrict__ bias, const float* __restrict__ resid,
               void* __restrict__ Cout, int ldc, int K) {
  __shared__ __align__(16) ushort As[128 * 32];
  __shared__ __align__(16) ushort Bs[128 * 32];
  const int tid = threadIdx.x;
  const int lane = tid & 63, w = tid >> 6;
  const int g = lane >> 4, c = lane & 15;
  int bid = blockIdx.y * gridDim.x + blockIdx.x;
  const int qq = (gridDim.x * gridDim.y) >> 3;
  bid = (bid & 7) * qq + (bid >> 3);
  const int m0 = (bid / gridDim.x) * 128, n0 = (bid % gridDim.x) * 128;
  const int wm = (w >> 1) * 64, wn = (w & 1) * 64;
  f4v acc[4][4];
#pragma unroll
  for (int i = 0; i < 4; ++i)
#pragma unroll
    for (int j = 0; j < 4; ++j) acc[i][j] = f4v{0.f, 0.f, 0.f, 0.f};

  int srow[2], skoff[2];
#pragma unroll
  for (int seg = 0; seg < 2; ++seg) {
    const int ci = seg * 256 + tid;
    srow[seg] = ci >> 2;
    skoff[seg] = 8 * ((ci & 3) ^ ((srow[seg] >> 1) & 3));
  }

  for (int k0 = 0; k0 < K; k0 += 32) {
#pragma unroll
    for (int seg = 0; seg < 2; ++seg) {
      const int ci = seg * 256 + tid;
      GLOAD_LDS(A + (size_t)(m0 + srow[seg]) * lda + k0 + skoff[seg], &As[ci * 8]);
      GLOAD_LDS(B + (size_t)(n0 + srow[seg]) * K + k0 + skoff[seg], &Bs[ci * 8]);
    }
    __syncthreads();
    s8v af[4], bf[4];
#pragma unroll
    for (int mi = 0; mi < 4; ++mi) {
      const int R = wm + mi * 16 + c;
      af[mi] = *(const s8v*)&As[R * 32 + 8 * (g ^ ((R >> 1) & 3))];
    }
#pragma unroll
    for (int ni = 0; ni < 4; ++ni) {
      const int R = wn + ni * 16 + c;
      bf[ni] = *(const s8v*)&Bs[R * 32 + 8 * (g ^ ((R >> 1) & 3))];
    }
#pragma unroll
    for (int mi = 0; mi < 4; ++mi)
#pragma unroll
      for (int ni = 0; ni < 4; ++ni)
        acc[mi][ni] = __builtin_amdgcn_mfma_f32_16x16x32_bf16(
            af[mi], bf[ni], acc[mi][ni], 0, 0, 0);
    __syncthreads();
  }

#pragma unroll
  for (int mi = 0; mi < 4; ++mi) {
#pragma unroll
    for (int ni = 0; ni < 4; ++ni) {
#pragma unroll
      for (int j = 0; j < 4; ++j) {
        const int row = m0 + wm + mi * 16 + g * 4 + j;
        const int col = n0 + wn + ni * 16 + c;
        float v = acc[mi][ni][j];
        if constexpr (EPI == 1) {
          v += bias[col] + resid[(size_t)row * ldc + col];
          ((float*)Cout)[(size_t)row * ldc + col] = v;
        } else {
          ((float*)Cout)[(size_t)row * ldc + col] += v;
        }
      }
    }
  }
}

// ---------------------------------------------------------------------------
// MFMA flash attention (unchanged from round 7): swapped 32x32, exp2-domain
// softmax, double-buffered prefetch, cvt_pk+permlane P-fragments.
// ---------------------------------------------------------------------------
__global__ __launch_bounds__(256)
void attn_mfma(const ushort* __restrict__ Qb, const ushort* __restrict__ Kb,
               const ushort* __restrict__ Vt, ushort* __restrict__ Ob) {
  __shared__ __align__(16) ushort Ksm[2][64 * 64];
  __shared__ __align__(16) ushort Vtsm[2][64 * 64];
  const int tid = threadIdx.x;
  const int lane = tid & 63, w = tid >> 6;
  const int ql = lane & 31, hi = lane >> 5;
  int bid = blockIdx.x;
  bid = (bid & 7) * 128 + (bid >> 3);
  const int qt = bid & 15, bh = bid >> 4;
  const ushort* Qh = Qb + (size_t)bh * Tc * 64;
  const ushort* Kh = Kb + (size_t)bh * Tc * 64;
  const ushort* Vth = Vt + (size_t)bh * 64 * Tc;
  const int qrow = qt * 128 + w * 32 + ql;
  s8v qf[4];
#pragma unroll
  for (int ds = 0; ds < 4; ++ds)
    qf[ds] = *(const s8v*)(Qh + (size_t)qrow * 64 + ds * 16 + hi * 8);
  f16v accO0, accO1;
#pragma unroll
  for (int i = 0; i < 16; ++i) { accO0[i] = 0.f; accO1[i] = 0.f; }
  float mold = -1e30f, lsum = 0.f;
  int srow[2], soff[2];
#pragma unroll
  for (int seg = 0; seg < 2; ++seg) {
    const int ci = seg * 256 + tid;
    srow[seg] = ci >> 3;
    soff[seg] = ((ci & 7) * 8) ^ ((srow[seg] & 7) << 3);
  }
  auto stage = [&](int buf, int j0) {
#pragma unroll
    for (int seg = 0; seg < 2; ++seg) {
      const int ci = seg * 256 + tid;
      GLOAD_LDS(Kh + (size_t)(j0 + srow[seg]) * 64 + soff[seg], &Ksm[buf][ci * 8]);
      GLOAD_LDS(Vth + (size_t)srow[seg] * Tc + j0 + soff[seg], &Vtsm[buf][ci * 8]);
    }
  };

  stage(0, 0);
  __syncthreads();
  int cur = 0;
  for (int j0 = 0; j0 < Tc; j0 += 64) {
    if (j0 + 64 < Tc) stage(cur ^ 1, j0 + 64);
    f16v s0, s1;
#pragma unroll
    for (int i = 0; i < 16; ++i) { s0[i] = 0.f; s1[i] = 0.f; }
    __builtin_amdgcn_s_setprio(1);
#pragma unroll
    for (int ds = 0; ds < 4; ++ds) {
      const int col = (ds * 16 + hi * 8);
      const int r0 = ql;
      s8v kf0 = *(const s8v*)&Ksm[cur][r0 * 64 + (col ^ ((r0 & 7) << 3))];
      s0 = __builtin_amdgcn_mfma_f32_32x32x16_bf16(kf0, qf[ds], s0, 0, 0, 0);
      const int r1 = 32 + ql;
      s8v kf1 = *(const s8v*)&Ksm[cur][r1 * 64 + (col ^ ((r1 & 7) << 3))];
      s1 = __builtin_amdgcn_mfma_f32_32x32x16_bf16(kf1, qf[ds], s1, 0, 0, 0);
    }
    __builtin_amdgcn_s_setprio(0);
    float cc0 = fmaxf(s0[0], s1[0]), cc1 = fmaxf(s0[1], s1[1]);
    float cc2 = fmaxf(s0[2], s1[2]), cc3 = fmaxf(s0[3], s1[3]);
#pragma unroll
    for (int i = 4; i < 16; i += 4) {
      cc0 = max3f(cc0, s0[i + 0], s1[i + 0]);
      cc1 = max3f(cc1, s0[i + 1], s1[i + 1]);
      cc2 = max3f(cc2, s0[i + 2], s1[i + 2]);
      cc3 = max3f(cc3, s0[i + 3], s1[i + 3]);
    }
    float mx = pmax32(fmaxf(max3f(cc0, cc1, cc2), cc3));
    const bool need = mx > mold + 11.5416f;
    if (__any((int)need)) {
      const float mnew = fmaxf(mold, mx);
      const float sc = exp2v(mold - mnew);
      lsum *= sc;
#pragma unroll
      for (int i = 0; i < 16; ++i) { accO0[i] *= sc; accO1[i] *= sc; }
      mold = mnew;
    }
    float r0s = 0.f, r1s = 0.f, r2s = 0.f, r3s = 0.f;
#pragma unroll
    for (int i = 0; i < 16; i += 4) {
      s0[i+0] = exp2v(s0[i+0] - mold); r0s += s0[i+0];
      s0[i+1] = exp2v(s0[i+1] - mold); r1s += s0[i+1];
      s0[i+2] = exp2v(s0[i+2] - mold); r2s += s0[i+2];
      s0[i+3] = exp2v(s0[i+3] - mold); r3s += s0[i+3];
      s1[i+0] = exp2v(s1[i+0] - mold); r0s += s1[i+0];
      s1[i+1] = exp2v(s1[i+1] - mold); r1s += s1[i+1];
      s1[i+2] = exp2v(s1[i+2] - mold); r2s += s1[i+2];
      s1[i+3] = exp2v(s1[i+3] - mold); r3s += s1[i+3];
    }
    lsum += psum32((r0s + r1s) + (r2s + r3s));
    s8v pa[4];
#pragma unroll
    for (int s = 0; s < 4; ++s) {
      const f16v st = (s < 2) ? s0 : s1;
      const int mA = 2 * (s & 1);
      uint32_t a0 = cvtpk(st[4 * mA + 0], st[4 * mA + 1]);
      uint32_t a1 = cvtpk(st[4 * mA + 2], st[4 * mA + 3]);
      uint32_t b0 = cvtpk(st[4 * mA + 4], st[4 * mA + 5]);
      uint32_t b1 = cvtpk(st[4 * mA + 6], st[4 * mA + 7]);
      asm("v_permlane32_swap_b32 %0, %1" : "+v"(b0), "+v"(a0));
      asm("v_permlane32_swap_b32 %0, %1" : "+v"(b1), "+v"(a1));
      union { uint32_t u[4]; s8v v; } pk;
      pk.u[0] = a0; pk.u[1] = a1; pk.u[2] = b0; pk.u[3] = b1;
      pa[s] = pk.v;
    }
    __builtin_amdgcn_s_setprio(1);
#pragma unroll
    for (int s = 0; s < 4; ++s) {
      const int col = (s * 16 + hi * 8);
      const int r0 = ql;
      s8v vf0 = *(const s8v*)&Vtsm[cur][r0 * 64 + (col ^ ((r0 & 7) << 3))];
      accO0 = __builtin_amdgcn_mfma_f32_32x32x16_bf16(vf0, pa[s], accO0, 0, 0, 0);
      const int r1 = 32 + ql;
      s8v vf1 = *(const s8v*)&Vtsm[cur][r1 * 64 + (col ^ ((r1 & 7) << 3))];
      accO1 = __builtin_amdgcn_mfma_f32_32x32x16_bf16(vf1, pa[s], accO1, 0, 0, 0);
    }
    __builtin_amdgcn_s_setprio(0);
    __syncthreads();
    cur ^= 1;
  }
  const int h = bh & 15, b = bh >> 4;
  const int tok = b * Tc + qt * 128 + w * 32 + ql;
  const float inv = 1.f / lsum;
  ushort* orow = Ob + (size_t)tok * Dc + h * 64;
#pragma unroll
  for (int dt = 0; dt < 2; ++dt) {
    const f16v ac = dt ? accO1 : accO0;
#pragma unroll
    for (int rq = 0; rq < 4; ++rq) {
      u4v pk;
#pragma unroll
      for (int j = 0; j < 4; ++j) pk[j] = f2bf(ac[4 * rq + j] * inv);
      *(u4v*)&orow[dt * 32 + 8 * rq + 4 * hi] = pk;
    }
  }
}

// ---------------------------------------------------------------------------
extern "C" void kernel_launch(void* const* d_in, const int* in_sizes, int n_in,
                              void* d_out, int out_size, void* d_ws, size_t ws_size,
                              hipStream_t stream) {
  (void)in_sizes; (void)n_in; (void)out_size; (void)ws_size;
  const float* x        = (const float*)d_in[0];
  const float* ln1_g    = (const float*)d_in[1];
  const float* ln1_b    = (const float*)d_in[2];
  const float* in_w     = (const float*)d_in[3];
  const float* in_b     = (const float*)d_in[4];
  const float* out_w    = (const float*)d_in[5];
  const float* out_b    = (const float*)d_in[6];
  const float* ln2_g    = (const float*)d_in[7];
  const float* ln2_b    = (const float*)d_in[8];
  const float* rw       = (const float*)d_in[9];
  const float* log_temp = (const float*)d_in[10];
  const float* Wg       = (const float*)d_in[11];
  const float* Wu       = (const float*)d_in[12];
  const float* Wd       = (const float*)d_in[13];
  float* out = (float*)d_out;

  // Workspace (ushorts), total ~138 MiB:
  ushort* h_bf   = (ushort*)d_ws;                       // NTOK*1024   16 MiB
  ushort* Qb     = h_bf   + (size_t)NTOK * Dc;          // 16 MiB
  ushort* Kb     = Qb     + (size_t)NTOK * Dc;          // 16 MiB
  ushort* Vt     = Kb     + (size_t)NTOK * Dc;          // 16 MiB ([bh][d][t])
  ushort* Ob     = Vt     + (size_t)NTOK * Dc;          // 16 MiB
  ushort* act    = Ob     + (size_t)NTOK * Dc;          // NTOK*2048   32 MiB
  ushort* wb_in  = act    + (size_t)NTOK * EDE;         // 3072*1024    6 MiB
  ushort* wb_out = wb_in  + (size_t)3 * Dc * Dc;        // 1024*1024    2 MiB
  ushort* wb_gu  = wb_out + (size_t)Dc * Dc;            // 4096*1024    8 MiB
  ushort* wb_d   = wb_gu  + (size_t)2 * EDE * Dc;       // 1024*2048    4 MiB
  float*  wts    = (float*)(wb_d + (size_t)Dc * EDE);   // NTOK*8     0.25 MiB

  const dim3 blk(256);

  // 0. weight conversions (every call; deterministic)
  f32_to_bf16<<<dim3(3 * Dc * Dc / 2048), blk, 0, stream>>>(in_w, wb_in);
  f32_to_bf16<<<dim3(Dc * Dc / 2048), blk, 0, stream>>>(out_w, wb_out);
  wgu_reorder<<<dim3(2 * EDE * Dc / 2048), blk, 0, stream>>>(Wg, Wu, wb_gu);
  wd_reorder<<<dim3(Ec * Dc * DEc / 2048), blk, 0, stream>>>(Wd, wb_d);

  // 1. LN1: x -> h_bf (bf16)
  ln_kernel<0><<<dim3(NTOK), blk, 0, stream>>>(x, ln1_g, ln1_b, h_bf,
                                               nullptr, nullptr, nullptr);
  // 2. QKV GEMM (256^2 8-phase) -> head-major Q(x0.125*log2e)/K + V^T
  gemm256<0><<<dim3(3 * Dc / 256, NTOK / 256), dim3(512), 0, stream>>>(
      h_bf, Dc, wb_in, in_b, Qb, Dc);
  // 3. MFMA attention -> Ob bf16
  attn_mfma<<<dim3(Bc * Hc * (Tc / 128)), blk, 0, stream>>>(Qb, Kb, Vt, Ob);
  // 4. out proj + bias + residual(x) -> out fp32 (128^2)
  gemm_bf16<1><<<dim3(Dc / 128, NTOK / 128), blk, 0, stream>>>(
      Ob, Dc, wb_out, out_b, x, out, Dc, Dc);
  // 5. LN2 + fused router: out -> h_bf (h2), wts
  ln_kernel<1><<<dim3(NTOK), blk, 0, stream>>>(out, ln2_g, ln2_b, h_bf,
                                               rw, log_temp, wts);
  // 6. fused gate+up GEMM (256^2 8-phase) + silu*up*wts -> act bf16
  gemm256<4><<<dim3(2 * EDE / 256, NTOK / 256), dim3(512), 0, stream>>>(
      h_bf, Dc, wb_gu, wts, act, Dc);
  // 7. single down GEMM (128^2, K=2048), += into out
  gemm_bf16<3><<<dim3(Dc / 128, NTOK / 128), blk, 0, stream>>>(
      act, EDE, wb_d, nullptr, nullptr, out, Dc, EDE);
}

// Round 9
// 404.797 us; speedup vs baseline: 12.5359x; 1.0204x over previous
//
#include <hip/hip_runtime.h>
#include <hip/hip_bf16.h>
#include <cstddef>
#include <cstdint>

// Problem constants (match reference)
constexpr int Bc  = 4;
constexpr int Tc  = 2048;
constexpr int Dc  = 1024;
constexpr int Hc  = 16;
constexpr int Ec  = 8;     // experts
constexpr int DEc = 256;   // expert dim
constexpr int NTOK = Bc * Tc;          // 8192 tokens
constexpr int EDE = Ec * DEc;          // 2048

typedef __attribute__((ext_vector_type(8)))  short  s8v;   // 8 bf16 (4 VGPRs)
typedef __attribute__((ext_vector_type(4)))  float  f4v;   // 16x16 MFMA C/D
typedef __attribute__((ext_vector_type(16))) float  f16v;  // 32x32 MFMA C/D
typedef __attribute__((ext_vector_type(8)))  ushort u8v;
typedef __attribute__((ext_vector_type(4)))  ushort u4v;

constexpr float LOG2E = 1.44269504088896340736f;

__device__ inline ushort f2bf(float f) {  // fp32 -> bf16 bits, RNE
  union { float f; uint32_t u; } v; v.f = f;
  uint32_t r = v.u + 0x7FFFu + ((v.u >> 16) & 1u);
  return (ushort)(r >> 16);
}
__device__ inline float exp2v(float x) {   // 2^x on the TRANS pipe
  float r; asm("v_exp_f32 %0, %1" : "=v"(r) : "v"(x)); return r;
}
__device__ inline float max3f(float a, float b, float c) {
  return fmaxf(fmaxf(a, b), c);             // clang fuses to v_max3_f32
}
// pair-reduce lane l <-> l^32 without DS ops (pure VALU)
__device__ inline float pmax32(float x) {
  float a = x, b = x;
  asm("v_permlane32_swap_b32 %0, %1" : "+v"(b), "+v"(a));
  return fmaxf(a, b);
}
__device__ inline float psum32(float x) {
  float a = x, b = x;
  asm("v_permlane32_swap_b32 %0, %1" : "+v"(b), "+v"(a));
  return a + b;
}

// async global->LDS, 16B per lane; LDS dest = wave-uniform base + lane*16
#define GLOAD_LDS(gsrc, ldst)                                        \
  __builtin_amdgcn_global_load_lds(                                  \
      (const __attribute__((address_space(1))) void*)(gsrc),         \
      (__attribute__((address_space(3))) void*)(ldst), 16, 0, 0)

// pack 2 f32 -> 1 u32 of 2 bf16 (lo = a, hi = b), RNE
__device__ inline uint32_t cvtpk(float a, float b) {
  uint32_t r;
  asm("v_cvt_pk_bf16_f32 %0, %1, %2" : "=v"(r) : "v"(a), "v"(b));
  return r;
}

__device__ inline u8v pack8(const float4& a, const float4& b) {
  u8v o;
  o[0] = f2bf(a.x); o[1] = f2bf(a.y); o[2] = f2bf(a.z); o[3] = f2bf(a.w);
  o[4] = f2bf(b.x); o[5] = f2bf(b.y); o[6] = f2bf(b.z); o[7] = f2bf(b.w);
  return o;
}

// ---------------------------------------------------------------------------
// Single fused weight-convert kernel (block-range dispatch):
//   [0,1536)    in_w  flat -> wb_in
//   [1536,2048) out_w flat -> wb_out
//   [2048,4096) Wg/Wu interleaved 16-row blocks -> wb_gu [4096,1024]
//   [4096,5120) Wd [E,D,DE] -> wb_d [D, E*DE]
// ---------------------------------------------------------------------------
__global__ __launch_bounds__(256)
void convert_all(const float* __restrict__ in_w, const float* __restrict__ out_w,
                 const float* __restrict__ Wg, const float* __restrict__ Wu,
                 const float* __restrict__ Wd,
                 ushort* __restrict__ wb_in, ushort* __restrict__ wb_out,
                 ushort* __restrict__ wb_gu, ushort* __restrict__ wb_d) {
  const int b = blockIdx.x;
  const int tid = threadIdx.x;
  if (b < 1536) {
    const size_t i = ((size_t)b * 256 + tid) * 8;
    *(u8v*)(wb_in + i) = pack8(*(const float4*)(in_w + i),
                               *(const float4*)(in_w + i + 4));
  } else if (b < 2048) {
    const size_t i = ((size_t)(b - 1536) * 256 + tid) * 8;
    *(u8v*)(wb_out + i) = pack8(*(const float4*)(out_w + i),
                                *(const float4*)(out_w + i + 4));
  } else if (b < 4096) {
    const size_t i = ((size_t)(b - 2048) * 256 + tid) * 8;
    const int r = (int)(i >> 10), k = (int)(i & 1023);
    const int j = ((r >> 5) << 4) + (r & 15);
    const float* src = (r & 16) ? Wu : Wg;
    *(u8v*)(wb_gu + i) = pack8(*(const float4*)(src + (size_t)j * Dc + k),
                               *(const float4*)(src + (size_t)j * Dc + k + 4));
  } else {
    const size_t i = ((size_t)(b - 4096) * 256 + tid) * 8;
    const int e = (int)(i >> 18);
    const int d = (int)((i >> 8) & 1023);
    const int f = (int)(i & 255);
    *(u8v*)(wb_d + (size_t)d * EDE + e * DEc + f) =
        pack8(*(const float4*)(Wd + i), *(const float4*)(Wd + i + 4));
  }
}

// ---------------------------------------------------------------------------
// LayerNorm (+ optional fused router). One block per token row (D=1024).
// ---------------------------------------------------------------------------
template <int ROUTER>
__global__ __launch_bounds__(256)
void ln_kernel(const float* __restrict__ in, const float* __restrict__ g,
               const float* __restrict__ bt, ushort* __restrict__ out,
               const float* __restrict__ rw, const float* __restrict__ log_temp,
               float* __restrict__ wts) {
  const int row = blockIdx.x;
  const int tid = threadIdx.x;
  const float* xr = in + (size_t)row * Dc;
  float4 v = *(const float4*)(xr + tid * 4);
  float s  = v.x + v.y + v.z + v.w;
  float ss = v.x * v.x + v.y * v.y + v.z * v.z + v.w * v.w;
#pragma unroll
  for (int off = 32; off; off >>= 1) {
    s  += __shfl_xor(s, off);
    ss += __shfl_xor(ss, off);
  }
  __shared__ float red[8];
  const int w = tid >> 6;
  if ((tid & 63) == 0) { red[w] = s; red[4 + w] = ss; }
  __syncthreads();
  const float ts  = red[0] + red[1] + red[2] + red[3];
  const float tss = red[4] + red[5] + red[6] + red[7];
  const float mean = ts * (1.0f / Dc);
  const float var  = tss * (1.0f / Dc) - mean * mean;
  const float rstd = rsqrtf(var + 1e-5f);
  float4 gv = *(const float4*)(g + tid * 4);
  float4 bv = *(const float4*)(bt + tid * 4);
  const float n0 = (v.x - mean) * rstd * gv.x + bv.x;
  const float n1 = (v.y - mean) * rstd * gv.y + bv.y;
  const float n2 = (v.z - mean) * rstd * gv.z + bv.z;
  const float n3 = (v.w - mean) * rstd * gv.w + bv.w;
  u4v o;
  o[0] = f2bf(n0); o[1] = f2bf(n1); o[2] = f2bf(n2); o[3] = f2bf(n3);
  *(u4v*)(out + (size_t)row * Dc + tid * 4) = o;
  if constexpr (ROUTER) {
    float part[Ec];
#pragma unroll
    for (int e = 0; e < Ec; ++e) {
      float4 wv = *(const float4*)(rw + (size_t)e * Dc + tid * 4);
      part[e] = n0 * wv.x + n1 * wv.y + n2 * wv.z + n3 * wv.w;
    }
#pragma unroll
    for (int off = 32; off; off >>= 1) {
#pragma unroll
      for (int e = 0; e < Ec; ++e) part[e] += __shfl_xor(part[e], off);
    }
    __shared__ float red2[4][Ec];
    if ((tid & 63) == 0) {
#pragma unroll
      for (int e = 0; e < Ec; ++e) red2[w][e] = part[e];
    }
    __syncthreads();
    if (tid == 0) {
      const float lt = *log_temp;
      const float temp = log1pf(__expf(lt)) + 0.1f;
      float lg[Ec];
#pragma unroll
      for (int e = 0; e < Ec; ++e)
        lg[e] = (red2[0][e] + red2[1][e] + red2[2][e] + red2[3][e]) / temp;
      float m1 = -1e30f, m2 = -1e30f;
#pragma unroll
      for (int e = 0; e < Ec; ++e) {
        const float vv = lg[e];
        if (vv > m1) { m2 = m1; m1 = vv; }
        else if (vv > m2) { m2 = vv; }
      }
      float sl[Ec];
      float mx = -1e30f;
#pragma unroll
      for (int e = 0; e < Ec; ++e) {
        const float sup = 1.f / (1.f + __expf(-10.f * (lg[e] - m2)));
        sl[e] = lg[e] * sup;
        mx = fmaxf(mx, sl[e]);
      }
      float ssum = 0.f;
#pragma unroll
      for (int e = 0; e < Ec; ++e) {
        const float p = __expf(sl[e] - mx);
        sl[e] = p;
        ssum += p;
      }
      const float inv = 1.f / ssum;
#pragma unroll
      for (int e = 0; e < Ec; ++e) wts[(size_t)row * Ec + e] = sl[e] * inv;
    }
  }
}

// ---------------------------------------------------------------------------
// 256x256 8-phase bf16 GEMM (T3+T4): BK=64, 512 thr = 8 waves (2Mx4N),
// double-buffered 128KiB LDS, raw s_barrier + counted vmcnt.
// EPI: 0 = QKV scatter   4 = fused silu(gate)*up*wts (B row-interleaved)
// ---------------------------------------------------------------------------
template <int EPI>
__global__ __launch_bounds__(512, 2)
void gemm256(const ushort* __restrict__ A, int lda,
             const ushort* __restrict__ B,
             const float* __restrict__ bias,
             void* __restrict__ Cout, int K) {
  __shared__ __align__(16) ushort Asm[2][256 * 64];
  __shared__ __align__(16) ushort Bsm[2][256 * 64];
  const int tid = threadIdx.x;
  const int lane = tid & 63, w = tid >> 6;
  const int g = lane >> 4, c = lane & 15;
  const int wr = w >> 2, wc = w & 3;
  int bid = blockIdx.y * gridDim.x + blockIdx.x;
  const int qq = (gridDim.x * gridDim.y) >> 3;
  bid = (bid & 7) * qq + (bid >> 3);
  const int m0 = (bid / gridDim.x) * 256, n0 = (bid % gridDim.x) * 256;
  f4v acc[8][4];
#pragma unroll
  for (int i = 0; i < 8; ++i)
#pragma unroll
    for (int j = 0; j < 4; ++j) acc[i][j] = f4v{0.f, 0.f, 0.f, 0.f};

  const int srow = tid >> 3;                       // 0..63
  const int koff = 8 * ((tid & 7) ^ (srow & 7));   // pre-swizzled k slot

#define STAGE_A(buf, kt, i)                                                  \
  GLOAD_LDS(A + (size_t)(m0 + (i) * 64 + srow) * lda + (kt) * 64 + koff,     \
            &Asm[buf][((i) * 512 + tid) * 8])
#define STAGE_B(buf, kt, i)                                                  \
  GLOAD_LDS(B + (size_t)(n0 + (i) * 64 + srow) * K + (kt) * 64 + koff,       \
            &Bsm[buf][((i) * 512 + tid) * 8])

#define RD_A(buf, mi, ks)                                                    \
  (*(const s8v*)&Asm[buf][(wr * 128 + (mi) * 16 + c) * 64 +                  \
      8 * (((ks) * 4 + g) ^ ((wr * 128 + (mi) * 16 + c) & 7))])
#define RD_B(buf, ni, ks)                                                    \
  (*(const s8v*)&Bsm[buf][(wc * 64 + (ni) * 16 + c) * 64 +                   \
      8 * (((ks) * 4 + g) ^ ((wc * 64 + (ni) * 16 + c) & 7))])

  const int NT = K >> 6;
  STAGE_B(0, 0, 0); STAGE_B(0, 0, 1); STAGE_B(0, 0, 2); STAGE_B(0, 0, 3);
  STAGE_A(0, 0, 0); STAGE_A(0, 0, 2); STAGE_A(0, 0, 1); STAGE_A(0, 0, 3);
  asm volatile("s_waitcnt vmcnt(0)" ::: "memory");
  __builtin_amdgcn_s_barrier();

  for (int t = 0; t < NT; ++t) {
    const int cur = t & 1, nxt = cur ^ 1;
    const bool st = (t + 1 < NT);
    s8v bf[2][4], af[2][2];
#pragma unroll
    for (int ks = 0; ks < 2; ++ks) {
#pragma unroll
      for (int ni = 0; ni < 4; ++ni) bf[ks][ni] = RD_B(cur, ni, ks);
      af[ks][0] = RD_A(cur, 0, ks); af[ks][1] = RD_A(cur, 1, ks);
    }
    if (st) { STAGE_B(nxt, t + 1, 0); STAGE_B(nxt, t + 1, 1); }
    __builtin_amdgcn_s_barrier();
    __builtin_amdgcn_s_setprio(1);
#pragma unroll
    for (int ks = 0; ks < 2; ++ks)
#pragma unroll
      for (int q = 0; q < 2; ++q)
#pragma unroll
        for (int ni = 0; ni < 4; ++ni)
          acc[q][ni] = __builtin_amdgcn_mfma_f32_16x16x32_bf16(
              af[ks][q], bf[ks][ni], acc[q][ni], 0, 0, 0);
    __builtin_amdgcn_s_setprio(0);
    __builtin_amdgcn_s_barrier();
#pragma unroll
    for (int ks = 0; ks < 2; ++ks) {
      af[ks][0] = RD_A(cur, 2, ks); af[ks][1] = RD_A(cur, 3, ks);
    }
    if (st) { STAGE_B(nxt, t + 1, 2); STAGE_B(nxt, t + 1, 3); }
    __builtin_amdgcn_s_barrier();
    __builtin_amdgcn_s_setprio(1);
#pragma unroll
    for (int ks = 0; ks < 2; ++ks)
#pragma unroll
      for (int q = 0; q < 2; ++q)
#pragma unroll
        for (int ni = 0; ni < 4; ++ni)
          acc[2 + q][ni] = __builtin_amdgcn_mfma_f32_16x16x32_bf16(
              af[ks][q], bf[ks][ni], acc[2 + q][ni], 0, 0, 0);
    __builtin_amdgcn_s_setprio(0);
    if (st) asm volatile("s_waitcnt vmcnt(4)" ::: "memory");
    else    asm volatile("s_waitcnt vmcnt(0)" ::: "memory");
    __builtin_amdgcn_s_barrier();
#pragma unroll
    for (int ks = 0; ks < 2; ++ks) {
      af[ks][0] = RD_A(cur, 4, ks); af[ks][1] = RD_A(cur, 5, ks);
    }
    if (st) { STAGE_A(nxt, t + 1, 0); STAGE_A(nxt, t + 1, 2); }
    __builtin_amdgcn_s_barrier();
    __builtin_amdgcn_s_setprio(1);
#pragma unroll
    for (int ks = 0; ks < 2; ++ks)
#pragma unroll
      for (int q = 0; q < 2; ++q)
#pragma unroll
        for (int ni = 0; ni < 4; ++ni)
          acc[4 + q][ni] = __builtin_amdgcn_mfma_f32_16x16x32_bf16(
              af[ks][q], bf[ks][ni], acc[4 + q][ni], 0, 0, 0);
    __builtin_amdgcn_s_setprio(0);
    __builtin_amdgcn_s_barrier();
#pragma unroll
    for (int ks = 0; ks < 2; ++ks) {
      af[ks][0] = RD_A(cur, 6, ks); af[ks][1] = RD_A(cur, 7, ks);
    }
    if (st) { STAGE_A(nxt, t + 1, 1); STAGE_A(nxt, t + 1, 3); }
    __builtin_amdgcn_s_barrier();
    __builtin_amdgcn_s_setprio(1);
#pragma unroll
    for (int ks = 0; ks < 2; ++ks)
#pragma unroll
      for (int q = 0; q < 2; ++q)
#pragma unroll
        for (int ni = 0; ni < 4; ++ni)
          acc[6 + q][ni] = __builtin_amdgcn_mfma_f32_16x16x32_bf16(
              af[ks][q], bf[ks][ni], acc[6 + q][ni], 0, 0, 0);
    __builtin_amdgcn_s_setprio(0);
    if (st) asm volatile("s_waitcnt vmcnt(2)" ::: "memory");
    __builtin_amdgcn_s_barrier();
  }
#undef STAGE_A
#undef STAGE_B
#undef RD_A
#undef RD_B

#pragma unroll
  for (int mi = 0; mi < 8; ++mi) {
    if constexpr (EPI == 4) {  // fused act: ni pairs (gate, up)
#pragma unroll
      for (int nip = 0; nip < 2; ++nip) {
        const int jbase = ((n0 + wc * 64) >> 1) + nip * 16;
        const int e = jbase >> 8;
#pragma unroll
        for (int j = 0; j < 4; ++j) {
          const int row = m0 + wr * 128 + mi * 16 + g * 4 + j;
          const float wgt = bias[(size_t)row * Ec + e];  // bias = wts
          const float gv = acc[mi][2 * nip][j];
          const float uv = acc[mi][2 * nip + 1][j];
          const float av = (gv / (1.f + __expf(-gv))) * uv * wgt;
          ((ushort*)Cout)[(size_t)row * EDE + jbase + c] = f2bf(av);
        }
      }
    } else {  // EPI == 0: QKV scatter, head-major
#pragma unroll
      for (int ni = 0; ni < 4; ++ni) {
        const int col = n0 + wc * 64 + ni * 16 + c;
        const int which = col >> 10, hh = (col >> 6) & 15, d = col & 63;
        const int row0 = m0 + wr * 128 + mi * 16 + g * 4;
        const int b = row0 >> 11, t0 = row0 & 2047;
        const float bs = bias[col];
        ushort* base = (ushort*)Cout;
        if (which == 2) {  // V transposed: Vt[bh][d][t]
          u4v pk;
#pragma unroll
          for (int j = 0; j < 4; ++j) pk[j] = f2bf(acc[mi][ni][j] + bs);
          *(u4v*)&base[2 * (size_t)NTOK * Dc +
                       (((size_t)(b * Hc + hh)) * 64 + d) * Tc + t0] = pk;
        } else {
          const float qs = (which == 0) ? 0.125f * LOG2E : 1.f;
          const size_t off = (size_t)which * ((size_t)NTOK * Dc);
#pragma unroll
          for (int j = 0; j < 4; ++j)
            base[off + (((size_t)(b * Hc + hh)) * Tc + t0 + j) * 64 + d] =
                f2bf((acc[mi][ni][j] + bs) * qs);
        }
      }
    }
  }
}

// ---------------------------------------------------------------------------
// 128x128 m97-structure bf16 GEMM (kept for N=1024 shapes).
// EPI: 1 = fp32 +bias+resid   3 = fp32 accumulate
// ---------------------------------------------------------------------------
template <int EPI>
__global__ __launch_bounds__(256)
void gemm_bf16(const ushort* __restrict__ A, int lda,
               const ushort* __restrict__ B,
               const float* __restrict__ bias, const float* __restrict__ resid,
               void* __restrict__ Cout, int ldc, int K) {
  __shared__ __align__(16) ushort As[128 * 32];
  __shared__ __align__(16) ushort Bs[128 * 32];
  const int tid = threadIdx.x;
  const int lane = tid & 63, w = tid >> 6;
  const int g = lane >> 4, c = lane & 15;
  int bid = blockIdx.y * gridDim.x + blockIdx.x;
  const int qq = (gridDim.x * gridDim.y) >> 3;
  bid = (bid & 7) * qq + (bid >> 3);
  const int m0 = (bid / gridDim.x) * 128, n0 = (bid % gridDim.x) * 128;
  const int wm = (w >> 1) * 64, wn = (w & 1) * 64;
  f4v acc[4][4];
#pragma unroll
  for (int i = 0; i < 4; ++i)
#pragma unroll
    for (int j = 0; j < 4; ++j) acc[i][j] = f4v{0.f, 0.f, 0.f, 0.f};

  int srow[2], skoff[2];
#pragma unroll
  for (int seg = 0; seg < 2; ++seg) {
    const int ci = seg * 256 + tid;
    srow[seg] = ci >> 2;
    skoff[seg] = 8 * ((ci & 3) ^ ((srow[seg] >> 1) & 3));
  }

  for (int k0 = 0; k0 < K; k0 += 32) {
#pragma unroll
    for (int seg = 0; seg < 2; ++seg) {
      const int ci = seg * 256 + tid;
      GLOAD_LDS(A + (size_t)(m0 + srow[seg]) * lda + k0 + skoff[seg], &As[ci * 8]);
      GLOAD_LDS(B + (size_t)(n0 + srow[seg]) * K + k0 + skoff[seg], &Bs[ci * 8]);
    }
    __syncthreads();
    s8v af[4], bf[4];
#pragma unroll
    for (int mi = 0; mi < 4; ++mi) {
      const int R = wm + mi * 16 + c;
      af[mi] = *(const s8v*)&As[R * 32 + 8 * (g ^ ((R >> 1) & 3))];
    }
#pragma unroll
    for (int ni = 0; ni < 4; ++ni) {
      const int R = wn + ni * 16 + c;
      bf[ni] = *(const s8v*)&Bs[R * 32 + 8 * (g ^ ((R >> 1) & 3))];
    }
#pragma unroll
    for (int mi = 0; mi < 4; ++mi)
#pragma unroll
      for (int ni = 0; ni < 4; ++ni)
        acc[mi][ni] = __builtin_amdgcn_mfma_f32_16x16x32_bf16(
            af[mi], bf[ni], acc[mi][ni], 0, 0, 0);
    __syncthreads();
  }

#pragma unroll
  for (int mi = 0; mi < 4; ++mi) {
#pragma unroll
    for (int ni = 0; ni < 4; ++ni) {
#pragma unroll
      for (int j = 0; j < 4; ++j) {
        const int row = m0 + wm + mi * 16 + g * 4 + j;
        const int col = n0 + wn + ni * 16 + c;
        float v = acc[mi][ni][j];
        if constexpr (EPI == 1) {
          v += bias[col] + resid[(size_t)row * ldc + col];
          ((float*)Cout)[(size_t)row * ldc + col] = v;
        } else {
          ((float*)Cout)[(size_t)row * ldc + col] += v;
        }
      }
    }
  }
}

// ---------------------------------------------------------------------------
// MFMA flash attention: swapped 32x32, exp2-domain softmax, double-buffered
// staging with COUNTED vmcnt(4) + raw s_barrier (prefetch spans the whole
// previous iteration; never drains to 0 in steady state).
// ---------------------------------------------------------------------------
__global__ __launch_bounds__(256)
void attn_mfma(const ushort* __restrict__ Qb, const ushort* __restrict__ Kb,
               const ushort* __restrict__ Vt, ushort* __restrict__ Ob) {
  __shared__ __align__(16) ushort Ksm[2][64 * 64];
  __shared__ __align__(16) ushort Vtsm[2][64 * 64];
  const int tid = threadIdx.x;
  const int lane = tid & 63, w = tid >> 6;
  const int ql = lane & 31, hi = lane >> 5;
  int bid = blockIdx.x;
  bid = (bid & 7) * 128 + (bid >> 3);
  const int qt = bid & 15, bh = bid >> 4;
  const ushort* Qh = Qb + (size_t)bh * Tc * 64;
  const ushort* Kh = Kb + (size_t)bh * Tc * 64;
  const ushort* Vth = Vt + (size_t)bh * 64 * Tc;
  const int qrow = qt * 128 + w * 32 + ql;
  s8v qf[4];
#pragma unroll
  for (int ds = 0; ds < 4; ++ds)
    qf[ds] = *(const s8v*)(Qh + (size_t)qrow * 64 + ds * 16 + hi * 8);
  f16v accO0, accO1;
#pragma unroll
  for (int i = 0; i < 16; ++i) { accO0[i] = 0.f; accO1[i] = 0.f; }
  float mold = -1e30f, lsum = 0.f;
  int srow[2], soff[2];
#pragma unroll
  for (int seg = 0; seg < 2; ++seg) {
    const int ci = seg * 256 + tid;
    srow[seg] = ci >> 3;
    soff[seg] = ((ci & 7) * 8) ^ ((srow[seg] & 7) << 3);
  }
  auto stage = [&](int buf, int j0) {
#pragma unroll
    for (int seg = 0; seg < 2; ++seg) {
      const int ci = seg * 256 + tid;
      GLOAD_LDS(Kh + (size_t)(j0 + srow[seg]) * 64 + soff[seg], &Ksm[buf][ci * 8]);
      GLOAD_LDS(Vth + (size_t)srow[seg] * Tc + j0 + soff[seg], &Vtsm[buf][ci * 8]);
    }
  };

  stage(0, 0);   // 4 loads in flight
  int cur = 0;
  for (int j0 = 0; j0 < Tc; j0 += 64) {
    const bool st = (j0 + 64 < Tc);
    if (st) {
      stage(cur ^ 1, j0 + 64);   // 4 more in flight (8 total)
      asm volatile("s_waitcnt vmcnt(4)" ::: "memory");  // cur tile ready
    } else {
      asm volatile("s_waitcnt vmcnt(0)" ::: "memory");
    }
    __builtin_amdgcn_s_barrier();   // all waves' cur-loads landed
    f16v s0, s1;
#pragma unroll
    for (int i = 0; i < 16; ++i) { s0[i] = 0.f; s1[i] = 0.f; }
    __builtin_amdgcn_s_setprio(1);
#pragma unroll
    for (int ds = 0; ds < 4; ++ds) {
      const int col = (ds * 16 + hi * 8);
      const int r0 = ql;
      s8v kf0 = *(const s8v*)&Ksm[cur][r0 * 64 + (col ^ ((r0 & 7) << 3))];
      s0 = __builtin_amdgcn_mfma_f32_32x32x16_bf16(kf0, qf[ds], s0, 0, 0, 0);
      const int r1 = 32 + ql;
      s8v kf1 = *(const s8v*)&Ksm[cur][r1 * 64 + (col ^ ((r1 & 7) << 3))];
      s1 = __builtin_amdgcn_mfma_f32_32x32x16_bf16(kf1, qf[ds], s1, 0, 0, 0);
    }
    __builtin_amdgcn_s_setprio(0);
    float cc0 = fmaxf(s0[0], s1[0]), cc1 = fmaxf(s0[1], s1[1]);
    float cc2 = fmaxf(s0[2], s1[2]), cc3 = fmaxf(s0[3], s1[3]);
#pragma unroll
    for (int i = 4; i < 16; i += 4) {
      cc0 = max3f(cc0, s0[i + 0], s1[i + 0]);
      cc1 = max3f(cc1, s0[i + 1], s1[i + 1]);
      cc2 = max3f(cc2, s0[i + 2], s1[i + 2]);
      cc3 = max3f(cc3, s0[i + 3], s1[i + 3]);
    }
    float mx = pmax32(fmaxf(max3f(cc0, cc1, cc2), cc3));
    const bool need = mx > mold + 11.5416f;
    if (__any((int)need)) {
      const float mnew = fmaxf(mold, mx);
      const float sc = exp2v(mold - mnew);
      lsum *= sc;
#pragma unroll
      for (int i = 0; i < 16; ++i) { accO0[i] *= sc; accO1[i] *= sc; }
      mold = mnew;
    }
    float r0s = 0.f, r1s = 0.f, r2s = 0.f, r3s = 0.f;
#pragma unroll
    for (int i = 0; i < 16; i += 4) {
      s0[i+0] = exp2v(s0[i+0] - mold); r0s += s0[i+0];
      s0[i+1] = exp2v(s0[i+1] - mold); r1s += s0[i+1];
      s0[i+2] = exp2v(s0[i+2] - mold); r2s += s0[i+2];
      s0[i+3] = exp2v(s0[i+3] - mold); r3s += s0[i+3];
      s1[i+0] = exp2v(s1[i+0] - mold); r0s += s1[i+0];
      s1[i+1] = exp2v(s1[i+1] - mold); r1s += s1[i+1];
      s1[i+2] = exp2v(s1[i+2] - mold); r2s += s1[i+2];
      s1[i+3] = exp2v(s1[i+3] - mold); r3s += s1[i+3];
    }
    lsum += psum32((r0s + r1s) + (r2s + r3s));
    s8v pa[4];
#pragma unroll
    for (int s = 0; s < 4; ++s) {
      const f16v st2 = (s < 2) ? s0 : s1;
      const int mA = 2 * (s & 1);
      uint32_t a0 = cvtpk(st2[4 * mA + 0], st2[4 * mA + 1]);
      uint32_t a1 = cvtpk(st2[4 * mA + 2], st2[4 * mA + 3]);
      uint32_t b0 = cvtpk(st2[4 * mA + 4], st2[4 * mA + 5]);
      uint32_t b1 = cvtpk(st2[4 * mA + 6], st2[4 * mA + 7]);
      asm("v_permlane32_swap_b32 %0, %1" : "+v"(b0), "+v"(a0));
      asm("v_permlane32_swap_b32 %0, %1" : "+v"(b1), "+v"(a1));
      union { uint32_t u[4]; s8v v; } pk;
      pk.u[0] = a0; pk.u[1] = a1; pk.u[2] = b0; pk.u[3] = b1;
      pa[s] = pk.v;
    }
    __builtin_amdgcn_s_setprio(1);
#pragma unroll
    for (int s = 0; s < 4; ++s) {
      const int col = (s * 16 + hi * 8);
      const int r0 = ql;
      s8v vf0 = *(const s8v*)&Vtsm[cur][r0 * 64 + (col ^ ((r0 & 7) << 3))];
      accO0 = __builtin_amdgcn_mfma_f32_32x32x16_bf16(vf0, pa[s], accO0, 0, 0, 0);
      const int r1 = 32 + ql;
      s8v vf1 = *(const s8v*)&Vtsm[cur][r1 * 64 + (col ^ ((r1 & 7) << 3))];
      accO1 = __builtin_amdgcn_mfma_f32_32x32x16_bf16(vf1, pa[s], accO1, 0, 0, 0);
    }
    __builtin_amdgcn_s_setprio(0);
    __builtin_amdgcn_s_barrier();   // all waves done reading cur
    cur ^= 1;
  }
  const int h = bh & 15, b = bh >> 4;
  const int tok = b * Tc + qt * 128 + w * 32 + ql;
  const float inv = 1.f / lsum;
  ushort* orow = Ob + (size_t)tok * Dc + h * 64;
#pragma unroll
  for (int dt = 0; dt < 2; ++dt) {
    const f16v ac = dt ? accO1 : accO0;
#pragma unroll
    for (int rq = 0; rq < 4; ++rq) {
      u4v pk;
#pragma unroll
      for (int j = 0; j < 4; ++j) pk[j] = f2bf(ac[4 * rq + j] * inv);
      *(u4v*)&orow[dt * 32 + 8 * rq + 4 * hi] = pk;
    }
  }
}

// ---------------------------------------------------------------------------
extern "C" void kernel_launch(void* const* d_in, const int* in_sizes, int n_in,
                              void* d_out, int out_size, void* d_ws, size_t ws_size,
                              hipStream_t stream) {
  (void)in_sizes; (void)n_in; (void)out_size; (void)ws_size;
  const float* x        = (const float*)d_in[0];
  const float* ln1_g    = (const float*)d_in[1];
  const float* ln1_b    = (const float*)d_in[2];
  const float* in_w     = (const float*)d_in[3];
  const float* in_b     = (const float*)d_in[4];
  const float* out_w    = (const float*)d_in[5];
  const float* out_b    = (const float*)d_in[6];
  const float* ln2_g    = (const float*)d_in[7];
  const float* ln2_b    = (const float*)d_in[8];
  const float* rw       = (const float*)d_in[9];
  const float* log_temp = (const float*)d_in[10];
  const float* Wg       = (const float*)d_in[11];
  const float* Wu       = (const float*)d_in[12];
  const float* Wd       = (const float*)d_in[13];
  float* out = (float*)d_out;

  // Workspace (ushorts), total ~138 MiB:
  ushort* h_bf   = (ushort*)d_ws;                       // NTOK*1024   16 MiB
  ushort* Qb     = h_bf   + (size_t)NTOK * Dc;          // 16 MiB
  ushort* Kb     = Qb     + (size_t)NTOK * Dc;          // 16 MiB
  ushort* Vt     = Kb     + (size_t)NTOK * Dc;          // 16 MiB ([bh][d][t])
  ushort* Ob     = Vt     + (size_t)NTOK * Dc;          // 16 MiB
  ushort* act    = Ob     + (size_t)NTOK * Dc;          // NTOK*2048   32 MiB
  ushort* wb_in  = act    + (size_t)NTOK * EDE;         // 3072*1024    6 MiB
  ushort* wb_out = wb_in  + (size_t)3 * Dc * Dc;        // 1024*1024    2 MiB
  ushort* wb_gu  = wb_out + (size_t)Dc * Dc;            // 4096*1024    8 MiB
  ushort* wb_d   = wb_gu  + (size_t)2 * EDE * Dc;       // 1024*2048    4 MiB
  float*  wts    = (float*)(wb_d + (size_t)Dc * EDE);   // NTOK*8     0.25 MiB

  const dim3 blk(256);

  // 0. all weight conversions in one launch
  convert_all<<<dim3(5120), blk, 0, stream>>>(
      in_w, out_w, Wg, Wu, Wd, wb_in, wb_out, wb_gu, wb_d);

  // 1. LN1: x -> h_bf (bf16)
  ln_kernel<0><<<dim3(NTOK), blk, 0, stream>>>(x, ln1_g, ln1_b, h_bf,
                                               nullptr, nullptr, nullptr);
  // 2. QKV GEMM (256^2 8-phase) -> head-major Q(x0.125*log2e)/K + V^T
  gemm256<0><<<dim3(3 * Dc / 256, NTOK / 256), dim3(512), 0, stream>>>(
      h_bf, Dc, wb_in, in_b, Qb, Dc);
  // 3. MFMA attention -> Ob bf16
  attn_mfma<<<dim3(Bc * Hc * (Tc / 128)), blk, 0, stream>>>(Qb, Kb, Vt, Ob);
  // 4. out proj + bias + residual(x) -> out fp32 (128^2)
  gemm_bf16<1><<<dim3(Dc / 128, NTOK / 128), blk, 0, stream>>>(
      Ob, Dc, wb_out, out_b, x, out, Dc, Dc);
  // 5. LN2 + fused router: out -> h_bf (h2), wts
  ln_kernel<1><<<dim3(NTOK), blk, 0, stream>>>(out, ln2_g, ln2_b, h_bf,
                                               rw, log_temp, wts);
  // 6. fused gate+up GEMM (256^2 8-phase) + silu*up*wts -> act bf16
  gemm256<4><<<dim3(2 * EDE / 256, NTOK / 256), dim3(512), 0, stream>>>(
      h_bf, Dc, wb_gu, wts, act, Dc);
  // 7. single down GEMM (128^2, K=2048), += into out
  gemm_bf16<3><<<dim3(Dc / 128, NTOK / 128), blk, 0, stream>>>(
      act, EDE, wb_d, nullptr, nullptr, out, Dc, EDE);
}